// Round 2
// baseline (1016.584 us; speedup 1.0000x reference)
//
#include <hip/hip_runtime.h>
#include <hip/hip_bf16.h>
#include <cstdint>

typedef __bf16 bf16x8 __attribute__((ext_vector_type(8)));
typedef float  f32x4  __attribute__((ext_vector_type(4)));
typedef unsigned short u16;
typedef u16 u16x8 __attribute__((ext_vector_type(8)));

__device__ __forceinline__ u16 f2bf(float f) {
    union { float f; uint32_t u; } x{f};
    uint32_t u = x.u;
    return (u16)((u + 0x7fffu + ((u >> 16) & 1u)) >> 16);
}

__device__ __forceinline__ float gelu_f(float x) {
    return 0.5f * x * (1.0f + erff(x * 0.70710678118654752f));
}

// async global->LDS, 16B per lane; LDS dest is wave-uniform base + lane*16
__device__ __forceinline__ void gl_lds16(const void* g, void* l) {
    __builtin_amdgcn_global_load_lds(
        (__attribute__((address_space(1))) void*)(void*)g,
        (__attribute__((address_space(3))) void*)l, 16, 0, 0);
}

#define MFMA16(a, b, c) __builtin_amdgcn_mfma_f32_16x16x32_bf16((a), (b), (c), 0, 0, 0)
#define SB0 __builtin_amdgcn_sched_barrier(0)
#define LGKM0 do { asm volatile("s_waitcnt lgkmcnt(0)" ::: "memory"); SB0; } while (0)

// ---------------------------------------------------------------------------
// gemm256: 256x256 tile, BK=64, 8 waves (2M x 4N), double-buffered 128KiB LDS,
// 4-phase K-step with counted vmcnt (never drains in main loop), setprio on
// MFMA clusters, XCD-chunked block swizzle. M fixed at 4096 (GY=16).
// A [M][K] bf16, Bt [N][K] bf16. Rows remapped in LDS (early/late halves) so
// tile t+2 staging into buf[cur] is safe after the post-phase-3 barrier.
// ---------------------------------------------------------------------------
template<int EPI, int OUTF32>
__global__ __launch_bounds__(512, 2) void gemm256(
    const u16* __restrict__ A, const u16* __restrict__ Bt,
    const float* __restrict__ bias, void* __restrict__ Cout,
    int N_, int K_)
{
    __shared__ char lds[131072];
    char* ldsA = lds;            // 2 x 32 KB
    char* ldsB = lds + 65536;    // 2 x 32 KB

    const int tid = threadIdx.x, lane = tid & 63, wave = tid >> 6;
    const int wm = wave >> 2, wn = wave & 3;
    const int laneRC = lane & 15;
    const int laneK2 = (lane >> 4) * 16;
    const int swzv = (laneRC & 7) << 4;
    const int cb0 = laneK2 ^ swzv;
    const int cb1 = (64 + laneK2) ^ swzv;

    // XCD-chunked swizzle (grids here are all %8==0), y (M) fastest in chunk
    const int nwg = gridDim.x;
    const int gid = blockIdx.x;
    const int swz = (nwg % 8 == 0) ? (gid % 8) * (nwg / 8) + gid / 8 : gid;
    const long col0 = (long)(swz >> 4) * 256;
    const long row0 = (long)(swz & 15) * 256;

    // staging source offsets (element units, add k0). lds row rl = s*64+(tid>>3)
    long aOff[4], bOff[4];
#pragma unroll
    for (int s = 0; s < 4; ++s) {
        const int rl = s * 64 + (tid >> 3);
        const int cbyte = (tid & 7) * 16;
        const int scol = cbyte ^ ((rl & 7) << 4);
        const int gA = (rl & 63) | (((rl >> 6) & 1) << 7) | (((rl >> 7) & 1) << 6);
        const int gB = (rl & 31) | (((rl >> 5) & 3) << 6) | (((rl >> 7) & 1) << 5);
        aOff[s] = (row0 + gA) * (long)K_ + (scol >> 1);
        bOff[s] = (col0 + gB) * (long)K_ + (scol >> 1);
    }

    // fragment LDS row byte-bases (early halves; late = +16384)
    int arE[4], brr[2];
#pragma unroll
    for (int i = 0; i < 4; ++i) arE[i] = (wm * 64 + i * 16 + laneRC) * 128;
#pragma unroll
    for (int j = 0; j < 2; ++j) brr[j] = (wn * 32 + j * 16 + laneRC) * 128;

    f32x4 acc[8][4];
#pragma unroll
    for (int i = 0; i < 8; ++i)
#pragma unroll
        for (int j = 0; j < 4; ++j)
#pragma unroll
            for (int t = 0; t < 4; ++t) acc[i][j][t] = 0.f;

    const int nt = K_ >> 6;

#define STAGE8(BUF, K0) do {                                                     \
    const long _k0 = (K0);                                                       \
    char* _dA = ldsA + (BUF) * 32768 + wave * 1024;                              \
    char* _dB = ldsB + (BUF) * 32768 + wave * 1024;                              \
    _Pragma("unroll") for (int s = 0; s < 4; ++s)                                \
        gl_lds16(A + aOff[s] + _k0, _dA + s * 8192);                             \
    _Pragma("unroll") for (int s = 0; s < 4; ++s)                                \
        gl_lds16(Bt + bOff[s] + _k0, _dB + s * 8192);                            \
} while (0)

#define QUAD(IB, JB) do {                                                        \
    __builtin_amdgcn_s_setprio(1);                                               \
    _Pragma("unroll") for (int i = 0; i < 4; ++i)                                \
    _Pragma("unroll") for (int j = 0; j < 2; ++j) {                              \
        acc[(IB)*4+i][(JB)*2+j] = MFMA16(af[i][0], bfr[(JB)*2+j][0], acc[(IB)*4+i][(JB)*2+j]); \
        acc[(IB)*4+i][(JB)*2+j] = MFMA16(af[i][1], bfr[(JB)*2+j][1], acc[(IB)*4+i][(JB)*2+j]); \
    }                                                                            \
    __builtin_amdgcn_s_setprio(0);                                               \
} while (0)

    // prologue: tiles 0 and 1 in flight; wait tile 0 (8 newest stay in flight)
    STAGE8(0, 0);
    STAGE8(1, 64);
    asm volatile("s_waitcnt vmcnt(8)" ::: "memory");
    __builtin_amdgcn_s_barrier();
    SB0;

    bf16x8 af[4][2], bfr[4][2];
    for (int t = 0; t < nt; ++t) {
        const int cur = t & 1;
        const char* bA = ldsA + cur * 32768;
        const char* bB = ldsB + cur * 32768;
        // ---- phase 1: A-early + B-low frags; MFMA quadrant (0,0)
#pragma unroll
        for (int i = 0; i < 4; ++i) {
            af[i][0] = *(const bf16x8*)(bA + arE[i] + cb0);
            af[i][1] = *(const bf16x8*)(bA + arE[i] + cb1);
        }
#pragma unroll
        for (int j = 0; j < 2; ++j) {
            bfr[j][0] = *(const bf16x8*)(bB + brr[j] + cb0);
            bfr[j][1] = *(const bf16x8*)(bB + brr[j] + cb1);
        }
        LGKM0;
        QUAD(0, 0);
        // ---- phase 2: B-high frags; MFMA quadrant (0,1)
#pragma unroll
        for (int j = 0; j < 2; ++j) {
            bfr[2 + j][0] = *(const bf16x8*)(bB + brr[j] + 16384 + cb0);
            bfr[2 + j][1] = *(const bf16x8*)(bB + brr[j] + 16384 + cb1);
        }
        LGKM0;
        QUAD(0, 1);
        // ---- phase 3: A-late frags; MFMA quadrant (1,0)
#pragma unroll
        for (int i = 0; i < 4; ++i) {
            af[i][0] = *(const bf16x8*)(bA + arE[i] + 16384 + cb0);
            af[i][1] = *(const bf16x8*)(bA + arE[i] + 16384 + cb1);
        }
        LGKM0;
        QUAD(1, 0);
        __builtin_amdgcn_s_barrier();   // all waves done reading buf[cur]
        SB0;
        // ---- phase 4: stage tile t+2 into buf[cur]; MFMA quadrant (1,1)
        if (t + 2 < nt) STAGE8(cur, (long)(t + 2) * 64);
        QUAD(1, 1);
        if (t + 2 < nt) {
            asm volatile("s_waitcnt vmcnt(8)" ::: "memory");   // tile t+1 landed
        } else if (t + 1 < nt) {
            asm volatile("s_waitcnt vmcnt(0)" ::: "memory");   // last prefetch landed
        }
        if (t + 1 < nt) { __builtin_amdgcn_s_barrier(); SB0; }
    }
#undef STAGE8
#undef QUAD

    // epilogue
#pragma unroll
    for (int j = 0; j < 4; ++j) {
        const long col = col0 + wn * 64 + j * 16 + laneRC;
        const float bv = bias[col];
#pragma unroll
        for (int i = 0; i < 8; ++i) {
            const long rb = row0 + wm * 128 + i * 16 + ((lane >> 4) << 2);
#pragma unroll
            for (int t = 0; t < 4; ++t) {
                float v = acc[i][j][t] + bv;
                if (EPI) v = gelu_f(v);
                const long off = (rb + t) * N_ + col;
                if (OUTF32) ((float*)Cout)[off] = v;
                else        ((u16*)Cout)[off]  = f2bf(v);
            }
        }
    }
}

// ---------------------------------------------------------------------------
// 128x128 GEMM (round-1 structure) — kept for N=768 GEMMs (o-proj, FFN2, head)
// ---------------------------------------------------------------------------
template<int EPI, int OUTF32>
__global__ __launch_bounds__(256, 2) void gemm_bf16(
    const u16* __restrict__ A, const u16* __restrict__ Bt,
    const float* __restrict__ bias, void* __restrict__ Cout,
    int N_, int K_)
{
    __shared__ u16 lA[128 * 64];
    __shared__ u16 lB[128 * 64];
    const int tid  = threadIdx.x;
    const int lane = tid & 63;
    const int wave = tid >> 6;
    const int wr = wave >> 1, wc = wave & 1;
    const long row0 = (long)blockIdx.y * 128;
    const long col0 = (long)blockIdx.x * 128;

    f32x4 acc[4][4];
#pragma unroll
    for (int i = 0; i < 4; ++i)
#pragma unroll
        for (int j = 0; j < 4; ++j)
#pragma unroll
            for (int t = 0; t < 4; ++t) acc[i][j][t] = 0.f;

    int sRow[4], sKb[4];
#pragma unroll
    for (int t = 0; t < 4; ++t) {
        int byteoff = (wave * 4 + t) * 1024 + lane * 16;
        int r = byteoff >> 7;
        sRow[t] = r;
        sKb[t]  = (byteoff & 127) ^ ((r & 7) << 4);
    }
    const int laneRC = lane & 15;
    const int laneK2 = (lane >> 4) * 16;

    for (int k0 = 0; k0 < K_; k0 += 64) {
#pragma unroll
        for (int t = 0; t < 4; ++t) {
            const int cb = (wave * 4 + t) * 1024;
            gl_lds16(A  + (row0 + sRow[t]) * K_ + k0 + (sKb[t] >> 1), (char*)lA + cb);
            gl_lds16(Bt + (col0 + sRow[t]) * K_ + k0 + (sKb[t] >> 1), (char*)lB + cb);
        }
        __syncthreads();
#pragma unroll
        for (int kk = 0; kk < 2; ++kk) {
            bf16x8 af[4], bfr[4];
#pragma unroll
            for (int i = 0; i < 4; ++i) {
                int r = wr * 64 + i * 16 + laneRC;
                af[i] = *(const bf16x8*)((const char*)lA + r * 128 + ((kk * 64 + laneK2) ^ ((r & 7) << 4)));
            }
#pragma unroll
            for (int j = 0; j < 4; ++j) {
                int n = wc * 64 + j * 16 + laneRC;
                bfr[j] = *(const bf16x8*)((const char*)lB + n * 128 + ((kk * 64 + laneK2) ^ ((n & 7) << 4)));
            }
#pragma unroll
            for (int i = 0; i < 4; ++i)
#pragma unroll
                for (int j = 0; j < 4; ++j)
                    acc[i][j] = MFMA16(af[i], bfr[j], acc[i][j]);
        }
        __syncthreads();
    }

#pragma unroll
    for (int j = 0; j < 4; ++j) {
        const long cidx = col0 + wc * 64 + j * 16 + laneRC;
        const float bvv = bias[cidx];
#pragma unroll
        for (int i = 0; i < 4; ++i) {
            const long rbase = row0 + wr * 64 + i * 16 + ((lane >> 4) << 2);
#pragma unroll
            for (int t = 0; t < 4; ++t) {
                float v = acc[i][j][t] + bvv;
                if (EPI) v = gelu_f(v);
                const long off = (rbase + t) * N_ + cidx;
                if (OUTF32) ((float*)Cout)[off] = v;
                else        ((u16*)Cout)[off]  = f2bf(v);
            }
        }
    }
}

// ---------------------------------------------------------------------------
// Flash attention: qkv [4096][2304] bf16 (cols: q|k|v, head-major within each).
// Block = 4 waves, 128 q-rows (32/wave); KB=64; online softmax f32.
// ---------------------------------------------------------------------------
__global__ __launch_bounds__(256, 2) void attn_fwd(
    const u16* __restrict__ qkv, u16* __restrict__ outb, float scale)
{
    __shared__ u16 lQ[128 * 64];
    __shared__ u16 lK[64 * 64];
    __shared__ u16 lVt[64 * 64];
    __shared__ u16 lP[128 * 64];
    const int bh = blockIdx.x;           // b*12 + h
    const int b = bh / 12, h = bh % 12;
    const int q0 = blockIdx.y * 128;
    const int tid = threadIdx.x, lane = tid & 63, wave = tid >> 6;
    const long baseQ = (long)b * 2048 * 2304 + h * 64;
    const long baseK = baseQ + 768;
    const long baseV = baseQ + 1536;
    const int laneRC = lane & 15;
    const int laneK2 = (lane >> 4) * 16;

#pragma unroll
    for (int t = 0; t < 4; ++t) {
        const int cb = (wave * 4 + t) * 1024;
        int byteoff = cb + lane * 16;
        int r = byteoff >> 7;
        int kb = (byteoff & 127) ^ ((r & 7) << 4);
        gl_lds16(qkv + baseQ + (long)(q0 + r) * 2304 + (kb >> 1), (char*)lQ + cb);
    }
    __syncthreads();
    bf16x8 qf[2][2];
#pragma unroll
    for (int rb = 0; rb < 2; ++rb)
#pragma unroll
        for (int kk = 0; kk < 2; ++kk) {
            int r = wave * 32 + rb * 16 + laneRC;
            qf[rb][kk] = *(const bf16x8*)((const char*)lQ + r * 128 + ((kk * 64 + laneK2) ^ ((r & 7) << 4)));
        }

    float mrun[2][4], lrun[2][4];
    f32x4 oacc[2][4];
#pragma unroll
    for (int rb = 0; rb < 2; ++rb)
#pragma unroll
        for (int r = 0; r < 4; ++r) { mrun[rb][r] = -1e30f; lrun[rb][r] = 0.f; }
#pragma unroll
    for (int rb = 0; rb < 2; ++rb)
#pragma unroll
        for (int dc = 0; dc < 4; ++dc)
#pragma unroll
            for (int t = 0; t < 4; ++t) oacc[rb][dc][t] = 0.f;

    for (int kt = 0; kt < 32; ++kt) {
        __syncthreads();
        const int kb0 = kt * 64;
#pragma unroll
        for (int t = 0; t < 2; ++t) {
            const int cb = (wave * 2 + t) * 1024;
            int byteoff = cb + lane * 16;
            int r = byteoff >> 7;
            int kb = (byteoff & 127) ^ ((r & 7) << 4);
            gl_lds16(qkv + baseK + (long)(kb0 + r) * 2304 + (kb >> 1), (char*)lK + cb);
        }
        {
            const int kv = lane, dg = wave;
            const u16x8* gv = (const u16x8*)(qkv + baseV + (long)(kb0 + kv) * 2304 + dg * 16);
            u16x8 v0 = gv[0], v1 = gv[1];
#pragma unroll
            for (int j = 0; j < 8; ++j) {
                int d0 = dg * 16 + j;
                *(u16*)((char*)lVt + d0 * 128 + ((kv * 2) ^ ((d0 & 7) << 4))) = v0[j];
                int d1 = dg * 16 + 8 + j;
                *(u16*)((char*)lVt + d1 * 128 + ((kv * 2) ^ ((d1 & 7) << 4))) = v1[j];
            }
        }
        __syncthreads();

        f32x4 s[2][4];
#pragma unroll
        for (int rb = 0; rb < 2; ++rb)
#pragma unroll
            for (int cb = 0; cb < 4; ++cb)
#pragma unroll
                for (int t = 0; t < 4; ++t) s[rb][cb][t] = 0.f;
#pragma unroll
        for (int kk = 0; kk < 2; ++kk) {
            bf16x8 kf[4];
#pragma unroll
            for (int cb = 0; cb < 4; ++cb) {
                int kr = cb * 16 + laneRC;
                kf[cb] = *(const bf16x8*)((const char*)lK + kr * 128 + ((kk * 64 + laneK2) ^ ((kr & 7) << 4)));
            }
#pragma unroll
            for (int rb = 0; rb < 2; ++rb)
#pragma unroll
                for (int cb = 0; cb < 4; ++cb)
                    s[rb][cb] = MFMA16(qf[rb][kk], kf[cb], s[rb][cb]);
        }

#pragma unroll
        for (int rb = 0; rb < 2; ++rb) {
            float tm[4];
#pragma unroll
            for (int r = 0; r < 4; ++r) {
                float v = fmaxf(fmaxf(s[rb][0][r], s[rb][1][r]),
                                fmaxf(s[rb][2][r], s[rb][3][r])) * scale;
#pragma unroll
                for (int msk = 1; msk < 16; msk <<= 1) v = fmaxf(v, __shfl_xor(v, msk, 64));
                tm[r] = v;
            }
            float corr[4], mn[4], rs[4];
#pragma unroll
            for (int r = 0; r < 4; ++r) {
                mn[r] = fmaxf(mrun[rb][r], tm[r]);
                corr[r] = __expf(mrun[rb][r] - mn[r]);
                mrun[rb][r] = mn[r];
                rs[r] = 0.f;
            }
#pragma unroll
            for (int cb2 = 0; cb2 < 4; ++cb2) {
                int pcol = cb2 * 16 + laneRC;
#pragma unroll
                for (int r = 0; r < 4; ++r) {
                    float pv = __expf(s[rb][cb2][r] * scale - mn[r]);
                    rs[r] += pv;
                    int prow = wave * 32 + rb * 16 + ((lane >> 4) << 2) + r;
                    *(u16*)((char*)lP + prow * 128 + ((pcol * 2) ^ ((prow & 7) << 4))) = f2bf(pv);
                }
            }
#pragma unroll
            for (int r = 0; r < 4; ++r) {
#pragma unroll
                for (int msk = 1; msk < 16; msk <<= 1) rs[r] += __shfl_xor(rs[r], msk, 64);
                lrun[rb][r] = lrun[rb][r] * corr[r] + rs[r];
            }
#pragma unroll
            for (int dc = 0; dc < 4; ++dc)
#pragma unroll
                for (int r = 0; r < 4; ++r) oacc[rb][dc][r] *= corr[r];
        }

#pragma unroll
        for (int kk = 0; kk < 2; ++kk) {
            bf16x8 pf[2], vf[4];
#pragma unroll
            for (int rb = 0; rb < 2; ++rb) {
                int pr = wave * 32 + rb * 16 + laneRC;
                pf[rb] = *(const bf16x8*)((const char*)lP + pr * 128 + ((kk * 64 + laneK2) ^ ((pr & 7) << 4)));
            }
#pragma unroll
            for (int dc = 0; dc < 4; ++dc) {
                int d = dc * 16 + laneRC;
                vf[dc] = *(const bf16x8*)((const char*)lVt + d * 128 + ((kk * 64 + laneK2) ^ ((d & 7) << 4)));
            }
#pragma unroll
            for (int rb = 0; rb < 2; ++rb)
#pragma unroll
                for (int dc = 0; dc < 4; ++dc)
                    oacc[rb][dc] = MFMA16(pf[rb], vf[dc], oacc[rb][dc]);
        }
    }

#pragma unroll
    for (int rb = 0; rb < 2; ++rb)
#pragma unroll
        for (int dc = 0; dc < 4; ++dc)
#pragma unroll
            for (int r = 0; r < 4; ++r) {
                long row = (long)b * 2048 + q0 + wave * 32 + rb * 16 + ((lane >> 4) << 2) + r;
                int col = h * 64 + dc * 16 + laneRC;
                outb[row * 768 + col] = f2bf(oacc[rb][dc][r] / lrun[rb][r]);
            }
}

// ---------------------------------------------------------------------------
__global__ __launch_bounds__(256) void ln_fused(
    const float* __restrict__ a, const float* __restrict__ bres,
    const float* __restrict__ g, const float* __restrict__ be,
    float* __restrict__ outf, u16* __restrict__ outb)
{
    const int row = blockIdx.x, tid = threadIdx.x;
    const int wave = tid >> 6, lane = tid & 63;
    const size_t rbase = (size_t)row * 768;
    float v[3]; int idx[3];
    float s1 = 0.f, s2 = 0.f;
#pragma unroll
    for (int i = 0; i < 3; ++i) {
        idx[i] = tid + i * 256;
        float x = a[rbase + idx[i]];
        if (bres) x += bres[rbase + idx[i]];
        v[i] = x; s1 += x; s2 += x * x;
    }
#pragma unroll
    for (int m = 1; m < 64; m <<= 1) { s1 += __shfl_xor(s1, m, 64); s2 += __shfl_xor(s2, m, 64); }
    __shared__ float rs1[4], rs2[4];
    if (lane == 0) { rs1[wave] = s1; rs2[wave] = s2; }
    __syncthreads();
    s1 = rs1[0] + rs1[1] + rs1[2] + rs1[3];
    s2 = rs2[0] + rs2[1] + rs2[2] + rs2[3];
    const float mean = s1 * (1.f / 768.f);
    const float var  = s2 * (1.f / 768.f) - mean * mean;
    const float rstd = rsqrtf(var + 1e-5f);
#pragma unroll
    for (int i = 0; i < 3; ++i) {
        float y = (v[i] - mean) * rstd * g[idx[i]] + be[idx[i]];
        if (outf) outf[rbase + idx[i]] = y;
        outb[rbase + idx[i]] = f2bf(y);
    }
}

__global__ void transpose_cvt(const float* __restrict__ in, u16* __restrict__ out, int R, int C)
{
    __shared__ float t[32][33];
    const int c0 = blockIdx.x * 32, r0 = blockIdx.y * 32;
    const int tx = threadIdx.x, ty = threadIdx.y;
#pragma unroll
    for (int i = 0; i < 4; ++i)
        t[ty + 8 * i][tx] = in[(size_t)(r0 + ty + 8 * i) * C + c0 + tx];
    __syncthreads();
#pragma unroll
    for (int i = 0; i < 4; ++i)
        out[(size_t)(c0 + ty + 8 * i) * R + r0 + tx] = f2bf(t[tx][ty + 8 * i]);
}

__global__ void cvt_bf16_k(const float* __restrict__ in, u16* __restrict__ out, long n)
{
    long i = ((long)blockIdx.x * 256 + threadIdx.x) * 4;
    if (i >= n) return;
    const float4 f = *(const float4*)(in + i);
    ushort4 u; u.x = f2bf(f.x); u.y = f2bf(f.y); u.z = f2bf(f.z); u.w = f2bf(f.w);
    *(ushort4*)(out + i) = u;
}

__global__ void concat_bias(const float* __restrict__ bq, const float* __restrict__ bk,
                            const float* __restrict__ bv, float* __restrict__ out, int total)
{
    int i = blockIdx.x * 256 + threadIdx.x;
    if (i >= total) return;
    int l = i / 2304, j = i - l * 2304;
    float v = (j < 768) ? bq[l * 768 + j]
            : (j < 1536) ? bk[l * 768 + j - 768]
            : bv[l * 768 + j - 1536];
    out[i] = v;
}

__global__ __launch_bounds__(256) void embed_pe(
    const int* __restrict__ ids, const float* __restrict__ table,
    float* __restrict__ xf, u16* __restrict__ xb)
{
    const int idx = blockIdx.x * 256 + threadIdx.x;
    const int row = idx / 768, d = idx - row * 768;
    const int s = row & 2047;
    const float e = table[(long)ids[row] * 768 + d];
    const int j = d >> 1;
    const float ang = (float)s * __expf(-0.011992630692677324f * (float)(4 * j));
    const float pe = (d & 1) ? cosf(ang) : sinf(ang);
    const float v = e + pe;
    xf[idx] = v;
    xb[idx] = f2bf(v);
}

// ---------------------------------------------------------------------------
extern "C" void kernel_launch(void* const* d_in, const int* in_sizes, int n_in,
                              void* d_out, int out_size, void* d_ws, size_t ws_size,
                              hipStream_t stream)
{
    const int S = 2048, D = 768, H = 12, L = 2, V = 32000, DF = 3072, M = 4096, NQKV = 2304;
    (void)in_sizes; (void)n_in; (void)out_size; (void)ws_size; (void)H; (void)S;

    const int*   ids  = (const int*)  d_in[0];
    const float* emb  = (const float*)d_in[1];
    const float* Wq   = (const float*)d_in[2];
    const float* bq   = (const float*)d_in[3];
    const float* Wk   = (const float*)d_in[4];
    const float* bk   = (const float*)d_in[5];
    const float* Wv   = (const float*)d_in[6];
    const float* bv   = (const float*)d_in[7];
    const float* Wo   = (const float*)d_in[8];
    const float* bo   = (const float*)d_in[9];
    const float* ln1g = (const float*)d_in[10];
    const float* ln1b = (const float*)d_in[11];
    const float* W1   = (const float*)d_in[12];
    const float* b1   = (const float*)d_in[13];
    const float* W2   = (const float*)d_in[14];
    const float* b2   = (const float*)d_in[15];
    const float* ln2g = (const float*)d_in[16];
    const float* ln2b = (const float*)d_in[17];
    const float* Wd   = (const float*)d_in[18];
    const float* bd   = (const float*)d_in[19];
    const float* lnmg = (const float*)d_in[20];
    const float* lnmb = (const float*)d_in[21];
    const float* decb = (const float*)d_in[22];

    char* p = (char*)d_ws;
    auto carve = [&](size_t bytes) { char* r = p; p += (bytes + 255) & ~(size_t)255; return r; };
    u16*   embB  = (u16*)  carve((size_t)V * D * 2);
    u16*   wqkvT = (u16*)  carve((size_t)L * NQKV * D * 2);
    float* bqkv  = (float*)carve((size_t)L * NQKV * 4);
    u16*   woT   = (u16*)  carve((size_t)L * D * D * 2);
    u16*   w1T   = (u16*)  carve((size_t)L * DF * D * 2);
    u16*   w2T   = (u16*)  carve((size_t)L * D * DF * 2);
    u16*   wdT   = (u16*)  carve((size_t)D * D * 2);
    float* xf    = (float*)carve((size_t)M * D * 4);
    u16*   xb    = (u16*)  carve((size_t)M * D * 2);
    u16*   qkvB  = (u16*)  carve((size_t)M * NQKV * 2);
    u16*   aoB   = (u16*)  carve((size_t)M * D * 2);
    float* tmpf  = (float*)carve((size_t)M * D * 4);
    u16*   hB    = (u16*)  carve((size_t)M * DF * 2);

    dim3 t32x8(32, 8);
    cvt_bf16_k<<<((long)V * D / 4 + 255) / 256, 256, 0, stream>>>(emb, embB, (long)V * D);
    for (int l = 0; l < L; ++l) {
        transpose_cvt<<<dim3(24, 24), t32x8, 0, stream>>>(Wq + (size_t)l * D * D, wqkvT + (size_t)l * NQKV * D,                    D, D);
        transpose_cvt<<<dim3(24, 24), t32x8, 0, stream>>>(Wk + (size_t)l * D * D, wqkvT + (size_t)l * NQKV * D + (size_t)D * D,    D, D);
        transpose_cvt<<<dim3(24, 24), t32x8, 0, stream>>>(Wv + (size_t)l * D * D, wqkvT + (size_t)l * NQKV * D + (size_t)2 * D * D, D, D);
        transpose_cvt<<<dim3(24, 24), t32x8, 0, stream>>>(Wo + (size_t)l * D * D, woT + (size_t)l * D * D, D, D);
        transpose_cvt<<<dim3(96, 24), t32x8, 0, stream>>>(W1 + (size_t)l * D * DF, w1T + (size_t)l * DF * D, D, DF);
        transpose_cvt<<<dim3(24, 96), t32x8, 0, stream>>>(W2 + (size_t)l * DF * D, w2T + (size_t)l * D * DF, DF, D);
    }
    transpose_cvt<<<dim3(24, 24), t32x8, 0, stream>>>(Wd, wdT, D, D);
    concat_bias<<<(L * NQKV + 255) / 256, 256, 0, stream>>>(bq, bk, bv, bqkv, L * NQKV);
    embed_pe<<<M * D / 256, 256, 0, stream>>>(ids, emb, xf, xb);

    const float scale = 0.036084391824351615f;  // 1/sqrt(768)
    for (int l = 0; l < L; ++l) {
        gemm256<0, 0><<<(NQKV / 256) * 16, 512, 0, stream>>>(xb, wqkvT + (size_t)l * NQKV * D, bqkv + l * NQKV, qkvB, NQKV, D);
        attn_fwd<<<dim3(24, 16), 256, 0, stream>>>(qkvB, aoB, scale);
        gemm_bf16<0, 1><<<dim3(D / 128, M / 128), 256, 0, stream>>>(aoB, woT + (size_t)l * D * D, bo + l * D, tmpf, D, D);
        ln_fused<<<M, 256, 0, stream>>>(xf, tmpf, ln1g + l * D, ln1b + l * D, xf, xb);
        gemm256<1, 0><<<(DF / 256) * 16, 512, 0, stream>>>(xb, w1T + (size_t)l * DF * D, b1 + l * DF, hB, DF, D);
        gemm_bf16<0, 1><<<dim3(D / 128, M / 128), 256, 0, stream>>>(hB, w2T + (size_t)l * D * DF, b2 + l * D, tmpf, D, DF);
        ln_fused<<<M, 256, 0, stream>>>(xf, tmpf, ln2g + l * D, ln2b + l * D, xf, xb);
    }
    gemm_bf16<1, 1><<<dim3(D / 128, M / 128), 256, 0, stream>>>(xb, wdT, bd, tmpf, D, D);
    ln_fused<<<M, 256, 0, stream>>>(tmpf, nullptr, lnmg, lnmb, nullptr, aoB);
    gemm256<0, 1><<<(V / 256) * 16, 512, 0, stream>>>(aoB, embB, decb, (float*)d_out, V, D);
}

// Round 3
// 995.443 us; speedup vs baseline: 1.0212x; 1.0212x over previous
//
#include <hip/hip_runtime.h>
#include <hip/hip_bf16.h>
#include <cstdint>

typedef __bf16 bf16x8 __attribute__((ext_vector_type(8)));
typedef float  f32x4  __attribute__((ext_vector_type(4)));
typedef unsigned short u16;
typedef u16 u16x8 __attribute__((ext_vector_type(8)));

__device__ __forceinline__ u16 f2bf(float f) {
    union { float f; uint32_t u; } x{f};
    uint32_t u = x.u;
    return (u16)((u + 0x7fffu + ((u >> 16) & 1u)) >> 16);
}

__device__ __forceinline__ float gelu_f(float x) {
    return 0.5f * x * (1.0f + erff(x * 0.70710678118654752f));
}

// async global->LDS, 16B per lane; LDS dest is wave-uniform base + lane*16
__device__ __forceinline__ void gl_lds16(const void* g, void* l) {
    __builtin_amdgcn_global_load_lds(
        (__attribute__((address_space(1))) void*)(void*)g,
        (__attribute__((address_space(3))) void*)l, 16, 0, 0);
}

#define MFMA16(a, b, c) __builtin_amdgcn_mfma_f32_16x16x32_bf16((a), (b), (c), 0, 0, 0)
#define SB0 __builtin_amdgcn_sched_barrier(0)
#define LGKM0 do { asm volatile("s_waitcnt lgkmcnt(0)" ::: "memory"); SB0; } while (0)

// ---------------------------------------------------------------------------
// gemm_v3: 128x128 tile, 4 waves (2x2, wave-tile 64x64), BK=32, double-buffered
// 32 KiB LDS -> ~4 blocks/CU (TLP hides latency). Counted vmcnt (never drains
// in main loop), raw barriers, setprio on MFMA cluster, XCD-chunked swizzle.
// A [M][K] bf16, Bt [N][K] bf16, M=4096 fixed (32 M-blocks). Grids are %8==0.
// LDS layout: 64 lines x 128B per operand tile; line j = [row j | row j+64],
// XOR-swizzled by ((line&7)<<4) -- same conflict-free family as r1 (0 confl).
// ---------------------------------------------------------------------------
template<int EPI, int OUTF32>
__global__ __launch_bounds__(256, 4) void gemm_v3(
    const u16* __restrict__ A, const u16* __restrict__ Bt,
    const float* __restrict__ bias, void* __restrict__ Cout,
    int N_, int K_)
{
    __shared__ char lds[32768];   // A dbuf 2x8KB @0; B dbuf 2x8KB @16384
    const int tid = threadIdx.x, lane = tid & 63, wave = tid >> 6;
    const int wm = wave >> 1, wn = wave & 1;
    const int laneRC = lane & 15;

    // XCD-chunked swizzle, M (row) fastest within a chunk
    const int nwg = gridDim.x, gid = blockIdx.x;
    const int swz = (gid % 8) * (nwg / 8) + gid / 8;
    const long row0 = (long)(swz % 32) * 128;
    const long col0 = (long)(swz / 32) * 128;

    // staging source decode (inverse swizzle) for my 2 chunks per operand
    int aoff[2], boff[2];
#pragma unroll
    for (int q = 0; q < 2; ++q) {
        const int o = tid * 16 + q * 4096;     // linear dest byte in 8KB tile
        const int j = o >> 7;                  // LDS line
        const int u = (o & 127) ^ ((j & 7) << 4);
        const int row = j + ((u >> 6) << 6);   // j + 64*half
        const int c = (u & 63) >> 1;           // k-elem offset
        aoff[q] = (int)((row0 + row) * K_) + c;
        boff[q] = (int)((col0 + row) * K_) + c;
    }

    // fragment read byte offsets (within current A/B buffer)
    int aRd[4], bRd[4];
#pragma unroll
    for (int i = 0; i < 4; ++i) {
        const int rowA = wm * 64 + i * 16 + laneRC;
        const int lA_ = rowA & 63;
        aRd[i] = lA_ * 128 + ((((rowA >> 6) << 6) + (lane >> 4) * 16) ^ ((lA_ & 7) << 4));
        const int rowB = wn * 64 + i * 16 + laneRC;
        const int lB_ = rowB & 63;
        bRd[i] = 16384 + lB_ * 128 + ((((rowB >> 6) << 6) + (lane >> 4) * 16) ^ ((lB_ & 7) << 4));
    }

    f32x4 acc[4][4];
#pragma unroll
    for (int i = 0; i < 4; ++i)
#pragma unroll
        for (int j = 0; j < 4; ++j)
#pragma unroll
            for (int t = 0; t < 4; ++t) acc[i][j][t] = 0.f;

    const int nt = K_ >> 5;   // BK=32

#define STAGE(BUF, K0) do {                                                     \
    const int _k0 = (K0);                                                       \
    char* _d = lds + (BUF) * 8192 + wave * 1024;                                \
    gl_lds16(A  + aoff[0] + _k0, _d);                                           \
    gl_lds16(A  + aoff[1] + _k0, _d + 4096);                                    \
    gl_lds16(Bt + boff[0] + _k0, _d + 16384);                                   \
    gl_lds16(Bt + boff[1] + _k0, _d + 20480);                                   \
} while (0)

    // prologue: tiles 0,1 in flight; wait tile 0 (4 newest = tile 1 stay out)
    STAGE(0, 0);
    STAGE(1, 32);
    asm volatile("s_waitcnt vmcnt(4)" ::: "memory");
    SB0;
    __builtin_amdgcn_s_barrier();
    SB0;

    for (int t = 0; t < nt; ++t) {
        const int cur = t & 1;
        const char* base = lds + cur * 8192;
        bf16x8 af[4], bfr[4];
#pragma unroll
        for (int i = 0; i < 4; ++i) af[i]  = *(const bf16x8*)(base + aRd[i]);
#pragma unroll
        for (int i = 0; i < 4; ++i) bfr[i] = *(const bf16x8*)(base + bRd[i]);
        LGKM0;                       // my 8 ds_reads done (regs valid)
        if (t + 2 < nt) {
            __builtin_amdgcn_s_barrier();   // all waves done reading buf[cur]
            SB0;
            STAGE(cur, (t + 2) * 32);       // issue tile t+2 into buf[cur]
        }
        __builtin_amdgcn_s_setprio(1);
#pragma unroll
        for (int i = 0; i < 4; ++i)
#pragma unroll
            for (int j = 0; j < 4; ++j)
                acc[i][j] = MFMA16(af[i], bfr[j], acc[i][j]);
        __builtin_amdgcn_s_setprio(0);
        if (t + 1 < nt) {
            if (t + 2 < nt) { asm volatile("s_waitcnt vmcnt(4)" ::: "memory"); }
            else            { asm volatile("s_waitcnt vmcnt(0)" ::: "memory"); }
            SB0;
            __builtin_amdgcn_s_barrier();   // tile t+1 visible to all
            SB0;
        }
    }
#undef STAGE

    // epilogue
#pragma unroll
    for (int j = 0; j < 4; ++j) {
        const long col = col0 + wn * 64 + j * 16 + laneRC;
        const float bvv = bias[col];
#pragma unroll
        for (int i = 0; i < 4; ++i) {
            const long rbase = row0 + wm * 64 + i * 16 + ((lane >> 4) << 2);
#pragma unroll
            for (int t = 0; t < 4; ++t) {
                float v = acc[i][j][t] + bvv;
                if (EPI) v = gelu_f(v);
                const long off = (rbase + t) * N_ + col;
                if (OUTF32) ((float*)Cout)[off] = v;
                else        ((u16*)Cout)[off]  = f2bf(v);
            }
        }
    }
}

// ---------------------------------------------------------------------------
// Flash attention: qkv [4096][2304] bf16 (cols: q|k|v, head-major within each).
// Block = 4 waves, 128 q-rows (32/wave); KB=64; online softmax f32.
// ---------------------------------------------------------------------------
__global__ __launch_bounds__(256, 2) void attn_fwd(
    const u16* __restrict__ qkv, u16* __restrict__ outb, float scale)
{
    __shared__ u16 lQ[128 * 64];
    __shared__ u16 lK[64 * 64];
    __shared__ u16 lVt[64 * 64];
    __shared__ u16 lP[128 * 64];
    const int bh = blockIdx.x;           // b*12 + h
    const int b = bh / 12, h = bh % 12;
    const int q0 = blockIdx.y * 128;
    const int tid = threadIdx.x, lane = tid & 63, wave = tid >> 6;
    const long baseQ = (long)b * 2048 * 2304 + h * 64;
    const long baseK = baseQ + 768;
    const long baseV = baseQ + 1536;
    const int laneRC = lane & 15;
    const int laneK2 = (lane >> 4) * 16;

#pragma unroll
    for (int t = 0; t < 4; ++t) {
        const int cb = (wave * 4 + t) * 1024;
        int byteoff = cb + lane * 16;
        int r = byteoff >> 7;
        int kb = (byteoff & 127) ^ ((r & 7) << 4);
        gl_lds16(qkv + baseQ + (long)(q0 + r) * 2304 + (kb >> 1), (char*)lQ + cb);
    }
    __syncthreads();
    bf16x8 qf[2][2];
#pragma unroll
    for (int rb = 0; rb < 2; ++rb)
#pragma unroll
        for (int kk = 0; kk < 2; ++kk) {
            int r = wave * 32 + rb * 16 + laneRC;
            qf[rb][kk] = *(const bf16x8*)((const char*)lQ + r * 128 + ((kk * 64 + laneK2) ^ ((r & 7) << 4)));
        }

    float mrun[2][4], lrun[2][4];
    f32x4 oacc[2][4];
#pragma unroll
    for (int rb = 0; rb < 2; ++rb)
#pragma unroll
        for (int r = 0; r < 4; ++r) { mrun[rb][r] = -1e30f; lrun[rb][r] = 0.f; }
#pragma unroll
    for (int rb = 0; rb < 2; ++rb)
#pragma unroll
        for (int dc = 0; dc < 4; ++dc)
#pragma unroll
            for (int t = 0; t < 4; ++t) oacc[rb][dc][t] = 0.f;

    for (int kt = 0; kt < 32; ++kt) {
        __syncthreads();
        const int kb0 = kt * 64;
#pragma unroll
        for (int t = 0; t < 2; ++t) {
            const int cb = (wave * 2 + t) * 1024;
            int byteoff = cb + lane * 16;
            int r = byteoff >> 7;
            int kb = (byteoff & 127) ^ ((r & 7) << 4);
            gl_lds16(qkv + baseK + (long)(kb0 + r) * 2304 + (kb >> 1), (char*)lK + cb);
        }
        {
            const int kv = lane, dg = wave;
            const u16x8* gv = (const u16x8*)(qkv + baseV + (long)(kb0 + kv) * 2304 + dg * 16);
            u16x8 v0 = gv[0], v1 = gv[1];
#pragma unroll
            for (int j = 0; j < 8; ++j) {
                int d0 = dg * 16 + j;
                *(u16*)((char*)lVt + d0 * 128 + ((kv * 2) ^ ((d0 & 7) << 4))) = v0[j];
                int d1 = dg * 16 + 8 + j;
                *(u16*)((char*)lVt + d1 * 128 + ((kv * 2) ^ ((d1 & 7) << 4))) = v1[j];
            }
        }
        __syncthreads();

        f32x4 s[2][4];
#pragma unroll
        for (int rb = 0; rb < 2; ++rb)
#pragma unroll
            for (int cb = 0; cb < 4; ++cb)
#pragma unroll
                for (int t = 0; t < 4; ++t) s[rb][cb][t] = 0.f;
#pragma unroll
        for (int kk = 0; kk < 2; ++kk) {
            bf16x8 kf[4];
#pragma unroll
            for (int cb = 0; cb < 4; ++cb) {
                int kr = cb * 16 + laneRC;
                kf[cb] = *(const bf16x8*)((const char*)lK + kr * 128 + ((kk * 64 + laneK2) ^ ((kr & 7) << 4)));
            }
#pragma unroll
            for (int rb = 0; rb < 2; ++rb)
#pragma unroll
                for (int cb = 0; cb < 4; ++cb)
                    s[rb][cb] = MFMA16(qf[rb][kk], kf[cb], s[rb][cb]);
        }

#pragma unroll
        for (int rb = 0; rb < 2; ++rb) {
            float tm[4];
#pragma unroll
            for (int r = 0; r < 4; ++r) {
                float v = fmaxf(fmaxf(s[rb][0][r], s[rb][1][r]),
                                fmaxf(s[rb][2][r], s[rb][3][r])) * scale;
#pragma unroll
                for (int msk = 1; msk < 16; msk <<= 1) v = fmaxf(v, __shfl_xor(v, msk, 64));
                tm[r] = v;
            }
            float corr[4], mn[4], rs[4];
#pragma unroll
            for (int r = 0; r < 4; ++r) {
                mn[r] = fmaxf(mrun[rb][r], tm[r]);
                corr[r] = __expf(mrun[rb][r] - mn[r]);
                mrun[rb][r] = mn[r];
                rs[r] = 0.f;
            }
#pragma unroll
            for (int cb2 = 0; cb2 < 4; ++cb2) {
                int pcol = cb2 * 16 + laneRC;
#pragma unroll
                for (int r = 0; r < 4; ++r) {
                    float pv = __expf(s[rb][cb2][r] * scale - mn[r]);
                    rs[r] += pv;
                    int prow = wave * 32 + rb * 16 + ((lane >> 4) << 2) + r;
                    *(u16*)((char*)lP + prow * 128 + ((pcol * 2) ^ ((prow & 7) << 4))) = f2bf(pv);
                }
            }
#pragma unroll
            for (int r = 0; r < 4; ++r) {
#pragma unroll
                for (int msk = 1; msk < 16; msk <<= 1) rs[r] += __shfl_xor(rs[r], msk, 64);
                lrun[rb][r] = lrun[rb][r] * corr[r] + rs[r];
            }
#pragma unroll
            for (int dc = 0; dc < 4; ++dc)
#pragma unroll
                for (int r = 0; r < 4; ++r) oacc[rb][dc][r] *= corr[r];
        }

#pragma unroll
        for (int kk = 0; kk < 2; ++kk) {
            bf16x8 pf[2], vf[4];
#pragma unroll
            for (int rb = 0; rb < 2; ++rb) {
                int pr = wave * 32 + rb * 16 + laneRC;
                pf[rb] = *(const bf16x8*)((const char*)lP + pr * 128 + ((kk * 64 + laneK2) ^ ((pr & 7) << 4)));
            }
#pragma unroll
            for (int dc = 0; dc < 4; ++dc) {
                int d = dc * 16 + laneRC;
                vf[dc] = *(const bf16x8*)((const char*)lVt + d * 128 + ((kk * 64 + laneK2) ^ ((d & 7) << 4)));
            }
#pragma unroll
            for (int rb = 0; rb < 2; ++rb)
#pragma unroll
                for (int dc = 0; dc < 4; ++dc)
                    oacc[rb][dc] = MFMA16(pf[rb], vf[dc], oacc[rb][dc]);
        }
    }

#pragma unroll
    for (int rb = 0; rb < 2; ++rb)
#pragma unroll
        for (int dc = 0; dc < 4; ++dc)
#pragma unroll
            for (int r = 0; r < 4; ++r) {
                long row = (long)b * 2048 + q0 + wave * 32 + rb * 16 + ((lane >> 4) << 2) + r;
                int col = h * 64 + dc * 16 + laneRC;
                outb[row * 768 + col] = f2bf(oacc[rb][dc][r] / lrun[rb][r]);
            }
}

// ---------------------------------------------------------------------------
__global__ __launch_bounds__(256) void ln_fused(
    const float* __restrict__ a, const float* __restrict__ bres,
    const float* __restrict__ g, const float* __restrict__ be,
    float* __restrict__ outf, u16* __restrict__ outb)
{
    const int row = blockIdx.x, tid = threadIdx.x;
    const int wave = tid >> 6, lane = tid & 63;
    const size_t rbase = (size_t)row * 768;
    float v[3]; int idx[3];
    float s1 = 0.f, s2 = 0.f;
#pragma unroll
    for (int i = 0; i < 3; ++i) {
        idx[i] = tid + i * 256;
        float x = a[rbase + idx[i]];
        if (bres) x += bres[rbase + idx[i]];
        v[i] = x; s1 += x; s2 += x * x;
    }
#pragma unroll
    for (int m = 1; m < 64; m <<= 1) { s1 += __shfl_xor(s1, m, 64); s2 += __shfl_xor(s2, m, 64); }
    __shared__ float rs1[4], rs2[4];
    if (lane == 0) { rs1[wave] = s1; rs2[wave] = s2; }
    __syncthreads();
    s1 = rs1[0] + rs1[1] + rs1[2] + rs1[3];
    s2 = rs2[0] + rs2[1] + rs2[2] + rs2[3];
    const float mean = s1 * (1.f / 768.f);
    const float var  = s2 * (1.f / 768.f) - mean * mean;
    const float rstd = rsqrtf(var + 1e-5f);
#pragma unroll
    for (int i = 0; i < 3; ++i) {
        float y = (v[i] - mean) * rstd * g[idx[i]] + be[idx[i]];
        if (outf) outf[rbase + idx[i]] = y;
        outb[rbase + idx[i]] = f2bf(y);
    }
}

__global__ void transpose_cvt(const float* __restrict__ in, u16* __restrict__ out, int R, int C)
{
    __shared__ float t[32][33];
    const int c0 = blockIdx.x * 32, r0 = blockIdx.y * 32;
    const int tx = threadIdx.x, ty = threadIdx.y;
#pragma unroll
    for (int i = 0; i < 4; ++i)
        t[ty + 8 * i][tx] = in[(size_t)(r0 + ty + 8 * i) * C + c0 + tx];
    __syncthreads();
#pragma unroll
    for (int i = 0; i < 4; ++i)
        out[(size_t)(c0 + ty + 8 * i) * R + r0 + tx] = f2bf(t[tx][ty + 8 * i]);
}

__global__ void cvt_bf16_k(const float* __restrict__ in, u16* __restrict__ out, long n)
{
    long i = ((long)blockIdx.x * 256 + threadIdx.x) * 4;
    if (i >= n) return;
    const float4 f = *(const float4*)(in + i);
    ushort4 u; u.x = f2bf(f.x); u.y = f2bf(f.y); u.z = f2bf(f.z); u.w = f2bf(f.w);
    *(ushort4*)(out + i) = u;
}

__global__ void concat_bias(const float* __restrict__ bq, const float* __restrict__ bk,
                            const float* __restrict__ bv, float* __restrict__ out, int total)
{
    int i = blockIdx.x * 256 + threadIdx.x;
    if (i >= total) return;
    int l = i / 2304, j = i - l * 2304;
    float v = (j < 768) ? bq[l * 768 + j]
            : (j < 1536) ? bk[l * 768 + j - 768]
            : bv[l * 768 + j - 1536];
    out[i] = v;
}

__global__ __launch_bounds__(256) void embed_pe(
    const int* __restrict__ ids, const float* __restrict__ table,
    float* __restrict__ xf, u16* __restrict__ xb)
{
    const int idx = blockIdx.x * 256 + threadIdx.x;
    const int row = idx / 768, d = idx - row * 768;
    const int s = row & 2047;
    const float e = table[(long)ids[row] * 768 + d];
    const int j = d >> 1;
    const float ang = (float)s * __expf(-0.011992630692677324f * (float)(4 * j));
    const float pe = (d & 1) ? cosf(ang) : sinf(ang);
    const float v = e + pe;
    xf[idx] = v;
    xb[idx] = f2bf(v);
}

// ---------------------------------------------------------------------------
extern "C" void kernel_launch(void* const* d_in, const int* in_sizes, int n_in,
                              void* d_out, int out_size, void* d_ws, size_t ws_size,
                              hipStream_t stream)
{
    const int S = 2048, D = 768, H = 12, L = 2, V = 32000, DF = 3072, M = 4096, NQKV = 2304;
    (void)in_sizes; (void)n_in; (void)out_size; (void)ws_size; (void)H; (void)S;

    const int*   ids  = (const int*)  d_in[0];
    const float* emb  = (const float*)d_in[1];
    const float* Wq   = (const float*)d_in[2];
    const float* bq   = (const float*)d_in[3];
    const float* Wk   = (const float*)d_in[4];
    const float* bk   = (const float*)d_in[5];
    const float* Wv   = (const float*)d_in[6];
    const float* bv   = (const float*)d_in[7];
    const float* Wo   = (const float*)d_in[8];
    const float* bo   = (const float*)d_in[9];
    const float* ln1g = (const float*)d_in[10];
    const float* ln1b = (const float*)d_in[11];
    const float* W1   = (const float*)d_in[12];
    const float* b1   = (const float*)d_in[13];
    const float* W2   = (const float*)d_in[14];
    const float* b2   = (const float*)d_in[15];
    const float* ln2g = (const float*)d_in[16];
    const float* ln2b = (const float*)d_in[17];
    const float* Wd   = (const float*)d_in[18];
    const float* bd   = (const float*)d_in[19];
    const float* lnmg = (const float*)d_in[20];
    const float* lnmb = (const float*)d_in[21];
    const float* decb = (const float*)d_in[22];

    char* p = (char*)d_ws;
    auto carve = [&](size_t bytes) { char* r = p; p += (bytes + 255) & ~(size_t)255; return r; };
    u16*   embB  = (u16*)  carve((size_t)V * D * 2);
    u16*   wqkvT = (u16*)  carve((size_t)L * NQKV * D * 2);
    float* bqkv  = (float*)carve((size_t)L * NQKV * 4);
    u16*   woT   = (u16*)  carve((size_t)L * D * D * 2);
    u16*   w1T   = (u16*)  carve((size_t)L * DF * D * 2);
    u16*   w2T   = (u16*)  carve((size_t)L * D * DF * 2);
    u16*   wdT   = (u16*)  carve((size_t)D * D * 2);
    float* xf    = (float*)carve((size_t)M * D * 4);
    u16*   xb    = (u16*)  carve((size_t)M * D * 2);
    u16*   qkvB  = (u16*)  carve((size_t)M * NQKV * 2);
    u16*   aoB   = (u16*)  carve((size_t)M * D * 2);
    float* tmpf  = (float*)carve((size_t)M * D * 4);
    u16*   hB    = (u16*)  carve((size_t)M * DF * 2);

    dim3 t32x8(32, 8);
    cvt_bf16_k<<<((long)V * D / 4 + 255) / 256, 256, 0, stream>>>(emb, embB, (long)V * D);
    for (int l = 0; l < L; ++l) {
        transpose_cvt<<<dim3(24, 24), t32x8, 0, stream>>>(Wq + (size_t)l * D * D, wqkvT + (size_t)l * NQKV * D,                    D, D);
        transpose_cvt<<<dim3(24, 24), t32x8, 0, stream>>>(Wk + (size_t)l * D * D, wqkvT + (size_t)l * NQKV * D + (size_t)D * D,    D, D);
        transpose_cvt<<<dim3(24, 24), t32x8, 0, stream>>>(Wv + (size_t)l * D * D, wqkvT + (size_t)l * NQKV * D + (size_t)2 * D * D, D, D);
        transpose_cvt<<<dim3(24, 24), t32x8, 0, stream>>>(Wo + (size_t)l * D * D, woT + (size_t)l * D * D, D, D);
        transpose_cvt<<<dim3(96, 24), t32x8, 0, stream>>>(W1 + (size_t)l * D * DF, w1T + (size_t)l * DF * D, D, DF);
        transpose_cvt<<<dim3(24, 96), t32x8, 0, stream>>>(W2 + (size_t)l * DF * D, w2T + (size_t)l * D * DF, DF, D);
    }
    transpose_cvt<<<dim3(24, 24), t32x8, 0, stream>>>(Wd, wdT, D, D);
    concat_bias<<<(L * NQKV + 255) / 256, 256, 0, stream>>>(bq, bk, bv, bqkv, L * NQKV);
    embed_pe<<<M * D / 256, 256, 0, stream>>>(ids, emb, xf, xb);

    const float scale = 0.036084391824351615f;  // 1/sqrt(768)
    for (int l = 0; l < L; ++l) {
        gemm_v3<0, 0><<<(NQKV / 128) * 32, 256, 0, stream>>>(xb, wqkvT + (size_t)l * NQKV * D, bqkv + l * NQKV, qkvB, NQKV, D);
        attn_fwd<<<dim3(24, 16), 256, 0, stream>>>(qkvB, aoB, scale);
        gemm_v3<0, 1><<<(D / 128) * 32, 256, 0, stream>>>(aoB, woT + (size_t)l * D * D, bo + l * D, tmpf, D, D);
        ln_fused<<<M, 256, 0, stream>>>(xf, tmpf, ln1g + l * D, ln1b + l * D, xf, xb);
        gemm_v3<1, 0><<<(DF / 128) * 32, 256, 0, stream>>>(xb, w1T + (size_t)l * DF * D, b1 + l * DF, hB, DF, D);
        gemm_v3<0, 1><<<(D / 128) * 32, 256, 0, stream>>>(hB, w2T + (size_t)l * D * DF, b2 + l * D, tmpf, D, DF);
        ln_fused<<<M, 256, 0, stream>>>(xf, tmpf, ln2g + l * D, ln2b + l * D, xf, xb);
    }
    gemm_v3<1, 1><<<(D / 128) * 32, 256, 0, stream>>>(xb, wdT, bd, tmpf, D, D);
    ln_fused<<<M, 256, 0, stream>>>(tmpf, nullptr, lnmg, lnmb, nullptr, aoB);
    gemm_v3<0, 1><<<(V / 128) * 32, 256, 0, stream>>>(aoB, embB, decb, (float*)d_out, V, D);
}

// Round 4
// 945.147 us; speedup vs baseline: 1.0756x; 1.0532x over previous
//
#include <hip/hip_runtime.h>
#include <hip/hip_bf16.h>
#include <cstdint>

typedef __bf16 bf16x8 __attribute__((ext_vector_type(8)));
typedef float  f32x4  __attribute__((ext_vector_type(4)));
typedef unsigned short u16;
typedef u16 u16x8 __attribute__((ext_vector_type(8)));

__device__ __forceinline__ u16 f2bf(float f) {
    union { float f; uint32_t u; } x{f};
    uint32_t u = x.u;
    return (u16)((u + 0x7fffu + ((u >> 16) & 1u)) >> 16);
}

__device__ __forceinline__ float gelu_f(float x) {
    return 0.5f * x * (1.0f + erff(x * 0.70710678118654752f));
}

// async global->LDS, 16B per lane; LDS dest is wave-uniform base + lane*16
__device__ __forceinline__ void gl_lds16(const void* g, void* l) {
    __builtin_amdgcn_global_load_lds(
        (__attribute__((address_space(1))) void*)(void*)g,
        (__attribute__((address_space(3))) void*)l, 16, 0, 0);
}

#define MFMA16(a, b, c) __builtin_amdgcn_mfma_f32_16x16x32_bf16((a), (b), (c), 0, 0, 0)

// ---------------------------------------------------------------------------
// 128x128 GEMM, BK=64, 4 waves (2x2), single-buffered (r1 structure - measured
// best of 3 structures tried). NT=1 -> nontemporal C stores (decoder: output
// never re-read; keeps the 524MB write stream from evicting B out of L2/L3).
// ---------------------------------------------------------------------------
template<int EPI, int OUTF32, int NT>
__global__ __launch_bounds__(256, 2) void gemm_bf16(
    const u16* __restrict__ A, const u16* __restrict__ Bt,
    const float* __restrict__ bias, void* __restrict__ Cout,
    int N_, int K_)
{
    __shared__ u16 lA[128 * 64];
    __shared__ u16 lB[128 * 64];
    const int tid  = threadIdx.x;
    const int lane = tid & 63;
    const int wave = tid >> 6;
    const int wr = wave >> 1, wc = wave & 1;
    const long row0 = (long)blockIdx.y * 128;
    const long col0 = (long)blockIdx.x * 128;

    f32x4 acc[4][4];
#pragma unroll
    for (int i = 0; i < 4; ++i)
#pragma unroll
        for (int j = 0; j < 4; ++j)
#pragma unroll
            for (int t = 0; t < 4; ++t) acc[i][j][t] = 0.f;

    int sRow[4], sKb[4];
#pragma unroll
    for (int t = 0; t < 4; ++t) {
        int byteoff = (wave * 4 + t) * 1024 + lane * 16;
        int r = byteoff >> 7;
        sRow[t] = r;
        sKb[t]  = (byteoff & 127) ^ ((r & 7) << 4);
    }
    const int laneRC = lane & 15;
    const int laneK2 = (lane >> 4) * 16;

    for (int k0 = 0; k0 < K_; k0 += 64) {
#pragma unroll
        for (int t = 0; t < 4; ++t) {
            const int cb = (wave * 4 + t) * 1024;
            gl_lds16(A  + (row0 + sRow[t]) * K_ + k0 + (sKb[t] >> 1), (char*)lA + cb);
            gl_lds16(Bt + (col0 + sRow[t]) * K_ + k0 + (sKb[t] >> 1), (char*)lB + cb);
        }
        __syncthreads();
#pragma unroll
        for (int kk = 0; kk < 2; ++kk) {
            bf16x8 af[4], bfr[4];
#pragma unroll
            for (int i = 0; i < 4; ++i) {
                int r = wr * 64 + i * 16 + laneRC;
                af[i] = *(const bf16x8*)((const char*)lA + r * 128 + ((kk * 64 + laneK2) ^ ((r & 7) << 4)));
            }
#pragma unroll
            for (int j = 0; j < 4; ++j) {
                int n = wc * 64 + j * 16 + laneRC;
                bfr[j] = *(const bf16x8*)((const char*)lB + n * 128 + ((kk * 64 + laneK2) ^ ((n & 7) << 4)));
            }
#pragma unroll
            for (int i = 0; i < 4; ++i)
#pragma unroll
                for (int j = 0; j < 4; ++j)
                    acc[i][j] = MFMA16(af[i], bfr[j], acc[i][j]);
        }
        __syncthreads();
    }

#pragma unroll
    for (int j = 0; j < 4; ++j) {
        const long cidx = col0 + wc * 64 + j * 16 + laneRC;
        const float bvv = bias[cidx];
#pragma unroll
        for (int i = 0; i < 4; ++i) {
            const long rbase = row0 + wr * 64 + i * 16 + ((lane >> 4) << 2);
#pragma unroll
            for (int t = 0; t < 4; ++t) {
                float v = acc[i][j][t] + bvv;
                if (EPI) v = gelu_f(v);
                const long off = (rbase + t) * N_ + cidx;
                if (OUTF32) {
                    if (NT) __builtin_nontemporal_store(v, (float*)Cout + off);
                    else    ((float*)Cout)[off] = v;
                } else {
                    if (NT) __builtin_nontemporal_store(f2bf(v), (u16*)Cout + off);
                    else    ((u16*)Cout)[off]  = f2bf(v);
                }
            }
        }
    }
}

// ---------------------------------------------------------------------------
// Flash attention: qkv [4096][2304] bf16 (cols: q|k|v, head-major within each).
// QB=64 (grid 768 blocks -> ~3 blocks/CU), 4 waves x 16 q-rows; KB=64;
// online softmax f32; 32 KiB LDS.
// ---------------------------------------------------------------------------
__global__ __launch_bounds__(256, 3) void attn_fwd(
    const u16* __restrict__ qkv, u16* __restrict__ outb, float scale)
{
    __shared__ u16 lQ[64 * 64];
    __shared__ u16 lK[64 * 64];
    __shared__ u16 lVt[64 * 64];
    __shared__ u16 lP[64 * 64];
    const int bh = blockIdx.x;           // b*12 + h
    const int b = bh / 12, h = bh % 12;
    const int q0 = blockIdx.y * 64;
    const int tid = threadIdx.x, lane = tid & 63, wave = tid >> 6;
    const long baseQ = (long)b * 2048 * 2304 + h * 64;
    const long baseK = baseQ + 768;
    const long baseV = baseQ + 1536;
    const int laneRC = lane & 15;
    const int laneK2 = (lane >> 4) * 16;

    // stage Q tile [64][64] (swizzled)
#pragma unroll
    for (int t = 0; t < 2; ++t) {
        const int cb = (wave * 2 + t) * 1024;
        int byteoff = cb + lane * 16;
        int r = byteoff >> 7;
        int kb = (byteoff & 127) ^ ((r & 7) << 4);
        gl_lds16(qkv + baseQ + (long)(q0 + r) * 2304 + (kb >> 1), (char*)lQ + cb);
    }
    __syncthreads();
    bf16x8 qf[2];
#pragma unroll
    for (int kk = 0; kk < 2; ++kk) {
        int r = wave * 16 + laneRC;
        qf[kk] = *(const bf16x8*)((const char*)lQ + r * 128 + ((kk * 64 + laneK2) ^ ((r & 7) << 4)));
    }

    float mrun[4], lrun[4];
    f32x4 oacc[4];
#pragma unroll
    for (int r = 0; r < 4; ++r) { mrun[r] = -1e30f; lrun[r] = 0.f; }
#pragma unroll
    for (int dc = 0; dc < 4; ++dc)
#pragma unroll
        for (int t = 0; t < 4; ++t) oacc[dc][t] = 0.f;

    for (int kt = 0; kt < 32; ++kt) {
        __syncthreads();                 // prior PV reads of lK/lVt done
        const int kb0 = kt * 64;
#pragma unroll
        for (int t = 0; t < 2; ++t) {    // stage K tile [64][64]
            const int cb = (wave * 2 + t) * 1024;
            int byteoff = cb + lane * 16;
            int r = byteoff >> 7;
            int kb = (byteoff & 127) ^ ((r & 7) << 4);
            gl_lds16(qkv + baseK + (long)(kb0 + r) * 2304 + (kb >> 1), (char*)lK + cb);
        }
        {   // stage V transposed: thread = (key=lane, dgroup=wave)
            const int kv = lane, dg = wave;
            const u16x8* gv = (const u16x8*)(qkv + baseV + (long)(kb0 + kv) * 2304 + dg * 16);
            u16x8 v0 = gv[0], v1 = gv[1];
#pragma unroll
            for (int j = 0; j < 8; ++j) {
                int d0 = dg * 16 + j;
                *(u16*)((char*)lVt + d0 * 128 + ((kv * 2) ^ ((d0 & 7) << 4))) = v0[j];
                int d1 = dg * 16 + 8 + j;
                *(u16*)((char*)lVt + d1 * 128 + ((kv * 2) ^ ((d1 & 7) << 4))) = v1[j];
            }
        }
        __syncthreads();

        // S = Q K^T
        f32x4 s[4];
#pragma unroll
        for (int cb = 0; cb < 4; ++cb)
#pragma unroll
            for (int t = 0; t < 4; ++t) s[cb][t] = 0.f;
#pragma unroll
        for (int kk = 0; kk < 2; ++kk) {
            bf16x8 kf[4];
#pragma unroll
            for (int cb = 0; cb < 4; ++cb) {
                int kr = cb * 16 + laneRC;
                kf[cb] = *(const bf16x8*)((const char*)lK + kr * 128 + ((kk * 64 + laneK2) ^ ((kr & 7) << 4)));
            }
#pragma unroll
            for (int cb = 0; cb < 4; ++cb)
                s[cb] = MFMA16(qf[kk], kf[cb], s[cb]);
        }

        // online softmax; P -> LDS (bf16, swizzled)
        {
            float tm[4];
#pragma unroll
            for (int r = 0; r < 4; ++r) {
                float v = fmaxf(fmaxf(s[0][r], s[1][r]), fmaxf(s[2][r], s[3][r])) * scale;
#pragma unroll
                for (int msk = 1; msk < 16; msk <<= 1) v = fmaxf(v, __shfl_xor(v, msk, 64));
                tm[r] = v;
            }
            float corr[4], mn[4], rs[4];
#pragma unroll
            for (int r = 0; r < 4; ++r) {
                mn[r] = fmaxf(mrun[r], tm[r]);
                corr[r] = __expf(mrun[r] - mn[r]);
                mrun[r] = mn[r];
                rs[r] = 0.f;
            }
#pragma unroll
            for (int cb2 = 0; cb2 < 4; ++cb2) {
                int pcol = cb2 * 16 + laneRC;
#pragma unroll
                for (int r = 0; r < 4; ++r) {
                    float pv = __expf(s[cb2][r] * scale - mn[r]);
                    rs[r] += pv;
                    int prow = wave * 16 + ((lane >> 4) << 2) + r;
                    *(u16*)((char*)lP + prow * 128 + ((pcol * 2) ^ ((prow & 7) << 4))) = f2bf(pv);
                }
            }
#pragma unroll
            for (int r = 0; r < 4; ++r) {
#pragma unroll
                for (int msk = 1; msk < 16; msk <<= 1) rs[r] += __shfl_xor(rs[r], msk, 64);
                lrun[r] = lrun[r] * corr[r] + rs[r];
            }
#pragma unroll
            for (int dc = 0; dc < 4; ++dc)
#pragma unroll
                for (int r = 0; r < 4; ++r) oacc[dc][r] *= corr[r];
        }

        // O += P @ V   (lP written/read by same wave; compiler orders via lgkmcnt)
#pragma unroll
        for (int kk = 0; kk < 2; ++kk) {
            bf16x8 pf, vf[4];
            {
                int pr = wave * 16 + laneRC;
                pf = *(const bf16x8*)((const char*)lP + pr * 128 + ((kk * 64 + laneK2) ^ ((pr & 7) << 4)));
            }
#pragma unroll
            for (int dc = 0; dc < 4; ++dc) {
                int d = dc * 16 + laneRC;
                vf[dc] = *(const bf16x8*)((const char*)lVt + d * 128 + ((kk * 64 + laneK2) ^ ((d & 7) << 4)));
            }
#pragma unroll
            for (int dc = 0; dc < 4; ++dc)
                oacc[dc] = MFMA16(pf, vf[dc], oacc[dc]);
        }
    }

#pragma unroll
    for (int dc = 0; dc < 4; ++dc)
#pragma unroll
        for (int r = 0; r < 4; ++r) {
            long row = (long)b * 2048 + q0 + wave * 16 + ((lane >> 4) << 2) + r;
            int col = h * 64 + dc * 16 + laneRC;
            outb[row * 768 + col] = f2bf(oacc[dc][r] / lrun[r]);
        }
}

// ---------------------------------------------------------------------------
__global__ __launch_bounds__(256) void ln_fused(
    const float* __restrict__ a, const float* __restrict__ bres,
    const float* __restrict__ g, const float* __restrict__ be,
    float* __restrict__ outf, u16* __restrict__ outb)
{
    const int row = blockIdx.x, tid = threadIdx.x;
    const int wave = tid >> 6, lane = tid & 63;
    const size_t rbase = (size_t)row * 768;
    float v[3]; int idx[3];
    float s1 = 0.f, s2 = 0.f;
#pragma unroll
    for (int i = 0; i < 3; ++i) {
        idx[i] = tid + i * 256;
        float x = a[rbase + idx[i]];
        if (bres) x += bres[rbase + idx[i]];
        v[i] = x; s1 += x; s2 += x * x;
    }
#pragma unroll
    for (int m = 1; m < 64; m <<= 1) { s1 += __shfl_xor(s1, m, 64); s2 += __shfl_xor(s2, m, 64); }
    __shared__ float rs1[4], rs2[4];
    if (lane == 0) { rs1[wave] = s1; rs2[wave] = s2; }
    __syncthreads();
    s1 = rs1[0] + rs1[1] + rs1[2] + rs1[3];
    s2 = rs2[0] + rs2[1] + rs2[2] + rs2[3];
    const float mean = s1 * (1.f / 768.f);
    const float var  = s2 * (1.f / 768.f) - mean * mean;
    const float rstd = rsqrtf(var + 1e-5f);
#pragma unroll
    for (int i = 0; i < 3; ++i) {
        float y = (v[i] - mean) * rstd * g[idx[i]] + be[idx[i]];
        if (outf) outf[rbase + idx[i]] = y;
        outb[rbase + idx[i]] = f2bf(y);
    }
}

__global__ void transpose_cvt(const float* __restrict__ in, u16* __restrict__ out, int R, int C)
{
    __shared__ float t[32][33];
    const int c0 = blockIdx.x * 32, r0 = blockIdx.y * 32;
    const int tx = threadIdx.x, ty = threadIdx.y;
#pragma unroll
    for (int i = 0; i < 4; ++i)
        t[ty + 8 * i][tx] = in[(size_t)(r0 + ty + 8 * i) * C + c0 + tx];
    __syncthreads();
#pragma unroll
    for (int i = 0; i < 4; ++i)
        out[(size_t)(c0 + ty + 8 * i) * R + r0 + tx] = f2bf(t[tx][ty + 8 * i]);
}

__global__ void cvt_bf16_k(const float* __restrict__ in, u16* __restrict__ out, long n)
{
    long i = ((long)blockIdx.x * 256 + threadIdx.x) * 4;
    if (i >= n) return;
    const float4 f = *(const float4*)(in + i);
    ushort4 u; u.x = f2bf(f.x); u.y = f2bf(f.y); u.z = f2bf(f.z); u.w = f2bf(f.w);
    *(ushort4*)(out + i) = u;
}

__global__ void concat_bias(const float* __restrict__ bq, const float* __restrict__ bk,
                            const float* __restrict__ bv, float* __restrict__ out, int total)
{
    int i = blockIdx.x * 256 + threadIdx.x;
    if (i >= total) return;
    int l = i / 2304, j = i - l * 2304;
    float v = (j < 768) ? bq[l * 768 + j]
            : (j < 1536) ? bk[l * 768 + j - 768]
            : bv[l * 768 + j - 1536];
    out[i] = v;
}

__global__ __launch_bounds__(256) void embed_pe(
    const int* __restrict__ ids, const float* __restrict__ table,
    float* __restrict__ xf, u16* __restrict__ xb)
{
    const int idx = blockIdx.x * 256 + threadIdx.x;
    const int row = idx / 768, d = idx - row * 768;
    const int s = row & 2047;
    const float e = table[(long)ids[row] * 768 + d];
    const int j = d >> 1;
    const float ang = (float)s * __expf(-0.011992630692677324f * (float)(4 * j));
    const float pe = (d & 1) ? cosf(ang) : sinf(ang);
    const float v = e + pe;
    xf[idx] = v;
    xb[idx] = f2bf(v);
}

// ---------------------------------------------------------------------------
extern "C" void kernel_launch(void* const* d_in, const int* in_sizes, int n_in,
                              void* d_out, int out_size, void* d_ws, size_t ws_size,
                              hipStream_t stream)
{
    const int S = 2048, D = 768, H = 12, L = 2, V = 32000, DF = 3072, M = 4096, NQKV = 2304;
    (void)in_sizes; (void)n_in; (void)out_size; (void)ws_size; (void)H; (void)S;

    const int*   ids  = (const int*)  d_in[0];
    const float* emb  = (const float*)d_in[1];
    const float* Wq   = (const float*)d_in[2];
    const float* bq   = (const float*)d_in[3];
    const float* Wk   = (const float*)d_in[4];
    const float* bk   = (const float*)d_in[5];
    const float* Wv   = (const float*)d_in[6];
    const float* bv   = (const float*)d_in[7];
    const float* Wo   = (const float*)d_in[8];
    const float* bo   = (const float*)d_in[9];
    const float* ln1g = (const float*)d_in[10];
    const float* ln1b = (const float*)d_in[11];
    const float* W1   = (const float*)d_in[12];
    const float* b1   = (const float*)d_in[13];
    const float* W2   = (const float*)d_in[14];
    const float* b2   = (const float*)d_in[15];
    const float* ln2g = (const float*)d_in[16];
    const float* ln2b = (const float*)d_in[17];
    const float* Wd   = (const float*)d_in[18];
    const float* bd   = (const float*)d_in[19];
    const float* lnmg = (const float*)d_in[20];
    const float* lnmb = (const float*)d_in[21];
    const float* decb = (const float*)d_in[22];

    char* p = (char*)d_ws;
    auto carve = [&](size_t bytes) { char* r = p; p += (bytes + 255) & ~(size_t)255; return r; };
    u16*   embB  = (u16*)  carve((size_t)V * D * 2);
    u16*   wqkvT = (u16*)  carve((size_t)L * NQKV * D * 2);
    float* bqkv  = (float*)carve((size_t)L * NQKV * 4);
    u16*   woT   = (u16*)  carve((size_t)L * D * D * 2);
    u16*   w1T   = (u16*)  carve((size_t)L * DF * D * 2);
    u16*   w2T   = (u16*)  carve((size_t)L * D * DF * 2);
    u16*   wdT   = (u16*)  carve((size_t)D * D * 2);
    float* xf    = (float*)carve((size_t)M * D * 4);
    u16*   xb    = (u16*)  carve((size_t)M * D * 2);
    u16*   qkvB  = (u16*)  carve((size_t)M * NQKV * 2);
    u16*   aoB   = (u16*)  carve((size_t)M * D * 2);
    float* tmpf  = (float*)carve((size_t)M * D * 4);
    u16*   hB    = (u16*)  carve((size_t)M * DF * 2);

    dim3 t32x8(32, 8);
    cvt_bf16_k<<<((long)V * D / 4 + 255) / 256, 256, 0, stream>>>(emb, embB, (long)V * D);
    for (int l = 0; l < L; ++l) {
        transpose_cvt<<<dim3(24, 24), t32x8, 0, stream>>>(Wq + (size_t)l * D * D, wqkvT + (size_t)l * NQKV * D,                    D, D);
        transpose_cvt<<<dim3(24, 24), t32x8, 0, stream>>>(Wk + (size_t)l * D * D, wqkvT + (size_t)l * NQKV * D + (size_t)D * D,    D, D);
        transpose_cvt<<<dim3(24, 24), t32x8, 0, stream>>>(Wv + (size_t)l * D * D, wqkvT + (size_t)l * NQKV * D + (size_t)2 * D * D, D, D);
        transpose_cvt<<<dim3(24, 24), t32x8, 0, stream>>>(Wo + (size_t)l * D * D, woT + (size_t)l * D * D, D, D);
        transpose_cvt<<<dim3(96, 24), t32x8, 0, stream>>>(W1 + (size_t)l * D * DF, w1T + (size_t)l * DF * D, D, DF);
        transpose_cvt<<<dim3(24, 96), t32x8, 0, stream>>>(W2 + (size_t)l * DF * D, w2T + (size_t)l * D * DF, DF, D);
    }
    transpose_cvt<<<dim3(24, 24), t32x8, 0, stream>>>(Wd, wdT, D, D);
    concat_bias<<<(L * NQKV + 255) / 256, 256, 0, stream>>>(bq, bk, bv, bqkv, L * NQKV);
    embed_pe<<<M * D / 256, 256, 0, stream>>>(ids, emb, xf, xb);

    const float scale = 0.036084391824351615f;  // 1/sqrt(768)
    for (int l = 0; l < L; ++l) {
        gemm_bf16<0, 0, 0><<<dim3(NQKV / 128, M / 128), 256, 0, stream>>>(xb, wqkvT + (size_t)l * NQKV * D, bqkv + l * NQKV, qkvB, NQKV, D);
        attn_fwd<<<dim3(24, 32), 256, 0, stream>>>(qkvB, aoB, scale);
        gemm_bf16<0, 1, 0><<<dim3(D / 128, M / 128), 256, 0, stream>>>(aoB, woT + (size_t)l * D * D, bo + l * D, tmpf, D, D);
        ln_fused<<<M, 256, 0, stream>>>(xf, tmpf, ln1g + l * D, ln1b + l * D, xf, xb);
        gemm_bf16<1, 0, 0><<<dim3(DF / 128, M / 128), 256, 0, stream>>>(xb, w1T + (size_t)l * DF * D, b1 + l * DF, hB, DF, D);
        gemm_bf16<0, 1, 0><<<dim3(D / 128, M / 128), 256, 0, stream>>>(hB, w2T + (size_t)l * D * DF, b2 + l * D, tmpf, D, DF);
        ln_fused<<<M, 256, 0, stream>>>(xf, tmpf, ln2g + l * D, ln2b + l * D, xf, xb);
    }
    gemm_bf16<1, 1, 0><<<dim3(D / 128, M / 128), 256, 0, stream>>>(xb, wdT, bd, tmpf, D, D);
    ln_fused<<<M, 256, 0, stream>>>(tmpf, nullptr, lnmg, lnmb, nullptr, aoB);
    gemm_bf16<0, 1, 1><<<dim3(V / 128, M / 128), 256, 0, stream>>>(aoB, embB, decb, (float*)d_out, V, D);
}

// Round 5
// 902.782 us; speedup vs baseline: 1.1261x; 1.0469x over previous
//
#include <hip/hip_runtime.h>
#include <hip/hip_bf16.h>
#include <cstdint>

typedef __bf16 bf16x8 __attribute__((ext_vector_type(8)));
typedef float  f32x4  __attribute__((ext_vector_type(4)));
typedef unsigned short u16;
typedef u16 u16x8 __attribute__((ext_vector_type(8)));

__device__ __forceinline__ u16 f2bf(float f) {
    union { float f; uint32_t u; } x{f};
    uint32_t u = x.u;
    return (u16)((u + 0x7fffu + ((u >> 16) & 1u)) >> 16);
}

__device__ __forceinline__ float gelu_f(float x) {
    return 0.5f * x * (1.0f + erff(x * 0.70710678118654752f));
}

// async global->LDS, 16B per lane; LDS dest is wave-uniform base + lane*16
__device__ __forceinline__ void gl_lds16(const void* g, void* l) {
    __builtin_amdgcn_global_load_lds(
        (__attribute__((address_space(1))) void*)(void*)g,
        (__attribute__((address_space(3))) void*)l, 16, 0, 0);
}

#define MFMA16(a, b, c) __builtin_amdgcn_mfma_f32_16x16x32_bf16((a), (b), (c), 0, 0, 0)
#define SB0 __builtin_amdgcn_sched_barrier(0)

// ---------------------------------------------------------------------------
// 128x128 GEMM, BK=64, 4 waves (2x2), single-buffered (r1 structure — measured
// best of the 3 structures tried: r1 328µs vs r2 336 vs r3 373 on decoder).
// ---------------------------------------------------------------------------
template<int EPI, int OUTF32>
__global__ __launch_bounds__(256, 2) void gemm_bf16(
    const u16* __restrict__ A, const u16* __restrict__ Bt,
    const float* __restrict__ bias, void* __restrict__ Cout,
    int N_, int K_)
{
    __shared__ u16 lA[128 * 64];
    __shared__ u16 lB[128 * 64];
    const int tid  = threadIdx.x;
    const int lane = tid & 63;
    const int wave = tid >> 6;
    const int wr = wave >> 1, wc = wave & 1;
    const long row0 = (long)blockIdx.y * 128;
    const long col0 = (long)blockIdx.x * 128;

    f32x4 acc[4][4];
#pragma unroll
    for (int i = 0; i < 4; ++i)
#pragma unroll
        for (int j = 0; j < 4; ++j)
#pragma unroll
            for (int t = 0; t < 4; ++t) acc[i][j][t] = 0.f;

    int sRow[4], sKb[4];
#pragma unroll
    for (int t = 0; t < 4; ++t) {
        int byteoff = (wave * 4 + t) * 1024 + lane * 16;
        int r = byteoff >> 7;
        sRow[t] = r;
        sKb[t]  = (byteoff & 127) ^ ((r & 7) << 4);
    }
    const int laneRC = lane & 15;
    const int laneK2 = (lane >> 4) * 16;

    for (int k0 = 0; k0 < K_; k0 += 64) {
#pragma unroll
        for (int t = 0; t < 4; ++t) {
            const int cb = (wave * 4 + t) * 1024;
            gl_lds16(A  + (row0 + sRow[t]) * K_ + k0 + (sKb[t] >> 1), (char*)lA + cb);
            gl_lds16(Bt + (col0 + sRow[t]) * K_ + k0 + (sKb[t] >> 1), (char*)lB + cb);
        }
        __syncthreads();
#pragma unroll
        for (int kk = 0; kk < 2; ++kk) {
            bf16x8 af[4], bfr[4];
#pragma unroll
            for (int i = 0; i < 4; ++i) {
                int r = wr * 64 + i * 16 + laneRC;
                af[i] = *(const bf16x8*)((const char*)lA + r * 128 + ((kk * 64 + laneK2) ^ ((r & 7) << 4)));
            }
#pragma unroll
            for (int j = 0; j < 4; ++j) {
                int n = wc * 64 + j * 16 + laneRC;
                bfr[j] = *(const bf16x8*)((const char*)lB + n * 128 + ((kk * 64 + laneK2) ^ ((n & 7) << 4)));
            }
#pragma unroll
            for (int i = 0; i < 4; ++i)
#pragma unroll
                for (int j = 0; j < 4; ++j)
                    acc[i][j] = MFMA16(af[i], bfr[j], acc[i][j]);
        }
        __syncthreads();
    }

#pragma unroll
    for (int j = 0; j < 4; ++j) {
        const long cidx = col0 + wc * 64 + j * 16 + laneRC;
        const float bvv = bias[cidx];
#pragma unroll
        for (int i = 0; i < 4; ++i) {
            const long rbase = row0 + wr * 64 + i * 16 + ((lane >> 4) << 2);
#pragma unroll
            for (int t = 0; t < 4; ++t) {
                float v = acc[i][j][t] + bvv;
                if (EPI) v = gelu_f(v);
                const long off = (rbase + t) * N_ + cidx;
                if (OUTF32) ((float*)Cout)[off] = v;
                else        ((u16*)Cout)[off]  = f2bf(v);
            }
        }
    }
}

// ---------------------------------------------------------------------------
// Flash attention, pipelined: qkv [4096][2304] bf16 (q|k|v head-major).
// QB=64 (grid 768), 4 waves x 16 q-rows, KB=64. Double-buffered K/V LDS,
// ONE barrier per K-tile; K staged via gl_lds issued 1 iter ahead; V loaded
// global->reg 1 iter ahead, written to LDS after the barrier (issue-early/
// write-late). 48 KiB LDS -> 3 blocks/CU.
// ---------------------------------------------------------------------------
__global__ __launch_bounds__(256, 3) void attn_fwd(
    const u16* __restrict__ qkv, u16* __restrict__ outb, float scale)
{
    __shared__ u16 lQ[64 * 64];
    __shared__ u16 lK[2][64 * 64];
    __shared__ u16 lVt[2][64 * 64];
    __shared__ u16 lP[64 * 64];
    const int bh = blockIdx.x;           // b*12 + h
    const int b = bh / 12, h = bh % 12;
    const int q0 = blockIdx.y * 64;
    const int tid = threadIdx.x, lane = tid & 63, wave = tid >> 6;
    const long baseQ = (long)b * 2048 * 2304 + h * 64;
    const long baseK = baseQ + 768;
    const long baseV = baseQ + 1536;
    const int laneRC = lane & 15;
    const int laneK2 = (lane >> 4) * 16;

    // staging decode (shared by Q and K tiles): 2 chunks/wave of a [64][64] tile
    int stR[2], stC[2];
#pragma unroll
    for (int t = 0; t < 2; ++t) {
        const int byteoff = (wave * 2 + t) * 1024 + lane * 16;
        const int r = byteoff >> 7;
        stR[t] = r;
        stC[t] = ((byteoff & 127) ^ ((r & 7) << 4)) >> 1;
    }

#define STAGEK(BUF, KB0) do {                                                    \
    _Pragma("unroll") for (int t = 0; t < 2; ++t)                                \
        gl_lds16(qkv + baseK + (long)((KB0) + stR[t]) * 2304 + stC[t],           \
                 (char*)lK[BUF] + (wave * 2 + t) * 1024);                        \
} while (0)

    // stage Q; issue K[0]; load V-regs for kt=0
#pragma unroll
    for (int t = 0; t < 2; ++t)
        gl_lds16(qkv + baseQ + (long)(q0 + stR[t]) * 2304 + stC[t],
                 (char*)lQ + (wave * 2 + t) * 1024);
    STAGEK(0, 0);
    u16x8 vA0, vA1;
    {
        const u16x8* gv = (const u16x8*)(qkv + baseV + (long)lane * 2304 + wave * 16);
        vA0 = gv[0]; vA1 = gv[1];
    }
    __syncthreads();   // drains all; Q + K[0] landed, V-regs present

    bf16x8 qf[2];
#pragma unroll
    for (int kk = 0; kk < 2; ++kk) {
        int r = wave * 16 + laneRC;
        qf[kk] = *(const bf16x8*)((const char*)lQ + r * 128 + ((kk * 64 + laneK2) ^ ((r & 7) << 4)));
    }

    float mrun[4], lrun[4];
    f32x4 oacc[4];
#pragma unroll
    for (int r = 0; r < 4; ++r) { mrun[r] = -1e30f; lrun[r] = 0.f; }
#pragma unroll
    for (int dc = 0; dc < 4; ++dc)
#pragma unroll
        for (int t = 0; t < 4; ++t) oacc[dc][t] = 0.f;

    u16x8 vB0 = vA0, vB1 = vA1;
    for (int kt = 0; kt < 32; ++kt) {
        const int cur = kt & 1;
        // ---- A: K[cur] + V-regs[cur] arrived (issued 1 iter ago); commit V to LDS
        asm volatile("s_waitcnt vmcnt(0)" ::: "memory");
        SB0;
        {
            const int kv = lane, dg = wave;
            char* vt = (char*)lVt[cur];
#pragma unroll
            for (int j = 0; j < 8; ++j) {
                int d0 = dg * 16 + j;
                *(u16*)(vt + d0 * 128 + ((kv * 2) ^ ((d0 & 7) << 4))) = vA0[j];
                int d1 = dg * 16 + 8 + j;
                *(u16*)(vt + d1 * 128 + ((kv * 2) ^ ((d1 & 7) << 4))) = vA1[j];
            }
        }
        __builtin_amdgcn_s_barrier();    // all writes to buf[cur] visible; all
        SB0;                             // reads of buf[cur^1] (iter kt-1) done
        // ---- B: issue next tile's staging (overlaps with compute below)
        if (kt + 1 < 32) {
            STAGEK(cur ^ 1, (kt + 1) * 64);
            const u16x8* gv = (const u16x8*)(qkv + baseV + (long)((kt + 1) * 64 + lane) * 2304 + wave * 16);
            vB0 = gv[0]; vB1 = gv[1];
        }
        // ---- C: compute on buf[cur]
        const char* lKc = (const char*)lK[cur];
        const char* lVc = (const char*)lVt[cur];

        f32x4 s[4];
#pragma unroll
        for (int cb = 0; cb < 4; ++cb)
#pragma unroll
            for (int t = 0; t < 4; ++t) s[cb][t] = 0.f;
#pragma unroll
        for (int kk = 0; kk < 2; ++kk) {
            bf16x8 kf[4];
#pragma unroll
            for (int cb = 0; cb < 4; ++cb) {
                int kr = cb * 16 + laneRC;
                kf[cb] = *(const bf16x8*)(lKc + kr * 128 + ((kk * 64 + laneK2) ^ ((kr & 7) << 4)));
            }
#pragma unroll
            for (int cb = 0; cb < 4; ++cb)
                s[cb] = MFMA16(qf[kk], kf[cb], s[cb]);
        }

        // online softmax; P -> LDS (bf16, swizzled; wave-private rows)
        {
            float tm[4];
#pragma unroll
            for (int r = 0; r < 4; ++r) {
                float v = fmaxf(fmaxf(s[0][r], s[1][r]), fmaxf(s[2][r], s[3][r])) * scale;
#pragma unroll
                for (int msk = 1; msk < 16; msk <<= 1) v = fmaxf(v, __shfl_xor(v, msk, 64));
                tm[r] = v;
            }
            float corr[4], mn[4], rs[4];
#pragma unroll
            for (int r = 0; r < 4; ++r) {
                mn[r] = fmaxf(mrun[r], tm[r]);
                corr[r] = __expf(mrun[r] - mn[r]);
                mrun[r] = mn[r];
                rs[r] = 0.f;
            }
#pragma unroll
            for (int cb2 = 0; cb2 < 4; ++cb2) {
                int pcol = cb2 * 16 + laneRC;
#pragma unroll
                for (int r = 0; r < 4; ++r) {
                    float pv = __expf(s[cb2][r] * scale - mn[r]);
                    rs[r] += pv;
                    int prow = wave * 16 + ((lane >> 4) << 2) + r;
                    *(u16*)((char*)lP + prow * 128 + ((pcol * 2) ^ ((prow & 7) << 4))) = f2bf(pv);
                }
            }
#pragma unroll
            for (int r = 0; r < 4; ++r) {
#pragma unroll
                for (int msk = 1; msk < 16; msk <<= 1) rs[r] += __shfl_xor(rs[r], msk, 64);
                lrun[r] = lrun[r] * corr[r] + rs[r];
            }
#pragma unroll
            for (int dc = 0; dc < 4; ++dc)
#pragma unroll
                for (int r = 0; r < 4; ++r) oacc[dc][r] *= corr[r];
        }

        // O += P @ V
#pragma unroll
        for (int kk = 0; kk < 2; ++kk) {
            bf16x8 pf, vf[4];
            {
                int pr = wave * 16 + laneRC;
                pf = *(const bf16x8*)((const char*)lP + pr * 128 + ((kk * 64 + laneK2) ^ ((pr & 7) << 4)));
            }
#pragma unroll
            for (int dc = 0; dc < 4; ++dc) {
                int d = dc * 16 + laneRC;
                vf[dc] = *(const bf16x8*)(lVc + d * 128 + ((kk * 64 + laneK2) ^ ((d & 7) << 4)));
            }
#pragma unroll
            for (int dc = 0; dc < 4; ++dc)
                oacc[dc] = MFMA16(pf, vf[dc], oacc[dc]);
        }
        vA0 = vB0; vA1 = vB1;
    }
#undef STAGEK

#pragma unroll
    for (int dc = 0; dc < 4; ++dc)
#pragma unroll
        for (int r = 0; r < 4; ++r) {
            long row = (long)b * 2048 + q0 + wave * 16 + ((lane >> 4) << 2) + r;
            int col = h * 64 + dc * 16 + laneRC;
            outb[row * 768 + col] = f2bf(oacc[dc][r] / lrun[r]);
        }
}

// ---------------------------------------------------------------------------
// fused residual-add + LayerNorm; wave-per-row, float4 loads, no LDS reduce
// ---------------------------------------------------------------------------
__global__ __launch_bounds__(256) void ln_fused(
    const float* __restrict__ a, const float* __restrict__ bres,
    const float* __restrict__ g, const float* __restrict__ be,
    float* __restrict__ outf, u16* __restrict__ outb)
{
    const int wave = threadIdx.x >> 6, lane = threadIdx.x & 63;
    const int row = blockIdx.x * 4 + wave;
    const size_t rbase = (size_t)row * 768;
    float4 v[3];
    float s1 = 0.f, s2 = 0.f;
#pragma unroll
    for (int i = 0; i < 3; ++i) {
        const int c = lane * 4 + i * 256;
        float4 x = *(const float4*)(a + rbase + c);
        if (bres) {
            const float4 y = *(const float4*)(bres + rbase + c);
            x.x += y.x; x.y += y.y; x.z += y.z; x.w += y.w;
        }
        v[i] = x;
        s1 += x.x + x.y + x.z + x.w;
        s2 += x.x * x.x + x.y * x.y + x.z * x.z + x.w * x.w;
    }
#pragma unroll
    for (int m = 1; m < 64; m <<= 1) { s1 += __shfl_xor(s1, m, 64); s2 += __shfl_xor(s2, m, 64); }
    const float mean = s1 * (1.f / 768.f);
    const float var  = s2 * (1.f / 768.f) - mean * mean;
    const float rstd = rsqrtf(var + 1e-5f);
#pragma unroll
    for (int i = 0; i < 3; ++i) {
        const int c = lane * 4 + i * 256;
        const float4 gg = *(const float4*)(g + c);
        const float4 bb = *(const float4*)(be + c);
        float4 y;
        y.x = (v[i].x - mean) * rstd * gg.x + bb.x;
        y.y = (v[i].y - mean) * rstd * gg.y + bb.y;
        y.z = (v[i].z - mean) * rstd * gg.z + bb.z;
        y.w = (v[i].w - mean) * rstd * gg.w + bb.w;
        if (outf) *(float4*)(outf + rbase + c) = y;
        ushort4 u; u.x = f2bf(y.x); u.y = f2bf(y.y); u.z = f2bf(y.z); u.w = f2bf(y.w);
        *(ushort4*)(outb + rbase + c) = u;
    }
}

// f32 [R][C] -> bf16 [C][R]
__global__ void transpose_cvt(const float* __restrict__ in, u16* __restrict__ out, int R, int C)
{
    __shared__ float t[32][33];
    const int c0 = blockIdx.x * 32, r0 = blockIdx.y * 32;
    const int tx = threadIdx.x, ty = threadIdx.y;
#pragma unroll
    for (int i = 0; i < 4; ++i)
        t[ty + 8 * i][tx] = in[(size_t)(r0 + ty + 8 * i) * C + c0 + tx];
    __syncthreads();
#pragma unroll
    for (int i = 0; i < 4; ++i)
        out[(size_t)(c0 + ty + 8 * i) * R + r0 + tx] = f2bf(t[tx][ty + 8 * i]);
}

__global__ void cvt_bf16_k(const float* __restrict__ in, u16* __restrict__ out, long n)
{
    long i = ((long)blockIdx.x * 256 + threadIdx.x) * 4;
    if (i >= n) return;
    const float4 f = *(const float4*)(in + i);
    ushort4 u; u.x = f2bf(f.x); u.y = f2bf(f.y); u.z = f2bf(f.z); u.w = f2bf(f.w);
    *(ushort4*)(out + i) = u;
}

__global__ void concat_bias(const float* __restrict__ bq, const float* __restrict__ bk,
                            const float* __restrict__ bv, float* __restrict__ out, int total)
{
    int i = blockIdx.x * 256 + threadIdx.x;
    if (i >= total) return;
    int l = i / 2304, j = i - l * 2304;
    float v = (j < 768) ? bq[l * 768 + j]
            : (j < 1536) ? bk[l * 768 + j - 768]
            : bv[l * 768 + j - 1536];
    out[i] = v;
}

__global__ __launch_bounds__(256) void embed_pe(
    const int* __restrict__ ids, const float* __restrict__ table,
    float* __restrict__ xf, u16* __restrict__ xb)
{
    const int idx = blockIdx.x * 256 + threadIdx.x;
    const int row = idx / 768, d = idx - row * 768;
    const int s = row & 2047;
    const float e = table[(long)ids[row] * 768 + d];
    const int j = d >> 1;
    const float ang = (float)s * __expf(-0.011992630692677324f * (float)(4 * j));
    const float pe = (d & 1) ? __cosf(ang) : __sinf(ang);
    const float v = e + pe;
    xf[idx] = v;
    xb[idx] = f2bf(v);
}

// ---------------------------------------------------------------------------
extern "C" void kernel_launch(void* const* d_in, const int* in_sizes, int n_in,
                              void* d_out, int out_size, void* d_ws, size_t ws_size,
                              hipStream_t stream)
{
    const int S = 2048, D = 768, H = 12, L = 2, V = 32000, DF = 3072, M = 4096, NQKV = 2304;
    (void)in_sizes; (void)n_in; (void)out_size; (void)ws_size; (void)H; (void)S;

    const int*   ids  = (const int*)  d_in[0];
    const float* emb  = (const float*)d_in[1];
    const float* Wq   = (const float*)d_in[2];
    const float* bq   = (const float*)d_in[3];
    const float* Wk   = (const float*)d_in[4];
    const float* bk   = (const float*)d_in[5];
    const float* Wv   = (const float*)d_in[6];
    const float* bv   = (const float*)d_in[7];
    const float* Wo   = (const float*)d_in[8];
    const float* bo   = (const float*)d_in[9];
    const float* ln1g = (const float*)d_in[10];
    const float* ln1b = (const float*)d_in[11];
    const float* W1   = (const float*)d_in[12];
    const float* b1   = (const float*)d_in[13];
    const float* W2   = (const float*)d_in[14];
    const float* b2   = (const float*)d_in[15];
    const float* ln2g = (const float*)d_in[16];
    const float* ln2b = (const float*)d_in[17];
    const float* Wd   = (const float*)d_in[18];
    const float* bd   = (const float*)d_in[19];
    const float* lnmg = (const float*)d_in[20];
    const float* lnmb = (const float*)d_in[21];
    const float* decb = (const float*)d_in[22];

    char* p = (char*)d_ws;
    auto carve = [&](size_t bytes) { char* r = p; p += (bytes + 255) & ~(size_t)255; return r; };
    u16*   embB  = (u16*)  carve((size_t)V * D * 2);
    u16*   wqkvT = (u16*)  carve((size_t)L * NQKV * D * 2);
    float* bqkv  = (float*)carve((size_t)L * NQKV * 4);
    u16*   woT   = (u16*)  carve((size_t)L * D * D * 2);
    u16*   w1T   = (u16*)  carve((size_t)L * DF * D * 2);
    u16*   w2T   = (u16*)  carve((size_t)L * D * DF * 2);
    u16*   wdT   = (u16*)  carve((size_t)D * D * 2);
    float* xf    = (float*)carve((size_t)M * D * 4);
    u16*   xb    = (u16*)  carve((size_t)M * D * 2);
    u16*   qkvB  = (u16*)  carve((size_t)M * NQKV * 2);
    u16*   aoB   = (u16*)  carve((size_t)M * D * 2);
    float* tmpf  = (float*)carve((size_t)M * D * 4);
    u16*   hB    = (u16*)  carve((size_t)M * DF * 2);

    dim3 t32x8(32, 8);
    cvt_bf16_k<<<((long)V * D / 4 + 255) / 256, 256, 0, stream>>>(emb, embB, (long)V * D);
    for (int l = 0; l < L; ++l) {
        transpose_cvt<<<dim3(24, 24), t32x8, 0, stream>>>(Wq + (size_t)l * D * D, wqkvT + (size_t)l * NQKV * D,                    D, D);
        transpose_cvt<<<dim3(24, 24), t32x8, 0, stream>>>(Wk + (size_t)l * D * D, wqkvT + (size_t)l * NQKV * D + (size_t)D * D,    D, D);
        transpose_cvt<<<dim3(24, 24), t32x8, 0, stream>>>(Wv + (size_t)l * D * D, wqkvT + (size_t)l * NQKV * D + (size_t)2 * D * D, D, D);
        transpose_cvt<<<dim3(24, 24), t32x8, 0, stream>>>(Wo + (size_t)l * D * D, woT + (size_t)l * D * D, D, D);
        transpose_cvt<<<dim3(96, 24), t32x8, 0, stream>>>(W1 + (size_t)l * D * DF, w1T + (size_t)l * DF * D, D, DF);
        transpose_cvt<<<dim3(24, 96), t32x8, 0, stream>>>(W2 + (size_t)l * DF * D, w2T + (size_t)l * D * DF, DF, D);
    }
    transpose_cvt<<<dim3(24, 24), t32x8, 0, stream>>>(Wd, wdT, D, D);
    concat_bias<<<(L * NQKV + 255) / 256, 256, 0, stream>>>(bq, bk, bv, bqkv, L * NQKV);
    embed_pe<<<M * D / 256, 256, 0, stream>>>(ids, emb, xf, xb);

    const float scale = 0.036084391824351615f;  // 1/sqrt(768)
    for (int l = 0; l < L; ++l) {
        gemm_bf16<0, 0><<<dim3(NQKV / 128, M / 128), 256, 0, stream>>>(xb, wqkvT + (size_t)l * NQKV * D, bqkv + l * NQKV, qkvB, NQKV, D);
        attn_fwd<<<dim3(24, 32), 256, 0, stream>>>(qkvB, aoB, scale);
        gemm_bf16<0, 1><<<dim3(D / 128, M / 128), 256, 0, stream>>>(aoB, woT + (size_t)l * D * D, bo + l * D, tmpf, D, D);
        ln_fused<<<M / 4, 256, 0, stream>>>(xf, tmpf, ln1g + l * D, ln1b + l * D, xf, xb);
        gemm_bf16<1, 0><<<dim3(DF / 128, M / 128), 256, 0, stream>>>(xb, w1T + (size_t)l * DF * D, b1 + l * DF, hB, DF, D);
        gemm_bf16<0, 1><<<dim3(D / 128, M / 128), 256, 0, stream>>>(hB, w2T + (size_t)l * D * DF, b2 + l * D, tmpf, D, DF);
        ln_fused<<<M / 4, 256, 0, stream>>>(xf, tmpf, ln2g + l * D, ln2b + l * D, xf, xb);
    }
    gemm_bf16<1, 1><<<dim3(D / 128, M / 128), 256, 0, stream>>>(xb, wdT, bd, tmpf, D, D);
    ln_fused<<<M / 4, 256, 0, stream>>>(tmpf, nullptr, lnmg, lnmb, nullptr, aoB);
    gemm_bf16<0, 1><<<dim3(V / 128, M / 128), 256, 0, stream>>>(aoB, embB, decb, (float*)d_out, V, D);
}

// Round 6
// 818.513 us; speedup vs baseline: 1.2420x; 1.1030x over previous
//
#include <hip/hip_runtime.h>
#include <hip/hip_bf16.h>
#include <cstdint>

typedef __bf16 bf16x8 __attribute__((ext_vector_type(8)));
typedef float  f32x4  __attribute__((ext_vector_type(4)));
typedef unsigned short u16;
typedef u16 u16x8 __attribute__((ext_vector_type(8)));

__device__ __forceinline__ u16 f2bf(float f) {
    union { float f; uint32_t u; } x{f};
    uint32_t u = x.u;
    return (u16)((u + 0x7fffu + ((u >> 16) & 1u)) >> 16);
}

__device__ __forceinline__ float gelu_f(float x) {
    return 0.5f * x * (1.0f + erff(x * 0.70710678118654752f));
}

// async global->LDS, 16B per lane; LDS dest is wave-uniform base + lane*16
__device__ __forceinline__ void gl_lds16(const void* g, void* l) {
    __builtin_amdgcn_global_load_lds(
        (__attribute__((address_space(1))) void*)(void*)g,
        (__attribute__((address_space(3))) void*)l, 16, 0, 0);
}

#define MFMA16(a, b, c) __builtin_amdgcn_mfma_f32_16x16x32_bf16((a), (b), (c), 0, 0, 0)
#define SB0 __builtin_amdgcn_sched_barrier(0)

// ---------------------------------------------------------------------------
// 128x128 GEMM, BK=64, 4 waves (2x2), single-buffered (r1 structure — measured
// best of the structures tried). LOC=1: linear grid remapped into chunks of
// 32 rows x 16 cols so the ~768-block concurrency window has 2-D locality
// (B panel stays L3-resident across row-blocks; fetch 798MB -> ~150MB ideal).
// ---------------------------------------------------------------------------
template<int EPI, int OUTF32, int LOC>
__global__ __launch_bounds__(256, 2) void gemm_bf16(
    const u16* __restrict__ A, const u16* __restrict__ Bt,
    const float* __restrict__ bias, void* __restrict__ Cout,
    int N_, int K_)
{
    __shared__ u16 lA[128 * 64];
    __shared__ u16 lB[128 * 64];
    const int tid  = threadIdx.x;
    const int lane = tid & 63;
    const int wave = tid >> 6;
    const int wr = wave >> 1, wc = wave & 1;
    long row0, col0;
    if (LOC) {   // linear grid: chunk = 512 blocks = 32 rows x 16 cols, row fastest
        const int bid = blockIdx.x;
        const int chunk = bid >> 9, rem = bid & 511;
        row0 = (long)(rem & 31) * 128;
        col0 = (long)(chunk * 16 + (rem >> 5)) * 128;
    } else {
        row0 = (long)blockIdx.y * 128;
        col0 = (long)blockIdx.x * 128;
    }

    f32x4 acc[4][4];
#pragma unroll
    for (int i = 0; i < 4; ++i)
#pragma unroll
        for (int j = 0; j < 4; ++j)
#pragma unroll
            for (int t = 0; t < 4; ++t) acc[i][j][t] = 0.f;

    int sRow[4], sKb[4];
#pragma unroll
    for (int t = 0; t < 4; ++t) {
        int byteoff = (wave * 4 + t) * 1024 + lane * 16;
        int r = byteoff >> 7;
        sRow[t] = r;
        sKb[t]  = (byteoff & 127) ^ ((r & 7) << 4);
    }
    const int laneRC = lane & 15;
    const int laneK2 = (lane >> 4) * 16;

    for (int k0 = 0; k0 < K_; k0 += 64) {
#pragma unroll
        for (int t = 0; t < 4; ++t) {
            const int cb = (wave * 4 + t) * 1024;
            gl_lds16(A  + (row0 + sRow[t]) * K_ + k0 + (sKb[t] >> 1), (char*)lA + cb);
            gl_lds16(Bt + (col0 + sRow[t]) * K_ + k0 + (sKb[t] >> 1), (char*)lB + cb);
        }
        __syncthreads();
#pragma unroll
        for (int kk = 0; kk < 2; ++kk) {
            bf16x8 af[4], bfr[4];
#pragma unroll
            for (int i = 0; i < 4; ++i) {
                int r = wr * 64 + i * 16 + laneRC;
                af[i] = *(const bf16x8*)((const char*)lA + r * 128 + ((kk * 64 + laneK2) ^ ((r & 7) << 4)));
            }
#pragma unroll
            for (int j = 0; j < 4; ++j) {
                int n = wc * 64 + j * 16 + laneRC;
                bfr[j] = *(const bf16x8*)((const char*)lB + n * 128 + ((kk * 64 + laneK2) ^ ((n & 7) << 4)));
            }
#pragma unroll
            for (int i = 0; i < 4; ++i)
#pragma unroll
                for (int j = 0; j < 4; ++j)
                    acc[i][j] = MFMA16(af[i], bfr[j], acc[i][j]);
        }
        __syncthreads();
    }

#pragma unroll
    for (int j = 0; j < 4; ++j) {
        const long cidx = col0 + wc * 64 + j * 16 + laneRC;
        const float bvv = bias[cidx];
#pragma unroll
        for (int i = 0; i < 4; ++i) {
            const long rbase = row0 + wr * 64 + i * 16 + ((lane >> 4) << 2);
#pragma unroll
            for (int t = 0; t < 4; ++t) {
                float v = acc[i][j][t] + bvv;
                if (EPI) v = gelu_f(v);
                const long off = (rbase + t) * N_ + cidx;
                if (OUTF32) ((float*)Cout)[off] = v;
                else        ((u16*)Cout)[off]  = f2bf(v);
            }
        }
    }
}

// ---------------------------------------------------------------------------
// 64x64 GEMM, BK=64, 4 waves (2x2, wave-tile 32x32), 16 KiB LDS, 4 blocks/CU.
// For N=768 GEMMs (o-proj, FFN2, head): 128-tile grid was 192 blocks on
// 256 CUs (grid-starved); this gives 768 blocks.
// ---------------------------------------------------------------------------
template<int EPI, int OUTF32>
__global__ __launch_bounds__(256, 4) void gemm64(
    const u16* __restrict__ A, const u16* __restrict__ Bt,
    const float* __restrict__ bias, void* __restrict__ Cout,
    int N_, int K_)
{
    __shared__ u16 lA[64 * 64];
    __shared__ u16 lB[64 * 64];
    const int tid  = threadIdx.x;
    const int lane = tid & 63;
    const int wave = tid >> 6;
    const int wr = wave >> 1, wc = wave & 1;
    const long row0 = (long)blockIdx.y * 64;
    const long col0 = (long)blockIdx.x * 64;

    f32x4 acc[2][2];
#pragma unroll
    for (int i = 0; i < 2; ++i)
#pragma unroll
        for (int j = 0; j < 2; ++j)
#pragma unroll
            for (int t = 0; t < 4; ++t) acc[i][j][t] = 0.f;

    int sRow[2], sKb[2];
#pragma unroll
    for (int t = 0; t < 2; ++t) {
        int byteoff = (wave * 2 + t) * 1024 + lane * 16;
        int r = byteoff >> 7;
        sRow[t] = r;
        sKb[t]  = (byteoff & 127) ^ ((r & 7) << 4);
    }
    const int laneRC = lane & 15;
    const int laneK2 = (lane >> 4) * 16;

    for (int k0 = 0; k0 < K_; k0 += 64) {
#pragma unroll
        for (int t = 0; t < 2; ++t) {
            const int cb = (wave * 2 + t) * 1024;
            gl_lds16(A  + (row0 + sRow[t]) * K_ + k0 + (sKb[t] >> 1), (char*)lA + cb);
            gl_lds16(Bt + (col0 + sRow[t]) * K_ + k0 + (sKb[t] >> 1), (char*)lB + cb);
        }
        __syncthreads();
#pragma unroll
        for (int kk = 0; kk < 2; ++kk) {
            bf16x8 af[2], bfr[2];
#pragma unroll
            for (int i = 0; i < 2; ++i) {
                int r = wr * 32 + i * 16 + laneRC;
                af[i] = *(const bf16x8*)((const char*)lA + r * 128 + ((kk * 64 + laneK2) ^ ((r & 7) << 4)));
            }
#pragma unroll
            for (int j = 0; j < 2; ++j) {
                int n = wc * 32 + j * 16 + laneRC;
                bfr[j] = *(const bf16x8*)((const char*)lB + n * 128 + ((kk * 64 + laneK2) ^ ((n & 7) << 4)));
            }
#pragma unroll
            for (int i = 0; i < 2; ++i)
#pragma unroll
                for (int j = 0; j < 2; ++j)
                    acc[i][j] = MFMA16(af[i], bfr[j], acc[i][j]);
        }
        __syncthreads();
    }

#pragma unroll
    for (int j = 0; j < 2; ++j) {
        const long cidx = col0 + wc * 32 + j * 16 + laneRC;
        const float bvv = bias[cidx];
#pragma unroll
        for (int i = 0; i < 2; ++i) {
            const long rbase = row0 + wr * 32 + i * 16 + ((lane >> 4) << 2);
#pragma unroll
            for (int t = 0; t < 4; ++t) {
                float v = acc[i][j][t] + bvv;
                if (EPI) v = gelu_f(v);
                const long off = (rbase + t) * N_ + cidx;
                if (OUTF32) ((float*)Cout)[off] = v;
                else        ((u16*)Cout)[off]  = f2bf(v);
            }
        }
    }
}

// ---------------------------------------------------------------------------
// Flash attention, pipelined (r5 structure): qkv [4096][2304] bf16.
// QB=64 (grid 768), 4 waves x 16 q-rows, KB=64, dbuf K/V LDS, 1 barrier/tile.
// ---------------------------------------------------------------------------
__global__ __launch_bounds__(256, 3) void attn_fwd(
    const u16* __restrict__ qkv, u16* __restrict__ outb, float scale)
{
    __shared__ u16 lQ[64 * 64];
    __shared__ u16 lK[2][64 * 64];
    __shared__ u16 lVt[2][64 * 64];
    __shared__ u16 lP[64 * 64];
    const int bh = blockIdx.x;           // b*12 + h
    const int b = bh / 12, h = bh % 12;
    const int q0 = blockIdx.y * 64;
    const int tid = threadIdx.x, lane = tid & 63, wave = tid >> 6;
    const long baseQ = (long)b * 2048 * 2304 + h * 64;
    const long baseK = baseQ + 768;
    const long baseV = baseQ + 1536;
    const int laneRC = lane & 15;
    const int laneK2 = (lane >> 4) * 16;

    int stR[2], stC[2];
#pragma unroll
    for (int t = 0; t < 2; ++t) {
        const int byteoff = (wave * 2 + t) * 1024 + lane * 16;
        const int r = byteoff >> 7;
        stR[t] = r;
        stC[t] = ((byteoff & 127) ^ ((r & 7) << 4)) >> 1;
    }

#define STAGEK(BUF, KB0) do {                                                    \
    _Pragma("unroll") for (int t = 0; t < 2; ++t)                                \
        gl_lds16(qkv + baseK + (long)((KB0) + stR[t]) * 2304 + stC[t],           \
                 (char*)lK[BUF] + (wave * 2 + t) * 1024);                        \
} while (0)

#pragma unroll
    for (int t = 0; t < 2; ++t)
        gl_lds16(qkv + baseQ + (long)(q0 + stR[t]) * 2304 + stC[t],
                 (char*)lQ + (wave * 2 + t) * 1024);
    STAGEK(0, 0);
    u16x8 vA0, vA1;
    {
        const u16x8* gv = (const u16x8*)(qkv + baseV + (long)lane * 2304 + wave * 16);
        vA0 = gv[0]; vA1 = gv[1];
    }
    __syncthreads();

    bf16x8 qf[2];
#pragma unroll
    for (int kk = 0; kk < 2; ++kk) {
        int r = wave * 16 + laneRC;
        qf[kk] = *(const bf16x8*)((const char*)lQ + r * 128 + ((kk * 64 + laneK2) ^ ((r & 7) << 4)));
    }

    float mrun[4], lrun[4];
    f32x4 oacc[4];
#pragma unroll
    for (int r = 0; r < 4; ++r) { mrun[r] = -1e30f; lrun[r] = 0.f; }
#pragma unroll
    for (int dc = 0; dc < 4; ++dc)
#pragma unroll
        for (int t = 0; t < 4; ++t) oacc[dc][t] = 0.f;

    u16x8 vB0 = vA0, vB1 = vA1;
    for (int kt = 0; kt < 32; ++kt) {
        const int cur = kt & 1;
        asm volatile("s_waitcnt vmcnt(0)" ::: "memory");
        SB0;
        {
            const int kv = lane, dg = wave;
            char* vt = (char*)lVt[cur];
#pragma unroll
            for (int j = 0; j < 8; ++j) {
                int d0 = dg * 16 + j;
                *(u16*)(vt + d0 * 128 + ((kv * 2) ^ ((d0 & 7) << 4))) = vA0[j];
                int d1 = dg * 16 + 8 + j;
                *(u16*)(vt + d1 * 128 + ((kv * 2) ^ ((d1 & 7) << 4))) = vA1[j];
            }
        }
        __builtin_amdgcn_s_barrier();
        SB0;
        if (kt + 1 < 32) {
            STAGEK(cur ^ 1, (kt + 1) * 64);
            const u16x8* gv = (const u16x8*)(qkv + baseV + (long)((kt + 1) * 64 + lane) * 2304 + wave * 16);
            vB0 = gv[0]; vB1 = gv[1];
        }
        const char* lKc = (const char*)lK[cur];
        const char* lVc = (const char*)lVt[cur];

        f32x4 s[4];
#pragma unroll
        for (int cb = 0; cb < 4; ++cb)
#pragma unroll
            for (int t = 0; t < 4; ++t) s[cb][t] = 0.f;
#pragma unroll
        for (int kk = 0; kk < 2; ++kk) {
            bf16x8 kf[4];
#pragma unroll
            for (int cb = 0; cb < 4; ++cb) {
                int kr = cb * 16 + laneRC;
                kf[cb] = *(const bf16x8*)(lKc + kr * 128 + ((kk * 64 + laneK2) ^ ((kr & 7) << 4)));
            }
#pragma unroll
            for (int cb = 0; cb < 4; ++cb)
                s[cb] = MFMA16(qf[kk], kf[cb], s[cb]);
        }

        {
            float tm[4];
#pragma unroll
            for (int r = 0; r < 4; ++r) {
                float v = fmaxf(fmaxf(s[0][r], s[1][r]), fmaxf(s[2][r], s[3][r])) * scale;
#pragma unroll
                for (int msk = 1; msk < 16; msk <<= 1) v = fmaxf(v, __shfl_xor(v, msk, 64));
                tm[r] = v;
            }
            float corr[4], mn[4], rs[4];
#pragma unroll
            for (int r = 0; r < 4; ++r) {
                mn[r] = fmaxf(mrun[r], tm[r]);
                corr[r] = __expf(mrun[r] - mn[r]);
                mrun[r] = mn[r];
                rs[r] = 0.f;
            }
#pragma unroll
            for (int cb2 = 0; cb2 < 4; ++cb2) {
                int pcol = cb2 * 16 + laneRC;
#pragma unroll
                for (int r = 0; r < 4; ++r) {
                    float pv = __expf(s[cb2][r] * scale - mn[r]);
                    rs[r] += pv;
                    int prow = wave * 16 + ((lane >> 4) << 2) + r;
                    *(u16*)((char*)lP + prow * 128 + ((pcol * 2) ^ ((prow & 7) << 4))) = f2bf(pv);
                }
            }
#pragma unroll
            for (int r = 0; r < 4; ++r) {
#pragma unroll
                for (int msk = 1; msk < 16; msk <<= 1) rs[r] += __shfl_xor(rs[r], msk, 64);
                lrun[r] = lrun[r] * corr[r] + rs[r];
            }
#pragma unroll
            for (int dc = 0; dc < 4; ++dc)
#pragma unroll
                for (int r = 0; r < 4; ++r) oacc[dc][r] *= corr[r];
        }

#pragma unroll
        for (int kk = 0; kk < 2; ++kk) {
            bf16x8 pf, vf[4];
            {
                int pr = wave * 16 + laneRC;
                pf = *(const bf16x8*)((const char*)lP + pr * 128 + ((kk * 64 + laneK2) ^ ((pr & 7) << 4)));
            }
#pragma unroll
            for (int dc = 0; dc < 4; ++dc) {
                int d = dc * 16 + laneRC;
                vf[dc] = *(const bf16x8*)(lVc + d * 128 + ((kk * 64 + laneK2) ^ ((d & 7) << 4)));
            }
#pragma unroll
            for (int dc = 0; dc < 4; ++dc)
                oacc[dc] = MFMA16(pf, vf[dc], oacc[dc]);
        }
        vA0 = vB0; vA1 = vB1;
    }
#undef STAGEK

#pragma unroll
    for (int dc = 0; dc < 4; ++dc)
#pragma unroll
        for (int r = 0; r < 4; ++r) {
            long row = (long)b * 2048 + q0 + wave * 16 + ((lane >> 4) << 2) + r;
            int col = h * 64 + dc * 16 + laneRC;
            outb[row * 768 + col] = f2bf(oacc[dc][r] / lrun[r]);
        }
}

// ---------------------------------------------------------------------------
// fused residual-add + LayerNorm; wave-per-row, float4 loads
// ---------------------------------------------------------------------------
__global__ __launch_bounds__(256) void ln_fused(
    const float* __restrict__ a, const float* __restrict__ bres,
    const float* __restrict__ g, const float* __restrict__ be,
    float* __restrict__ outf, u16* __restrict__ outb)
{
    const int wave = threadIdx.x >> 6, lane = threadIdx.x & 63;
    const int row = blockIdx.x * 4 + wave;
    const size_t rbase = (size_t)row * 768;
    float4 v[3];
    float s1 = 0.f, s2 = 0.f;
#pragma unroll
    for (int i = 0; i < 3; ++i) {
        const int c = lane * 4 + i * 256;
        float4 x = *(const float4*)(a + rbase + c);
        if (bres) {
            const float4 y = *(const float4*)(bres + rbase + c);
            x.x += y.x; x.y += y.y; x.z += y.z; x.w += y.w;
        }
        v[i] = x;
        s1 += x.x + x.y + x.z + x.w;
        s2 += x.x * x.x + x.y * x.y + x.z * x.z + x.w * x.w;
    }
#pragma unroll
    for (int m = 1; m < 64; m <<= 1) { s1 += __shfl_xor(s1, m, 64); s2 += __shfl_xor(s2, m, 64); }
    const float mean = s1 * (1.f / 768.f);
    const float var  = s2 * (1.f / 768.f) - mean * mean;
    const float rstd = rsqrtf(var + 1e-5f);
#pragma unroll
    for (int i = 0; i < 3; ++i) {
        const int c = lane * 4 + i * 256;
        const float4 gg = *(const float4*)(g + c);
        const float4 bb = *(const float4*)(be + c);
        float4 y;
        y.x = (v[i].x - mean) * rstd * gg.x + bb.x;
        y.y = (v[i].y - mean) * rstd * gg.y + bb.y;
        y.z = (v[i].z - mean) * rstd * gg.z + bb.z;
        y.w = (v[i].w - mean) * rstd * gg.w + bb.w;
        if (outf) *(float4*)(outf + rbase + c) = y;
        ushort4 u; u.x = f2bf(y.x); u.y = f2bf(y.y); u.z = f2bf(y.z); u.w = f2bf(y.w);
        *(ushort4*)(outb + rbase + c) = u;
    }
}

// f32 [R][C] -> bf16 [C][R]
__global__ void transpose_cvt(const float* __restrict__ in, u16* __restrict__ out, int R, int C)
{
    __shared__ float t[32][33];
    const int c0 = blockIdx.x * 32, r0 = blockIdx.y * 32;
    const int tx = threadIdx.x, ty = threadIdx.y;
#pragma unroll
    for (int i = 0; i < 4; ++i)
        t[ty + 8 * i][tx] = in[(size_t)(r0 + ty + 8 * i) * C + c0 + tx];
    __syncthreads();
#pragma unroll
    for (int i = 0; i < 4; ++i)
        out[(size_t)(c0 + ty + 8 * i) * R + r0 + tx] = f2bf(t[tx][ty + 8 * i]);
}

__global__ void cvt_bf16_k(const float* __restrict__ in, u16* __restrict__ out, long n)
{
    long i = ((long)blockIdx.x * 256 + threadIdx.x) * 4;
    if (i >= n) return;
    const float4 f = *(const float4*)(in + i);
    ushort4 u; u.x = f2bf(f.x); u.y = f2bf(f.y); u.z = f2bf(f.z); u.w = f2bf(f.w);
    *(ushort4*)(out + i) = u;
}

__global__ void concat_bias(const float* __restrict__ bq, const float* __restrict__ bk,
                            const float* __restrict__ bv, float* __restrict__ out, int total)
{
    int i = blockIdx.x * 256 + threadIdx.x;
    if (i >= total) return;
    int l = i / 2304, j = i - l * 2304;
    float v = (j < 768) ? bq[l * 768 + j]
            : (j < 1536) ? bk[l * 768 + j - 768]
            : bv[l * 768 + j - 1536];
    out[i] = v;
}

__global__ __launch_bounds__(256) void embed_pe(
    const int* __restrict__ ids, const float* __restrict__ table,
    float* __restrict__ xf, u16* __restrict__ xb)
{
    const int idx = blockIdx.x * 256 + threadIdx.x;
    const int row = idx / 768, d = idx - row * 768;
    const int s = row & 2047;
    const float e = table[(long)ids[row] * 768 + d];
    const int j = d >> 1;
    const float ang = (float)s * __expf(-0.011992630692677324f * (float)(4 * j));
    const float pe = (d & 1) ? __cosf(ang) : __sinf(ang);
    const float v = e + pe;
    xf[idx] = v;
    xb[idx] = f2bf(v);
}

// ---------------------------------------------------------------------------
extern "C" void kernel_launch(void* const* d_in, const int* in_sizes, int n_in,
                              void* d_out, int out_size, void* d_ws, size_t ws_size,
                              hipStream_t stream)
{
    const int S = 2048, D = 768, H = 12, L = 2, V = 32000, DF = 3072, M = 4096, NQKV = 2304;
    (void)in_sizes; (void)n_in; (void)out_size; (void)ws_size; (void)H; (void)S;

    const int*   ids  = (const int*)  d_in[0];
    const float* emb  = (const float*)d_in[1];
    const float* Wq   = (const float*)d_in[2];
    const float* bq   = (const float*)d_in[3];
    const float* Wk   = (const float*)d_in[4];
    const float* bk   = (const float*)d_in[5];
    const float* Wv   = (const float*)d_in[6];
    const float* bv   = (const float*)d_in[7];
    const float* Wo   = (const float*)d_in[8];
    const float* bo   = (const float*)d_in[9];
    const float* ln1g = (const float*)d_in[10];
    const float* ln1b = (const float*)d_in[11];
    const float* W1   = (const float*)d_in[12];
    const float* b1   = (const float*)d_in[13];
    const float* W2   = (const float*)d_in[14];
    const float* b2   = (const float*)d_in[15];
    const float* ln2g = (const float*)d_in[16];
    const float* ln2b = (const float*)d_in[17];
    const float* Wd   = (const float*)d_in[18];
    const float* bd   = (const float*)d_in[19];
    const float* lnmg = (const float*)d_in[20];
    const float* lnmb = (const float*)d_in[21];
    const float* decb = (const float*)d_in[22];

    char* p = (char*)d_ws;
    auto carve = [&](size_t bytes) { char* r = p; p += (bytes + 255) & ~(size_t)255; return r; };
    u16*   embB  = (u16*)  carve((size_t)V * D * 2);
    u16*   wqkvT = (u16*)  carve((size_t)L * NQKV * D * 2);
    float* bqkv  = (float*)carve((size_t)L * NQKV * 4);
    u16*   woT   = (u16*)  carve((size_t)L * D * D * 2);
    u16*   w1T   = (u16*)  carve((size_t)L * DF * D * 2);
    u16*   w2T   = (u16*)  carve((size_t)L * D * DF * 2);
    u16*   wdT   = (u16*)  carve((size_t)D * D * 2);
    float* xf    = (float*)carve((size_t)M * D * 4);
    u16*   xb    = (u16*)  carve((size_t)M * D * 2);
    u16*   qkvB  = (u16*)  carve((size_t)M * NQKV * 2);
    u16*   aoB   = (u16*)  carve((size_t)M * D * 2);
    float* tmpf  = (float*)carve((size_t)M * D * 4);
    u16*   hB    = (u16*)  carve((size_t)M * DF * 2);

    dim3 t32x8(32, 8);
    cvt_bf16_k<<<((long)V * D / 4 + 255) / 256, 256, 0, stream>>>(emb, embB, (long)V * D);
    for (int l = 0; l < L; ++l) {
        transpose_cvt<<<dim3(24, 24), t32x8, 0, stream>>>(Wq + (size_t)l * D * D, wqkvT + (size_t)l * NQKV * D,                    D, D);
        transpose_cvt<<<dim3(24, 24), t32x8, 0, stream>>>(Wk + (size_t)l * D * D, wqkvT + (size_t)l * NQKV * D + (size_t)D * D,    D, D);
        transpose_cvt<<<dim3(24, 24), t32x8, 0, stream>>>(Wv + (size_t)l * D * D, wqkvT + (size_t)l * NQKV * D + (size_t)2 * D * D, D, D);
        transpose_cvt<<<dim3(24, 24), t32x8, 0, stream>>>(Wo + (size_t)l * D * D, woT + (size_t)l * D * D, D, D);
        transpose_cvt<<<dim3(96, 24), t32x8, 0, stream>>>(W1 + (size_t)l * D * DF, w1T + (size_t)l * DF * D, D, DF);
        transpose_cvt<<<dim3(24, 96), t32x8, 0, stream>>>(W2 + (size_t)l * DF * D, w2T + (size_t)l * D * DF, DF, D);
    }
    transpose_cvt<<<dim3(24, 24), t32x8, 0, stream>>>(Wd, wdT, D, D);
    concat_bias<<<(L * NQKV + 255) / 256, 256, 0, stream>>>(bq, bk, bv, bqkv, L * NQKV);
    embed_pe<<<M * D / 256, 256, 0, stream>>>(ids, emb, xf, xb);

    const float scale = 0.036084391824351615f;  // 1/sqrt(768)
    for (int l = 0; l < L; ++l) {
        gemm_bf16<0, 0, 0><<<dim3(NQKV / 128, M / 128), 256, 0, stream>>>(xb, wqkvT + (size_t)l * NQKV * D, bqkv + l * NQKV, qkvB, NQKV, D);
        attn_fwd<<<dim3(24, 32), 256, 0, stream>>>(qkvB, aoB, scale);
        gemm64<0, 1><<<dim3(D / 64, M / 64), 256, 0, stream>>>(aoB, woT + (size_t)l * D * D, bo + l * D, tmpf, D, D);
        ln_fused<<<M / 4, 256, 0, stream>>>(xf, tmpf, ln1g + l * D, ln1b + l * D, xf, xb);
        gemm_bf16<1, 0, 0><<<dim3(DF / 128, M / 128), 256, 0, stream>>>(xb, w1T + (size_t)l * DF * D, b1 + l * DF, hB, DF, D);
        gemm64<0, 1><<<dim3(D / 64, M / 64), 256, 0, stream>>>(hB, w2T + (size_t)l * D * DF, b2 + l * D, tmpf, D, DF);
        ln_fused<<<M / 4, 256, 0, stream>>>(xf, tmpf, ln2g + l * D, ln2b + l * D, xf, xb);
    }
    gemm64<1, 1><<<dim3(D / 64, M / 64), 256, 0, stream>>>(xb, wdT, bd, tmpf, D, D);
    ln_fused<<<M / 4, 256, 0, stream>>>(tmpf, nullptr, lnmg, lnmb, nullptr, aoB);
    gemm_bf16<0, 1, 1><<<V / 128 * 32, 256, 0, stream>>>(aoB, embB, decb, (float*)d_out, V, D);
}

// Round 7
// 763.764 us; speedup vs baseline: 1.3310x; 1.0717x over previous
//
#include <hip/hip_runtime.h>
#include <hip/hip_bf16.h>
#include <cstdint>

typedef __bf16 bf16x8 __attribute__((ext_vector_type(8)));
typedef float  f32x4  __attribute__((ext_vector_type(4)));
typedef unsigned short u16;
typedef u16 u16x8 __attribute__((ext_vector_type(8)));

__device__ __forceinline__ u16 f2bf(float f) {
    union { float f; uint32_t u; } x{f};
    uint32_t u = x.u;
    return (u16)((u + 0x7fffu + ((u >> 16) & 1u)) >> 16);
}

__device__ __forceinline__ float gelu_f(float x) {
    return 0.5f * x * (1.0f + erff(x * 0.70710678118654752f));
}

// async global->LDS, 16B per lane; LDS dest is wave-uniform base + lane*16
__device__ __forceinline__ void gl_lds16(const void* g, void* l) {
    __builtin_amdgcn_global_load_lds(
        (__attribute__((address_space(1))) void*)(void*)g,
        (__attribute__((address_space(3))) void*)l, 16, 0, 0);
}

#define MFMA16(a, b, c) __builtin_amdgcn_mfma_f32_16x16x32_bf16((a), (b), (c), 0, 0, 0)
#define SB0 __builtin_amdgcn_sched_barrier(0)

// ---------------------------------------------------------------------------
// 128x128 GEMM, BK=64, 4 waves (2x2), single-buffered (r1 structure — measured
// best). LOC=1: linear grid remapped into chunks of 32 rows x 16 cols so the
// concurrency window has 2-D locality (decoder fetch 798MB -> L3-resident B).
// ---------------------------------------------------------------------------
template<int EPI, int OUTF32, int LOC>
__global__ __launch_bounds__(256, 2) void gemm_bf16(
    const u16* __restrict__ A, const u16* __restrict__ Bt,
    const float* __restrict__ bias, void* __restrict__ Cout,
    int N_, int K_)
{
    __shared__ u16 lA[128 * 64];
    __shared__ u16 lB[128 * 64];
    const int tid  = threadIdx.x;
    const int lane = tid & 63;
    const int wave = tid >> 6;
    const int wr = wave >> 1, wc = wave & 1;
    long row0, col0;
    if (LOC) {   // linear grid: chunk = 512 blocks = 32 rows x 16 cols, row fastest
        const int bid = blockIdx.x;
        const int chunk = bid >> 9, rem = bid & 511;
        row0 = (long)(rem & 31) * 128;
        col0 = (long)(chunk * 16 + (rem >> 5)) * 128;
    } else {
        row0 = (long)blockIdx.y * 128;
        col0 = (long)blockIdx.x * 128;
    }

    f32x4 acc[4][4];
#pragma unroll
    for (int i = 0; i < 4; ++i)
#pragma unroll
        for (int j = 0; j < 4; ++j)
#pragma unroll
            for (int t = 0; t < 4; ++t) acc[i][j][t] = 0.f;

    int sRow[4], sKb[4];
#pragma unroll
    for (int t = 0; t < 4; ++t) {
        int byteoff = (wave * 4 + t) * 1024 + lane * 16;
        int r = byteoff >> 7;
        sRow[t] = r;
        sKb[t]  = (byteoff & 127) ^ ((r & 7) << 4);
    }
    const int laneRC = lane & 15;
    const int laneK2 = (lane >> 4) * 16;

    for (int k0 = 0; k0 < K_; k0 += 64) {
#pragma unroll
        for (int t = 0; t < 4; ++t) {
            const int cb = (wave * 4 + t) * 1024;
            gl_lds16(A  + (row0 + sRow[t]) * K_ + k0 + (sKb[t] >> 1), (char*)lA + cb);
            gl_lds16(Bt + (col0 + sRow[t]) * K_ + k0 + (sKb[t] >> 1), (char*)lB + cb);
        }
        __syncthreads();
#pragma unroll
        for (int kk = 0; kk < 2; ++kk) {
            bf16x8 af[4], bfr[4];
#pragma unroll
            for (int i = 0; i < 4; ++i) {
                int r = wr * 64 + i * 16 + laneRC;
                af[i] = *(const bf16x8*)((const char*)lA + r * 128 + ((kk * 64 + laneK2) ^ ((r & 7) << 4)));
            }
#pragma unroll
            for (int j = 0; j < 4; ++j) {
                int n = wc * 64 + j * 16 + laneRC;
                bfr[j] = *(const bf16x8*)((const char*)lB + n * 128 + ((kk * 64 + laneK2) ^ ((n & 7) << 4)));
            }
#pragma unroll
            for (int i = 0; i < 4; ++i)
#pragma unroll
                for (int j = 0; j < 4; ++j)
                    acc[i][j] = MFMA16(af[i], bfr[j], acc[i][j]);
        }
        __syncthreads();
    }

#pragma unroll
    for (int j = 0; j < 4; ++j) {
        const long cidx = col0 + wc * 64 + j * 16 + laneRC;
        const float bvv = bias[cidx];
#pragma unroll
        for (int i = 0; i < 4; ++i) {
            const long rbase = row0 + wr * 64 + i * 16 + ((lane >> 4) << 2);
#pragma unroll
            for (int t = 0; t < 4; ++t) {
                float v = acc[i][j][t] + bvv;
                if (EPI) v = gelu_f(v);
                const long off = (rbase + t) * N_ + cidx;
                if (OUTF32) ((float*)Cout)[off] = v;
                else        ((u16*)Cout)[off]  = f2bf(v);
            }
        }
    }
}

// ---------------------------------------------------------------------------
// 64x64 GEMM, BK=64, 4 waves (2x2, wave-tile 32x32), 16 KiB LDS.
// For N=768 GEMMs (o-proj, FFN2, head): 768 blocks vs 192 with 128-tile.
// ---------------------------------------------------------------------------
template<int EPI, int OUTF32>
__global__ __launch_bounds__(256, 4) void gemm64(
    const u16* __restrict__ A, const u16* __restrict__ Bt,
    const float* __restrict__ bias, void* __restrict__ Cout,
    int N_, int K_)
{
    __shared__ u16 lA[64 * 64];
    __shared__ u16 lB[64 * 64];
    const int tid  = threadIdx.x;
    const int lane = tid & 63;
    const int wave = tid >> 6;
    const int wr = wave >> 1, wc = wave & 1;
    const long row0 = (long)blockIdx.y * 64;
    const long col0 = (long)blockIdx.x * 64;

    f32x4 acc[2][2];
#pragma unroll
    for (int i = 0; i < 2; ++i)
#pragma unroll
        for (int j = 0; j < 2; ++j)
#pragma unroll
            for (int t = 0; t < 4; ++t) acc[i][j][t] = 0.f;

    int sRow[2], sKb[2];
#pragma unroll
    for (int t = 0; t < 2; ++t) {
        int byteoff = (wave * 2 + t) * 1024 + lane * 16;
        int r = byteoff >> 7;
        sRow[t] = r;
        sKb[t]  = (byteoff & 127) ^ ((r & 7) << 4);
    }
    const int laneRC = lane & 15;
    const int laneK2 = (lane >> 4) * 16;

    for (int k0 = 0; k0 < K_; k0 += 64) {
#pragma unroll
        for (int t = 0; t < 2; ++t) {
            const int cb = (wave * 2 + t) * 1024;
            gl_lds16(A  + (row0 + sRow[t]) * K_ + k0 + (sKb[t] >> 1), (char*)lA + cb);
            gl_lds16(Bt + (col0 + sRow[t]) * K_ + k0 + (sKb[t] >> 1), (char*)lB + cb);
        }
        __syncthreads();
#pragma unroll
        for (int kk = 0; kk < 2; ++kk) {
            bf16x8 af[2], bfr[2];
#pragma unroll
            for (int i = 0; i < 2; ++i) {
                int r = wr * 32 + i * 16 + laneRC;
                af[i] = *(const bf16x8*)((const char*)lA + r * 128 + ((kk * 64 + laneK2) ^ ((r & 7) << 4)));
            }
#pragma unroll
            for (int j = 0; j < 2; ++j) {
                int n = wc * 32 + j * 16 + laneRC;
                bfr[j] = *(const bf16x8*)((const char*)lB + n * 128 + ((kk * 64 + laneK2) ^ ((n & 7) << 4)));
            }
#pragma unroll
            for (int i = 0; i < 2; ++i)
#pragma unroll
                for (int j = 0; j < 2; ++j)
                    acc[i][j] = MFMA16(af[i], bfr[j], acc[i][j]);
        }
        __syncthreads();
    }

#pragma unroll
    for (int j = 0; j < 2; ++j) {
        const long cidx = col0 + wc * 32 + j * 16 + laneRC;
        const float bvv = bias[cidx];
#pragma unroll
        for (int i = 0; i < 2; ++i) {
            const long rbase = row0 + wr * 32 + i * 16 + ((lane >> 4) << 2);
#pragma unroll
            for (int t = 0; t < 4; ++t) {
                float v = acc[i][j][t] + bvv;
                if (EPI) v = gelu_f(v);
                const long off = (rbase + t) * N_ + cidx;
                if (OUTF32) ((float*)Cout)[off] = v;
                else        ((u16*)Cout)[off]  = f2bf(v);
            }
        }
    }
}

// ---------------------------------------------------------------------------
// Flash attention v2: ones-column row sums in MFMA, swapped PV (O^T layout,
// packed b64 output stores), defer-max THR=8, setprio on MFMA clusters.
// QB=64 (grid 768), 4 waves x 16 q-rows, KB=64, dbuf K/V LDS, 1 barrier/tile.
// ---------------------------------------------------------------------------
__global__ __launch_bounds__(256, 3) void attn_fwd(
    const u16* __restrict__ qkv, u16* __restrict__ outb, float scale)
{
    __shared__ u16 lQ[64 * 64];
    __shared__ u16 lK[2][64 * 64];
    __shared__ u16 lVt[2][64 * 64];
    __shared__ u16 lP[64 * 64];
    const int bh = blockIdx.x;           // b*12 + h
    const int b = bh / 12, h = bh % 12;
    const int q0 = blockIdx.y * 64;
    const int tid = threadIdx.x, lane = tid & 63, wave = tid >> 6;
    const long baseQ = (long)b * 2048 * 2304 + h * 64;
    const long baseK = baseQ + 768;
    const long baseV = baseQ + 1536;
    const int laneRC = lane & 15;
    const int laneK2 = (lane >> 4) * 16;

    int stR[2], stC[2];
#pragma unroll
    for (int t = 0; t < 2; ++t) {
        const int byteoff = (wave * 2 + t) * 1024 + lane * 16;
        const int r = byteoff >> 7;
        stR[t] = r;
        stC[t] = ((byteoff & 127) ^ ((r & 7) << 4)) >> 1;
    }

#define STAGEK(BUF, KB0) do {                                                    \
    _Pragma("unroll") for (int t = 0; t < 2; ++t)                                \
        gl_lds16(qkv + baseK + (long)((KB0) + stR[t]) * 2304 + stC[t],           \
                 (char*)lK[BUF] + (wave * 2 + t) * 1024);                        \
} while (0)

#pragma unroll
    for (int t = 0; t < 2; ++t)
        gl_lds16(qkv + baseQ + (long)(q0 + stR[t]) * 2304 + stC[t],
                 (char*)lQ + (wave * 2 + t) * 1024);
    STAGEK(0, 0);
    u16x8 vA0, vA1;
    {
        const u16x8* gv = (const u16x8*)(qkv + baseV + (long)lane * 2304 + wave * 16);
        vA0 = gv[0]; vA1 = gv[1];
    }
    __syncthreads();

    bf16x8 qf[2];
#pragma unroll
    for (int kk = 0; kk < 2; ++kk) {
        int r = wave * 16 + laneRC;
        qf[kk] = *(const bf16x8*)((const char*)lQ + r * 128 + ((kk * 64 + laneK2) ^ ((r & 7) << 4)));
    }

    bf16x8 onesf;
#pragma unroll
    for (int j = 0; j < 8; ++j) onesf[j] = (__bf16)1.0f;

    float mrun[4];
    f32x4 oacc[4], oaccS;            // oacc in O^T layout; oaccS = row sums
#pragma unroll
    for (int r = 0; r < 4; ++r) mrun[r] = -1e30f;
#pragma unroll
    for (int dc = 0; dc < 4; ++dc)
#pragma unroll
        for (int t = 0; t < 4; ++t) oacc[dc][t] = 0.f;
#pragma unroll
    for (int t = 0; t < 4; ++t) oaccS[t] = 0.f;

    u16x8 vB0 = vA0, vB1 = vA1;
    for (int kt = 0; kt < 32; ++kt) {
        const int cur = kt & 1;
        asm volatile("s_waitcnt vmcnt(0)" ::: "memory");
        SB0;
        {
            const int kv = lane, dg = wave;
            char* vt = (char*)lVt[cur];
#pragma unroll
            for (int j = 0; j < 8; ++j) {
                int d0 = dg * 16 + j;
                *(u16*)(vt + d0 * 128 + ((kv * 2) ^ ((d0 & 7) << 4))) = vA0[j];
                int d1 = dg * 16 + 8 + j;
                *(u16*)(vt + d1 * 128 + ((kv * 2) ^ ((d1 & 7) << 4))) = vA1[j];
            }
        }
        __builtin_amdgcn_s_barrier();
        SB0;
        if (kt + 1 < 32) {
            STAGEK(cur ^ 1, (kt + 1) * 64);
            const u16x8* gv = (const u16x8*)(qkv + baseV + (long)((kt + 1) * 64 + lane) * 2304 + wave * 16);
            vB0 = gv[0]; vB1 = gv[1];
        }
        const char* lKc = (const char*)lK[cur];
        const char* lVc = (const char*)lVt[cur];

        // S = Q K^T : lane holds q-rows (lane>>4)*4+t, key col = cb*16+laneRC
        f32x4 s[4];
#pragma unroll
        for (int cb = 0; cb < 4; ++cb)
#pragma unroll
            for (int t = 0; t < 4; ++t) s[cb][t] = 0.f;
        __builtin_amdgcn_s_setprio(1);
#pragma unroll
        for (int kk = 0; kk < 2; ++kk) {
            bf16x8 kf[4];
#pragma unroll
            for (int cb = 0; cb < 4; ++cb) {
                int kr = cb * 16 + laneRC;
                kf[cb] = *(const bf16x8*)(lKc + kr * 128 + ((kk * 64 + laneK2) ^ ((kr & 7) << 4)));
            }
#pragma unroll
            for (int cb = 0; cb < 4; ++cb)
                s[cb] = MFMA16(qf[kk], kf[cb], s[cb]);
        }
        __builtin_amdgcn_s_setprio(0);

        // online softmax (defer-max THR=8); P -> LDS bf16 (wave-private rows)
        {
            float tm[4];
#pragma unroll
            for (int r = 0; r < 4; ++r) {
                float v = fmaxf(fmaxf(s[0][r], s[1][r]), fmaxf(s[2][r], s[3][r])) * scale;
#pragma unroll
                for (int msk = 1; msk < 16; msk <<= 1) v = fmaxf(v, __shfl_xor(v, msk, 64));
                tm[r] = v;
            }
            float ex = fmaxf(fmaxf(tm[0] - mrun[0], tm[1] - mrun[1]),
                             fmaxf(tm[2] - mrun[2], tm[3] - mrun[3]));
            float mn[4];
            if (__ballot(ex > 8.0f)) {       // rescale path (rare after tile 0)
                float corr[4];
#pragma unroll
                for (int r = 0; r < 4; ++r) {
                    mn[r] = fmaxf(mrun[r], tm[r]);
                    corr[r] = __expf(mrun[r] - mn[r]);
                    mrun[r] = mn[r];
                }
                // corr lives in QK layout (per q-row r of quarter); PV layout
                // needs corr for q = lane&15: q = 4*((lane&15)>>2) + ((lane&15)&3)
                const int srcl = ((lane & 15) >> 2) << 4;
                float c0 = __shfl(corr[0], srcl, 64);
                float c1 = __shfl(corr[1], srcl, 64);
                float c2 = __shfl(corr[2], srcl, 64);
                float c3 = __shfl(corr[3], srcl, 64);
                const int selr = (lane & 15) & 3;
                float cp = selr == 0 ? c0 : (selr == 1 ? c1 : (selr == 2 ? c2 : c3));
#pragma unroll
                for (int dc = 0; dc < 4; ++dc)
#pragma unroll
                    for (int t = 0; t < 4; ++t) oacc[dc][t] *= cp;
#pragma unroll
                for (int t = 0; t < 4; ++t) oaccS[t] *= cp;
            } else {
#pragma unroll
                for (int r = 0; r < 4; ++r) mn[r] = mrun[r];
            }
#pragma unroll
            for (int cb2 = 0; cb2 < 4; ++cb2) {
                int pcol = cb2 * 16 + laneRC;
#pragma unroll
                for (int r = 0; r < 4; ++r) {
                    float pv = __expf(s[cb2][r] * scale - mn[r]);
                    int prow = wave * 16 + ((lane >> 4) << 2) + r;
                    *(u16*)((char*)lP + prow * 128 + ((pcol * 2) ^ ((prow & 7) << 4))) = f2bf(pv);
                }
            }
        }

        // O^T += V^T P^T ; sums += ones P^T   (swapped operands)
        __builtin_amdgcn_s_setprio(1);
#pragma unroll
        for (int kk = 0; kk < 2; ++kk) {
            bf16x8 pf, vf[4];
            {
                int pr = wave * 16 + laneRC;
                pf = *(const bf16x8*)((const char*)lP + pr * 128 + ((kk * 64 + laneK2) ^ ((pr & 7) << 4)));
            }
#pragma unroll
            for (int dc = 0; dc < 4; ++dc) {
                int d = dc * 16 + laneRC;
                vf[dc] = *(const bf16x8*)(lVc + d * 128 + ((kk * 64 + laneK2) ^ ((d & 7) << 4)));
            }
#pragma unroll
            for (int dc = 0; dc < 4; ++dc)
                oacc[dc] = MFMA16(vf[dc], pf, oacc[dc]);
            oaccS = MFMA16(onesf, pf, oaccS);
        }
        __builtin_amdgcn_s_setprio(0);
        vA0 = vB0; vA1 = vB1;
    }
#undef STAGEK

    // epilogue: lane holds q = lane&15, d-rows dc*16 + (lane>>4)*4 + t
    const float inv = 1.0f / oaccS[0];
    const long rowq = (long)b * 2048 + q0 + wave * 16 + (lane & 15);
#pragma unroll
    for (int dc = 0; dc < 4; ++dc) {
        const int colb = h * 64 + dc * 16 + ((lane >> 4) << 2);
        ushort4 st;
        st.x = f2bf(oacc[dc][0] * inv);
        st.y = f2bf(oacc[dc][1] * inv);
        st.z = f2bf(oacc[dc][2] * inv);
        st.w = f2bf(oacc[dc][3] * inv);
        *(ushort4*)(outb + rowq * 768 + colb) = st;
    }
}

// ---------------------------------------------------------------------------
// fused residual-add + LayerNorm; wave-per-row, float4 loads
// ---------------------------------------------------------------------------
__global__ __launch_bounds__(256) void ln_fused(
    const float* __restrict__ a, const float* __restrict__ bres,
    const float* __restrict__ g, const float* __restrict__ be,
    float* __restrict__ outf, u16* __restrict__ outb)
{
    const int wave = threadIdx.x >> 6, lane = threadIdx.x & 63;
    const int row = blockIdx.x * 4 + wave;
    const size_t rbase = (size_t)row * 768;
    float4 v[3];
    float s1 = 0.f, s2 = 0.f;
#pragma unroll
    for (int i = 0; i < 3; ++i) {
        const int c = lane * 4 + i * 256;
        float4 x = *(const float4*)(a + rbase + c);
        if (bres) {
            const float4 y = *(const float4*)(bres + rbase + c);
            x.x += y.x; x.y += y.y; x.z += y.z; x.w += y.w;
        }
        v[i] = x;
        s1 += x.x + x.y + x.z + x.w;
        s2 += x.x * x.x + x.y * x.y + x.z * x.z + x.w * x.w;
    }
#pragma unroll
    for (int m = 1; m < 64; m <<= 1) { s1 += __shfl_xor(s1, m, 64); s2 += __shfl_xor(s2, m, 64); }
    const float mean = s1 * (1.f / 768.f);
    const float var  = s2 * (1.f / 768.f) - mean * mean;
    const float rstd = rsqrtf(var + 1e-5f);
#pragma unroll
    for (int i = 0; i < 3; ++i) {
        const int c = lane * 4 + i * 256;
        const float4 gg = *(const float4*)(g + c);
        const float4 bb = *(const float4*)(be + c);
        float4 y;
        y.x = (v[i].x - mean) * rstd * gg.x + bb.x;
        y.y = (v[i].y - mean) * rstd * gg.y + bb.y;
        y.z = (v[i].z - mean) * rstd * gg.z + bb.z;
        y.w = (v[i].w - mean) * rstd * gg.w + bb.w;
        if (outf) *(float4*)(outf + rbase + c) = y;
        ushort4 u; u.x = f2bf(y.x); u.y = f2bf(y.y); u.z = f2bf(y.z); u.w = f2bf(y.w);
        *(ushort4*)(outb + rbase + c) = u;
    }
}

// multi-weight f32 [R][C] -> bf16 [C][R] (z = weight index)
struct TP9 { const float* s[9]; u16* d[9]; };
__global__ void transpose_multi(TP9 p, int R, int C)
{
    __shared__ float t[32][33];
    const float* in = p.s[blockIdx.z];
    u16* out = p.d[blockIdx.z];
    const int c0 = blockIdx.x * 32, r0 = blockIdx.y * 32;
    const int tx = threadIdx.x, ty = threadIdx.y;
#pragma unroll
    for (int i = 0; i < 4; ++i)
        t[ty + 8 * i][tx] = in[(size_t)(r0 + ty + 8 * i) * C + c0 + tx];
    __syncthreads();
#pragma unroll
    for (int i = 0; i < 4; ++i)
        out[(size_t)(c0 + ty + 8 * i) * R + r0 + tx] = f2bf(t[tx][ty + 8 * i]);
}

__global__ void cvt_bf16_k(const float* __restrict__ in, u16* __restrict__ out, long n)
{
    long i = ((long)blockIdx.x * 256 + threadIdx.x) * 4;
    if (i >= n) return;
    const float4 f = *(const float4*)(in + i);
    ushort4 u; u.x = f2bf(f.x); u.y = f2bf(f.y); u.z = f2bf(f.z); u.w = f2bf(f.w);
    *(ushort4*)(out + i) = u;
}

__global__ void concat_bias(const float* __restrict__ bq, const float* __restrict__ bk,
                            const float* __restrict__ bv, float* __restrict__ out, int total)
{
    int i = blockIdx.x * 256 + threadIdx.x;
    if (i >= total) return;
    int l = i / 2304, j = i - l * 2304;
    float v = (j < 768) ? bq[l * 768 + j]
            : (j < 1536) ? bk[l * 768 + j - 768]
            : bv[l * 768 + j - 1536];
    out[i] = v;
}

__global__ __launch_bounds__(256) void embed_pe(
    const int* __restrict__ ids, const float* __restrict__ table,
    float* __restrict__ xf, u16* __restrict__ xb)
{
    const int idx = blockIdx.x * 256 + threadIdx.x;
    const int row = idx / 768, d = idx - row * 768;
    const int s = row & 2047;
    const float e = table[(long)ids[row] * 768 + d];
    const int j = d >> 1;
    const float ang = (float)s * __expf(-0.011992630692677324f * (float)(4 * j));
    const float pe = (d & 1) ? __cosf(ang) : __sinf(ang);
    const float v = e + pe;
    xf[idx] = v;
    xb[idx] = f2bf(v);
}

// ---------------------------------------------------------------------------
extern "C" void kernel_launch(void* const* d_in, const int* in_sizes, int n_in,
                              void* d_out, int out_size, void* d_ws, size_t ws_size,
                              hipStream_t stream)
{
    const int S = 2048, D = 768, H = 12, L = 2, V = 32000, DF = 3072, M = 4096, NQKV = 2304;
    (void)in_sizes; (void)n_in; (void)out_size; (void)ws_size; (void)H; (void)S;

    const int*   ids  = (const int*)  d_in[0];
    const float* emb  = (const float*)d_in[1];
    const float* Wq   = (const float*)d_in[2];
    const float* bq   = (const float*)d_in[3];
    const float* Wk   = (const float*)d_in[4];
    const float* bk   = (const float*)d_in[5];
    const float* Wv   = (const float*)d_in[6];
    const float* bv   = (const float*)d_in[7];
    const float* Wo   = (const float*)d_in[8];
    const float* bo   = (const float*)d_in[9];
    const float* ln1g = (const float*)d_in[10];
    const float* ln1b = (const float*)d_in[11];
    const float* W1   = (const float*)d_in[12];
    const float* b1   = (const float*)d_in[13];
    const float* W2   = (const float*)d_in[14];
    const float* b2   = (const float*)d_in[15];
    const float* ln2g = (const float*)d_in[16];
    const float* ln2b = (const float*)d_in[17];
    const float* Wd   = (const float*)d_in[18];
    const float* bd   = (const float*)d_in[19];
    const float* lnmg = (const float*)d_in[20];
    const float* lnmb = (const float*)d_in[21];
    const float* decb = (const float*)d_in[22];

    char* p = (char*)d_ws;
    auto carve = [&](size_t bytes) { char* r = p; p += (bytes + 255) & ~(size_t)255; return r; };
    u16*   embB  = (u16*)  carve((size_t)V * D * 2);
    u16*   wqkvT = (u16*)  carve((size_t)L * NQKV * D * 2);
    float* bqkv  = (float*)carve((size_t)L * NQKV * 4);
    u16*   woT   = (u16*)  carve((size_t)L * D * D * 2);
    u16*   w1T   = (u16*)  carve((size_t)L * DF * D * 2);
    u16*   w2T   = (u16*)  carve((size_t)L * D * DF * 2);
    u16*   wdT   = (u16*)  carve((size_t)D * D * 2);
    float* xf    = (float*)carve((size_t)M * D * 4);
    u16*   xb    = (u16*)  carve((size_t)M * D * 2);
    u16*   qkvB  = (u16*)  carve((size_t)M * NQKV * 2);
    u16*   aoB   = (u16*)  carve((size_t)M * D * 2);
    float* tmpf  = (float*)carve((size_t)M * D * 4);
    u16*   hB    = (u16*)  carve((size_t)M * DF * 2);

    dim3 t32x8(32, 8);
    cvt_bf16_k<<<((long)V * D / 4 + 255) / 256, 256, 0, stream>>>(emb, embB, (long)V * D);
    {   // 9 D x D transposes in one launch
        TP9 t9;
        for (int l = 0; l < L; ++l) {
            t9.s[l * 4 + 0] = Wq + (size_t)l * D * D; t9.d[l * 4 + 0] = wqkvT + (size_t)l * NQKV * D;
            t9.s[l * 4 + 1] = Wk + (size_t)l * D * D; t9.d[l * 4 + 1] = wqkvT + (size_t)l * NQKV * D + (size_t)D * D;
            t9.s[l * 4 + 2] = Wv + (size_t)l * D * D; t9.d[l * 4 + 2] = wqkvT + (size_t)l * NQKV * D + (size_t)2 * D * D;
            t9.s[l * 4 + 3] = Wo + (size_t)l * D * D; t9.d[l * 4 + 3] = woT + (size_t)l * D * D;
        }
        t9.s[8] = Wd; t9.d[8] = wdT;
        transpose_multi<<<dim3(24, 24, 9), t32x8, 0, stream>>>(t9, D, D);
        TP9 tw1; tw1.s[0] = W1; tw1.d[0] = w1T; tw1.s[1] = W1 + (size_t)D * DF; tw1.d[1] = w1T + (size_t)DF * D;
        transpose_multi<<<dim3(96, 24, 2), t32x8, 0, stream>>>(tw1, D, DF);
        TP9 tw2; tw2.s[0] = W2; tw2.d[0] = w2T; tw2.s[1] = W2 + (size_t)DF * D; tw2.d[1] = w2T + (size_t)D * DF;
        transpose_multi<<<dim3(24, 96, 2), t32x8, 0, stream>>>(tw2, DF, D);
    }
    concat_bias<<<(L * NQKV + 255) / 256, 256, 0, stream>>>(bq, bk, bv, bqkv, L * NQKV);
    embed_pe<<<M * D / 256, 256, 0, stream>>>(ids, emb, xf, xb);

    const float scale = 0.036084391824351615f;  // 1/sqrt(768)
    for (int l = 0; l < L; ++l) {
        gemm_bf16<0, 0, 0><<<dim3(NQKV / 128, M / 128), 256, 0, stream>>>(xb, wqkvT + (size_t)l * NQKV * D, bqkv + l * NQKV, qkvB, NQKV, D);
        attn_fwd<<<dim3(24, 32), 256, 0, stream>>>(qkvB, aoB, scale);
        gemm64<0, 1><<<dim3(D / 64, M / 64), 256, 0, stream>>>(aoB, woT + (size_t)l * D * D, bo + l * D, tmpf, D, D);
        ln_fused<<<M / 4, 256, 0, stream>>>(xf, tmpf, ln1g + l * D, ln1b + l * D, xf, xb);
        gemm_bf16<1, 0, 0><<<dim3(DF / 128, M / 128), 256, 0, stream>>>(xb, w1T + (size_t)l * DF * D, b1 + l * DF, hB, DF, D);
        gemm64<0, 1><<<dim3(D / 64, M / 64), 256, 0, stream>>>(hB, w2T + (size_t)l * D * DF, b2 + l * D, tmpf, D, DF);
        ln_fused<<<M / 4, 256, 0, stream>>>(xf, tmpf, ln2g + l * D, ln2b + l * D, xf, xb);
    }
    gemm64<1, 1><<<dim3(D / 64, M / 64), 256, 0, stream>>>(xb, wdT, bd, tmpf, D, D);
    ln_fused<<<M / 4, 256, 0, stream>>>(tmpf, nullptr, lnmg, lnmb, nullptr, aoB);
    gemm_bf16<0, 1, 1><<<V / 128 * 32, 256, 0, stream>>>(aoB, embB, decb, (float*)d_out, V, D);
}

// Round 8
// 740.075 us; speedup vs baseline: 1.3736x; 1.0320x over previous
//
#include <hip/hip_runtime.h>
#include <hip/hip_bf16.h>
#include <cstdint>

typedef __bf16 bf16x8 __attribute__((ext_vector_type(8)));
typedef float  f32x4  __attribute__((ext_vector_type(4)));
typedef unsigned short u16;
typedef u16 u16x8 __attribute__((ext_vector_type(8)));

__device__ __forceinline__ u16 f2bf(float f) {
    union { float f; uint32_t u; } x{f};
    uint32_t u = x.u;
    return (u16)((u + 0x7fffu + ((u >> 16) & 1u)) >> 16);
}

__device__ __forceinline__ float gelu_f(float x) {
    return 0.5f * x * (1.0f + erff(x * 0.70710678118654752f));
}

// async global->LDS, 16B per lane; LDS dest is wave-uniform base + lane*16
__device__ __forceinline__ void gl_lds16(const void* g, void* l) {
    __builtin_amdgcn_global_load_lds(
        (__attribute__((address_space(1))) void*)(void*)g,
        (__attribute__((address_space(3))) void*)l, 16, 0, 0);
}

#define MFMA16(a, b, c) __builtin_amdgcn_mfma_f32_16x16x32_bf16((a), (b), (c), 0, 0, 0)
#define SB0 __builtin_amdgcn_sched_barrier(0)

// ---------------------------------------------------------------------------
// 128x128 GEMM, BK=64, 4 waves (2x2), single-buffered (measured best).
// LOC=1: linear grid remapped into 512-block chunks (32 rows x 16 cols) for
// L3 B-residency (decoder). SPLITK>1: grid.z splits K; partial z writes f32
// to Cout + z*4096*N_ (deterministic sum in ln_fused<NP>); bias only z==0.
// ---------------------------------------------------------------------------
template<int EPI, int OUTF32, int LOC, int SPLITK>
__global__ __launch_bounds__(256, 2) void gemm_bf16(
    const u16* __restrict__ A, const u16* __restrict__ Bt,
    const float* __restrict__ bias, void* __restrict__ Cout,
    int N_, int K_)
{
    __shared__ u16 lA[128 * 64];
    __shared__ u16 lB[128 * 64];
    const int tid  = threadIdx.x;
    const int lane = tid & 63;
    const int wave = tid >> 6;
    const int wr = wave >> 1, wc = wave & 1;
    long row0, col0;
    if (LOC) {   // linear grid: chunk = 512 blocks = 32 rows x 16 cols, row fastest
        const int bid = blockIdx.x;
        const int chunk = bid >> 9, rem = bid & 511;
        row0 = (long)(rem & 31) * 128;
        col0 = (long)(chunk * 16 + (rem >> 5)) * 128;
    } else {
        row0 = (long)blockIdx.y * 128;
        col0 = (long)blockIdx.x * 128;
    }
    const int KS = K_ / SPLITK;
    const int kz = (SPLITK > 1) ? blockIdx.z * KS : 0;

    f32x4 acc[4][4];
#pragma unroll
    for (int i = 0; i < 4; ++i)
#pragma unroll
        for (int j = 0; j < 4; ++j)
#pragma unroll
            for (int t = 0; t < 4; ++t) acc[i][j][t] = 0.f;

    int sRow[4], sKb[4];
#pragma unroll
    for (int t = 0; t < 4; ++t) {
        int byteoff = (wave * 4 + t) * 1024 + lane * 16;
        int r = byteoff >> 7;
        sRow[t] = r;
        sKb[t]  = (byteoff & 127) ^ ((r & 7) << 4);
    }
    const int laneRC = lane & 15;
    const int laneK2 = (lane >> 4) * 16;

    for (int k0 = kz; k0 < kz + KS; k0 += 64) {
#pragma unroll
        for (int t = 0; t < 4; ++t) {
            const int cb = (wave * 4 + t) * 1024;
            gl_lds16(A  + (row0 + sRow[t]) * K_ + k0 + (sKb[t] >> 1), (char*)lA + cb);
            gl_lds16(Bt + (col0 + sRow[t]) * K_ + k0 + (sKb[t] >> 1), (char*)lB + cb);
        }
        __syncthreads();
#pragma unroll
        for (int kk = 0; kk < 2; ++kk) {
            bf16x8 af[4], bfr[4];
#pragma unroll
            for (int i = 0; i < 4; ++i) {
                int r = wr * 64 + i * 16 + laneRC;
                af[i] = *(const bf16x8*)((const char*)lA + r * 128 + ((kk * 64 + laneK2) ^ ((r & 7) << 4)));
            }
#pragma unroll
            for (int j = 0; j < 4; ++j) {
                int n = wc * 64 + j * 16 + laneRC;
                bfr[j] = *(const bf16x8*)((const char*)lB + n * 128 + ((kk * 64 + laneK2) ^ ((n & 7) << 4)));
            }
#pragma unroll
            for (int i = 0; i < 4; ++i)
#pragma unroll
                for (int j = 0; j < 4; ++j)
                    acc[i][j] = MFMA16(af[i], bfr[j], acc[i][j]);
        }
        __syncthreads();
    }

    float* outF = (float*)Cout + (SPLITK > 1 ? (long)blockIdx.z * 4096 * N_ : 0);
#pragma unroll
    for (int j = 0; j < 4; ++j) {
        const long cidx = col0 + wc * 64 + j * 16 + laneRC;
        const float bvv = (SPLITK == 1 || blockIdx.z == 0) ? bias[cidx] : 0.f;
#pragma unroll
        for (int i = 0; i < 4; ++i) {
            const long rbase = row0 + wr * 64 + i * 16 + ((lane >> 4) << 2);
#pragma unroll
            for (int t = 0; t < 4; ++t) {
                float v = acc[i][j][t] + bvv;
                if (EPI) v = gelu_f(v);
                const long off = (rbase + t) * N_ + cidx;
                if (OUTF32) outF[off] = v;
                else        ((u16*)Cout)[off] = f2bf(v);
            }
        }
    }
}

// ---------------------------------------------------------------------------
// 64x64 GEMM, BK=64, 4 waves (2x2, wave-tile 32x32), 16 KiB LDS.
// For K=768/N=768 GEMMs (o-proj, head): 768 blocks.
// ---------------------------------------------------------------------------
template<int EPI, int OUTF32>
__global__ __launch_bounds__(256, 4) void gemm64(
    const u16* __restrict__ A, const u16* __restrict__ Bt,
    const float* __restrict__ bias, void* __restrict__ Cout,
    int N_, int K_)
{
    __shared__ u16 lA[64 * 64];
    __shared__ u16 lB[64 * 64];
    const int tid  = threadIdx.x;
    const int lane = tid & 63;
    const int wave = tid >> 6;
    const int wr = wave >> 1, wc = wave & 1;
    const long row0 = (long)blockIdx.y * 64;
    const long col0 = (long)blockIdx.x * 64;

    f32x4 acc[2][2];
#pragma unroll
    for (int i = 0; i < 2; ++i)
#pragma unroll
        for (int j = 0; j < 2; ++j)
#pragma unroll
            for (int t = 0; t < 4; ++t) acc[i][j][t] = 0.f;

    int sRow[2], sKb[2];
#pragma unroll
    for (int t = 0; t < 2; ++t) {
        int byteoff = (wave * 2 + t) * 1024 + lane * 16;
        int r = byteoff >> 7;
        sRow[t] = r;
        sKb[t]  = (byteoff & 127) ^ ((r & 7) << 4);
    }
    const int laneRC = lane & 15;
    const int laneK2 = (lane >> 4) * 16;

    for (int k0 = 0; k0 < K_; k0 += 64) {
#pragma unroll
        for (int t = 0; t < 2; ++t) {
            const int cb = (wave * 2 + t) * 1024;
            gl_lds16(A  + (row0 + sRow[t]) * K_ + k0 + (sKb[t] >> 1), (char*)lA + cb);
            gl_lds16(Bt + (col0 + sRow[t]) * K_ + k0 + (sKb[t] >> 1), (char*)lB + cb);
        }
        __syncthreads();
#pragma unroll
        for (int kk = 0; kk < 2; ++kk) {
            bf16x8 af[2], bfr[2];
#pragma unroll
            for (int i = 0; i < 2; ++i) {
                int r = wr * 32 + i * 16 + laneRC;
                af[i] = *(const bf16x8*)((const char*)lA + r * 128 + ((kk * 64 + laneK2) ^ ((r & 7) << 4)));
            }
#pragma unroll
            for (int j = 0; j < 2; ++j) {
                int n = wc * 32 + j * 16 + laneRC;
                bfr[j] = *(const bf16x8*)((const char*)lB + n * 128 + ((kk * 64 + laneK2) ^ ((n & 7) << 4)));
            }
#pragma unroll
            for (int i = 0; i < 2; ++i)
#pragma unroll
                for (int j = 0; j < 2; ++j)
                    acc[i][j] = MFMA16(af[i], bfr[j], acc[i][j]);
        }
        __syncthreads();
    }

#pragma unroll
    for (int j = 0; j < 2; ++j) {
        const long cidx = col0 + wc * 32 + j * 16 + laneRC;
        const float bvv = bias[cidx];
#pragma unroll
        for (int i = 0; i < 2; ++i) {
            const long rbase = row0 + wr * 32 + i * 16 + ((lane >> 4) << 2);
#pragma unroll
            for (int t = 0; t < 4; ++t) {
                float v = acc[i][j][t] + bvv;
                if (EPI) v = gelu_f(v);
                const long off = (rbase + t) * N_ + cidx;
                if (OUTF32) ((float*)Cout)[off] = v;
                else        ((u16*)Cout)[off]  = f2bf(v);
            }
        }
    }
}

// ---------------------------------------------------------------------------
// Flash attention v3: ones-column row sums in MFMA, swapped PV (O^T layout),
// defer-max with reduce-check every 4th tile, setprio on MFMA clusters.
// QB=64 (grid 768), 4 waves x 16 q-rows, KB=64, dbuf K/V LDS, 1 barrier/tile.
// ---------------------------------------------------------------------------
__global__ __launch_bounds__(256, 3) void attn_fwd(
    const u16* __restrict__ qkv, u16* __restrict__ outb, float scale)
{
    __shared__ u16 lQ[64 * 64];
    __shared__ u16 lK[2][64 * 64];
    __shared__ u16 lVt[2][64 * 64];
    __shared__ u16 lP[64 * 64];
    const int bh = blockIdx.x;           // b*12 + h
    const int b = bh / 12, h = bh % 12;
    const int q0 = blockIdx.y * 64;
    const int tid = threadIdx.x, lane = tid & 63, wave = tid >> 6;
    const long baseQ = (long)b * 2048 * 2304 + h * 64;
    const long baseK = baseQ + 768;
    const long baseV = baseQ + 1536;
    const int laneRC = lane & 15;
    const int laneK2 = (lane >> 4) * 16;

    int stR[2], stC[2];
#pragma unroll
    for (int t = 0; t < 2; ++t) {
        const int byteoff = (wave * 2 + t) * 1024 + lane * 16;
        const int r = byteoff >> 7;
        stR[t] = r;
        stC[t] = ((byteoff & 127) ^ ((r & 7) << 4)) >> 1;
    }

#define STAGEK(BUF, KB0) do {                                                    \
    _Pragma("unroll") for (int t = 0; t < 2; ++t)                                \
        gl_lds16(qkv + baseK + (long)((KB0) + stR[t]) * 2304 + stC[t],           \
                 (char*)lK[BUF] + (wave * 2 + t) * 1024);                        \
} while (0)

#pragma unroll
    for (int t = 0; t < 2; ++t)
        gl_lds16(qkv + baseQ + (long)(q0 + stR[t]) * 2304 + stC[t],
                 (char*)lQ + (wave * 2 + t) * 1024);
    STAGEK(0, 0);
    u16x8 vA0, vA1;
    {
        const u16x8* gv = (const u16x8*)(qkv + baseV + (long)lane * 2304 + wave * 16);
        vA0 = gv[0]; vA1 = gv[1];
    }
    __syncthreads();

    bf16x8 qf[2];
#pragma unroll
    for (int kk = 0; kk < 2; ++kk) {
        int r = wave * 16 + laneRC;
        qf[kk] = *(const bf16x8*)((const char*)lQ + r * 128 + ((kk * 64 + laneK2) ^ ((r & 7) << 4)));
    }

    bf16x8 onesf;
#pragma unroll
    for (int j = 0; j < 8; ++j) onesf[j] = (__bf16)1.0f;

    float mrun[4];
    f32x4 oacc[4], oaccS;            // oacc in O^T layout; oaccS = row sums
#pragma unroll
    for (int r = 0; r < 4; ++r) mrun[r] = -1e30f;
#pragma unroll
    for (int dc = 0; dc < 4; ++dc)
#pragma unroll
        for (int t = 0; t < 4; ++t) oacc[dc][t] = 0.f;
#pragma unroll
    for (int t = 0; t < 4; ++t) oaccS[t] = 0.f;

    u16x8 vB0 = vA0, vB1 = vA1;
    for (int kt = 0; kt < 32; ++kt) {
        const int cur = kt & 1;
        asm volatile("s_waitcnt vmcnt(0)" ::: "memory");
        SB0;
        {
            const int kv = lane, dg = wave;
            char* vt = (char*)lVt[cur];
#pragma unroll
            for (int j = 0; j < 8; ++j) {
                int d0 = dg * 16 + j;
                *(u16*)(vt + d0 * 128 + ((kv * 2) ^ ((d0 & 7) << 4))) = vA0[j];
                int d1 = dg * 16 + 8 + j;
                *(u16*)(vt + d1 * 128 + ((kv * 2) ^ ((d1 & 7) << 4))) = vA1[j];
            }
        }
        __builtin_amdgcn_s_barrier();
        SB0;
        if (kt + 1 < 32) {
            STAGEK(cur ^ 1, (kt + 1) * 64);
            const u16x8* gv = (const u16x8*)(qkv + baseV + (long)((kt + 1) * 64 + lane) * 2304 + wave * 16);
            vB0 = gv[0]; vB1 = gv[1];
        }
        const char* lKc = (const char*)lK[cur];
        const char* lVc = (const char*)lVt[cur];

        // S = Q K^T
        f32x4 s[4];
#pragma unroll
        for (int cb = 0; cb < 4; ++cb)
#pragma unroll
            for (int t = 0; t < 4; ++t) s[cb][t] = 0.f;
        __builtin_amdgcn_s_setprio(1);
#pragma unroll
        for (int kk = 0; kk < 2; ++kk) {
            bf16x8 kf[4];
#pragma unroll
            for (int cb = 0; cb < 4; ++cb) {
                int kr = cb * 16 + laneRC;
                kf[cb] = *(const bf16x8*)(lKc + kr * 128 + ((kk * 64 + laneK2) ^ ((kr & 7) << 4)));
            }
#pragma unroll
            for (int cb = 0; cb < 4; ++cb)
                s[cb] = MFMA16(qf[kk], kf[cb], s[cb]);
        }
        __builtin_amdgcn_s_setprio(0);

        // defer-max online softmax; reduce-check only every 4th tile
        if ((kt & 3) == 0) {
            float tm[4];
#pragma unroll
            for (int r = 0; r < 4; ++r) {
                float v = fmaxf(fmaxf(s[0][r], s[1][r]), fmaxf(s[2][r], s[3][r])) * scale;
#pragma unroll
                for (int msk = 1; msk < 16; msk <<= 1) v = fmaxf(v, __shfl_xor(v, msk, 64));
                tm[r] = v;
            }
            float ex = fmaxf(fmaxf(tm[0] - mrun[0], tm[1] - mrun[1]),
                             fmaxf(tm[2] - mrun[2], tm[3] - mrun[3]));
            if (__ballot(ex > 8.0f)) {       // rescale path (rare after tile 0)
                float corr[4];
#pragma unroll
                for (int r = 0; r < 4; ++r) {
                    float mnew = fmaxf(mrun[r], tm[r]);
                    corr[r] = __expf(mrun[r] - mnew);
                    mrun[r] = mnew;
                }
                // corr is in QK layout; PV layout needs corr for q = lane&15
                const int srcl = ((lane & 15) >> 2) << 4;
                float c0 = __shfl(corr[0], srcl, 64);
                float c1 = __shfl(corr[1], srcl, 64);
                float c2 = __shfl(corr[2], srcl, 64);
                float c3 = __shfl(corr[3], srcl, 64);
                const int selr = (lane & 15) & 3;
                float cp = selr == 0 ? c0 : (selr == 1 ? c1 : (selr == 2 ? c2 : c3));
#pragma unroll
                for (int dc = 0; dc < 4; ++dc)
#pragma unroll
                    for (int t = 0; t < 4; ++t) oacc[dc][t] *= cp;
#pragma unroll
                for (int t = 0; t < 4; ++t) oaccS[t] *= cp;
            }
        }
#pragma unroll
        for (int cb2 = 0; cb2 < 4; ++cb2) {
            int pcol = cb2 * 16 + laneRC;
#pragma unroll
            for (int r = 0; r < 4; ++r) {
                float pv = __expf(s[cb2][r] * scale - mrun[r]);
                int prow = wave * 16 + ((lane >> 4) << 2) + r;
                *(u16*)((char*)lP + prow * 128 + ((pcol * 2) ^ ((prow & 7) << 4))) = f2bf(pv);
            }
        }

        // O^T += V^T P^T ; sums += ones P^T   (swapped operands)
        __builtin_amdgcn_s_setprio(1);
#pragma unroll
        for (int kk = 0; kk < 2; ++kk) {
            bf16x8 pf, vf[4];
            {
                int pr = wave * 16 + laneRC;
                pf = *(const bf16x8*)((const char*)lP + pr * 128 + ((kk * 64 + laneK2) ^ ((pr & 7) << 4)));
            }
#pragma unroll
            for (int dc = 0; dc < 4; ++dc) {
                int d = dc * 16 + laneRC;
                vf[dc] = *(const bf16x8*)(lVc + d * 128 + ((kk * 64 + laneK2) ^ ((d & 7) << 4)));
            }
#pragma unroll
            for (int dc = 0; dc < 4; ++dc)
                oacc[dc] = MFMA16(vf[dc], pf, oacc[dc]);
            oaccS = MFMA16(onesf, pf, oaccS);
        }
        __builtin_amdgcn_s_setprio(0);
        vA0 = vB0; vA1 = vB1;
    }
#undef STAGEK

    // epilogue: lane holds q = lane&15, d-rows dc*16 + (lane>>4)*4 + t
    const float inv = 1.0f / oaccS[0];
    const long rowq = (long)b * 2048 + q0 + wave * 16 + (lane & 15);
#pragma unroll
    for (int dc = 0; dc < 4; ++dc) {
        const int colb = h * 64 + dc * 16 + ((lane >> 4) << 2);
        ushort4 st;
        st.x = f2bf(oacc[dc][0] * inv);
        st.y = f2bf(oacc[dc][1] * inv);
        st.z = f2bf(oacc[dc][2] * inv);
        st.w = f2bf(oacc[dc][3] * inv);
        *(ushort4*)(outb + rowq * 768 + colb) = st;
    }
}

// ---------------------------------------------------------------------------
// fused residual-add + NP partial-sums + LayerNorm; wave-per-row, float4 loads
// ---------------------------------------------------------------------------
template<int NP>
__global__ __launch_bounds__(256) void ln_fused(
    const float* __restrict__ a, const float* __restrict__ parts, long pstride,
    const float* __restrict__ g, const float* __restrict__ be,
    float* __restrict__ outf, u16* __restrict__ outb)
{
    const int wave = threadIdx.x >> 6, lane = threadIdx.x & 63;
    const int row = blockIdx.x * 4 + wave;
    const size_t rbase = (size_t)row * 768;
    float4 v[3];
    float s1 = 0.f, s2 = 0.f;
#pragma unroll
    for (int i = 0; i < 3; ++i) {
        const int c = lane * 4 + i * 256;
        float4 x = *(const float4*)(a + rbase + c);
#pragma unroll
        for (int p = 0; p < NP; ++p) {
            const float4 y = *(const float4*)(parts + (size_t)p * pstride + rbase + c);
            x.x += y.x; x.y += y.y; x.z += y.z; x.w += y.w;
        }
        v[i] = x;
        s1 += x.x + x.y + x.z + x.w;
        s2 += x.x * x.x + x.y * x.y + x.z * x.z + x.w * x.w;
    }
#pragma unroll
    for (int m = 1; m < 64; m <<= 1) { s1 += __shfl_xor(s1, m, 64); s2 += __shfl_xor(s2, m, 64); }
    const float mean = s1 * (1.f / 768.f);
    const float var  = s2 * (1.f / 768.f) - mean * mean;
    const float rstd = rsqrtf(var + 1e-5f);
#pragma unroll
    for (int i = 0; i < 3; ++i) {
        const int c = lane * 4 + i * 256;
        const float4 gg = *(const float4*)(g + c);
        const float4 bb = *(const float4*)(be + c);
        float4 y;
        y.x = (v[i].x - mean) * rstd * gg.x + bb.x;
        y.y = (v[i].y - mean) * rstd * gg.y + bb.y;
        y.z = (v[i].z - mean) * rstd * gg.z + bb.z;
        y.w = (v[i].w - mean) * rstd * gg.w + bb.w;
        if (outf) *(float4*)(outf + rbase + c) = y;
        ushort4 u; u.x = f2bf(y.x); u.y = f2bf(y.y); u.z = f2bf(y.z); u.w = f2bf(y.w);
        *(ushort4*)(outb + rbase + c) = u;
    }
}

// multi-weight f32 [R][C] -> bf16 [C][R] (z = weight index)
struct TP9 { const float* s[9]; u16* d[9]; };
__global__ void transpose_multi(TP9 p, int R, int C)
{
    __shared__ float t[32][33];
    const float* in = p.s[blockIdx.z];
    u16* out = p.d[blockIdx.z];
    const int c0 = blockIdx.x * 32, r0 = blockIdx.y * 32;
    const int tx = threadIdx.x, ty = threadIdx.y;
#pragma unroll
    for (int i = 0; i < 4; ++i)
        t[ty + 8 * i][tx] = in[(size_t)(r0 + ty + 8 * i) * C + c0 + tx];
    __syncthreads();
#pragma unroll
    for (int i = 0; i < 4; ++i)
        out[(size_t)(c0 + ty + 8 * i) * R + r0 + tx] = f2bf(t[tx][ty + 8 * i]);
}

// fused prep: embB cvt (range A) + embed+PE (range B) + bias concat (tail)
__global__ __launch_bounds__(256) void prep_misc(
    const float* __restrict__ emb, u16* __restrict__ embB,
    const int* __restrict__ ids, float* __restrict__ xf, u16* __restrict__ xb,
    const float* __restrict__ bq, const float* __restrict__ bk,
    const float* __restrict__ bv, float* __restrict__ bqkv)
{
    const long A = 6144000;      // V*D/4 vec4 conversions
    const long B = 3145728;      // 4096*768 embed elements
    long t = (long)blockIdx.x * 256 + threadIdx.x;
    if (t < A) {
        const long i = t * 4;
        const float4 f = *(const float4*)(emb + i);
        ushort4 u; u.x = f2bf(f.x); u.y = f2bf(f.y); u.z = f2bf(f.z); u.w = f2bf(f.w);
        *(ushort4*)(embB + i) = u;
    } else if (t < A + B) {
        const int idx = (int)(t - A);
        const int row = idx / 768, d = idx - row * 768;
        const int s = row & 2047;
        const float e = emb[(long)ids[row] * 768 + d];
        const int j = d >> 1;
        const float ang = (float)s * __expf(-0.011992630692677324f * (float)(4 * j));
        const float pe = (d & 1) ? __cosf(ang) : __sinf(ang);
        const float v = e + pe;
        xf[idx] = v;
        xb[idx] = f2bf(v);
    } else {
        const int i = (int)(t - A - B);
        if (i < 4608) {
            int l = i / 2304, j = i - l * 2304;
            float v = (j < 768) ? bq[l * 768 + j]
                    : (j < 1536) ? bk[l * 768 + j - 768]
                    : bv[l * 768 + j - 1536];
            bqkv[i] = v;
        }
    }
}

// ---------------------------------------------------------------------------
extern "C" void kernel_launch(void* const* d_in, const int* in_sizes, int n_in,
                              void* d_out, int out_size, void* d_ws, size_t ws_size,
                              hipStream_t stream)
{
    const int S = 2048, D = 768, H = 12, L = 2, V = 32000, DF = 3072, M = 4096, NQKV = 2304;
    (void)in_sizes; (void)n_in; (void)out_size; (void)ws_size; (void)H; (void)S;

    const int*   ids  = (const int*)  d_in[0];
    const float* emb  = (const float*)d_in[1];
    const float* Wq   = (const float*)d_in[2];
    const float* bq   = (const float*)d_in[3];
    const float* Wk   = (const float*)d_in[4];
    const float* bk   = (const float*)d_in[5];
    const float* Wv   = (const float*)d_in[6];
    const float* bv   = (const float*)d_in[7];
    const float* Wo   = (const float*)d_in[8];
    const float* bo   = (const float*)d_in[9];
    const float* ln1g = (const float*)d_in[10];
    const float* ln1b = (const float*)d_in[11];
    const float* W1   = (const float*)d_in[12];
    const float* b1   = (const float*)d_in[13];
    const float* W2   = (const float*)d_in[14];
    const float* b2   = (const float*)d_in[15];
    const float* ln2g = (const float*)d_in[16];
    const float* ln2b = (const float*)d_in[17];
    const float* Wd   = (const float*)d_in[18];
    const float* bd   = (const float*)d_in[19];
    const float* lnmg = (const float*)d_in[20];
    const float* lnmb = (const float*)d_in[21];
    const float* decb = (const float*)d_in[22];

    char* p = (char*)d_ws;
    auto carve = [&](size_t bytes) { char* r = p; p += (bytes + 255) & ~(size_t)255; return r; };
    u16*   embB  = (u16*)  carve((size_t)V * D * 2);
    u16*   wqkvT = (u16*)  carve((size_t)L * NQKV * D * 2);
    float* bqkv  = (float*)carve((size_t)L * NQKV * 4);
    u16*   woT   = (u16*)  carve((size_t)L * D * D * 2);
    u16*   w1T   = (u16*)  carve((size_t)L * DF * D * 2);
    u16*   w2T   = (u16*)  carve((size_t)L * D * DF * 2);
    u16*   wdT   = (u16*)  carve((size_t)D * D * 2);
    float* xf    = (float*)carve((size_t)M * D * 4);
    u16*   xb    = (u16*)  carve((size_t)M * D * 2);
    u16*   qkvB  = (u16*)  carve((size_t)M * NQKV * 2);
    u16*   aoB   = (u16*)  carve((size_t)M * D * 2);
    float* tmpf  = (float*)carve((size_t)M * D * 4 * 4);   // 4 split-K partials
    u16*   hB    = (u16*)  carve((size_t)M * DF * 2);

    dim3 t32x8(32, 8);
    prep_misc<<<(6144000 + 3145728 + 4608) / 256, 256, 0, stream>>>(
        emb, embB, ids, xf, xb, bq, bk, bv, bqkv);
    {   // 9 D x D transposes in one launch
        TP9 t9;
        for (int l = 0; l < L; ++l) {
            t9.s[l * 4 + 0] = Wq + (size_t)l * D * D; t9.d[l * 4 + 0] = wqkvT + (size_t)l * NQKV * D;
            t9.s[l * 4 + 1] = Wk + (size_t)l * D * D; t9.d[l * 4 + 1] = wqkvT + (size_t)l * NQKV * D + (size_t)D * D;
            t9.s[l * 4 + 2] = Wv + (size_t)l * D * D; t9.d[l * 4 + 2] = wqkvT + (size_t)l * NQKV * D + (size_t)2 * D * D;
            t9.s[l * 4 + 3] = Wo + (size_t)l * D * D; t9.d[l * 4 + 3] = woT + (size_t)l * D * D;
        }
        t9.s[8] = Wd; t9.d[8] = wdT;
        transpose_multi<<<dim3(24, 24, 9), t32x8, 0, stream>>>(t9, D, D);
        TP9 tw1; tw1.s[0] = W1; tw1.d[0] = w1T; tw1.s[1] = W1 + (size_t)D * DF; tw1.d[1] = w1T + (size_t)DF * D;
        transpose_multi<<<dim3(96, 24, 2), t32x8, 0, stream>>>(tw1, D, DF);
        TP9 tw2; tw2.s[0] = W2; tw2.d[0] = w2T; tw2.s[1] = W2 + (size_t)DF * D; tw2.d[1] = w2T + (size_t)D * DF;
        transpose_multi<<<dim3(24, 96, 2), t32x8, 0, stream>>>(tw2, DF, D);
    }

    const float scale = 0.036084391824351615f;  // 1/sqrt(768)
    const long PSTR = (long)M * D;
    for (int l = 0; l < L; ++l) {
        gemm_bf16<0, 0, 0, 1><<<dim3(NQKV / 128, M / 128), 256, 0, stream>>>(xb, wqkvT + (size_t)l * NQKV * D, bqkv + l * NQKV, qkvB, NQKV, D);
        attn_fwd<<<dim3(24, 32), 256, 0, stream>>>(qkvB, aoB, scale);
        gemm64<0, 1><<<dim3(D / 64, M / 64), 256, 0, stream>>>(aoB, woT + (size_t)l * D * D, bo + l * D, tmpf, D, D);
        ln_fused<1><<<M / 4, 256, 0, stream>>>(xf, tmpf, PSTR, ln1g + l * D, ln1b + l * D, xf, xb);
        gemm_bf16<1, 0, 0, 1><<<dim3(DF / 128, M / 128), 256, 0, stream>>>(xb, w1T + (size_t)l * DF * D, b1 + l * DF, hB, DF, D);
        gemm_bf16<0, 1, 0, 4><<<dim3(D / 128, M / 128, 4), 256, 0, stream>>>(hB, w2T + (size_t)l * D * DF, b2 + l * D, tmpf, D, DF);
        ln_fused<4><<<M / 4, 256, 0, stream>>>(xf, tmpf, PSTR, ln2g + l * D, ln2b + l * D, xf, xb);
    }
    gemm64<1, 1><<<dim3(D / 64, M / 64), 256, 0, stream>>>(xb, wdT, bd, tmpf, D, D);
    ln_fused<0><<<M / 4, 256, 0, stream>>>(tmpf, nullptr, 0, lnmg, lnmb, nullptr, aoB);
    gemm_bf16<0, 1, 1, 1><<<V / 128 * 32, 256, 0, stream>>>(aoB, embB, decb, (float*)d_out, V, D);
}

// Round 9
// 719.221 us; speedup vs baseline: 1.4135x; 1.0290x over previous
//
#include <hip/hip_runtime.h>
#include <hip/hip_bf16.h>
#include <cstdint>

typedef __bf16 bf16x8 __attribute__((ext_vector_type(8)));
typedef float  f32x4  __attribute__((ext_vector_type(4)));
typedef unsigned short u16;
typedef u16 u16x8 __attribute__((ext_vector_type(8)));

__device__ __forceinline__ u16 f2bf(float f) {
    union { float f; uint32_t u; } x{f};
    uint32_t u = x.u;
    return (u16)((u + 0x7fffu + ((u >> 16) & 1u)) >> 16);
}

__device__ __forceinline__ float gelu_f(float x) {
    return 0.5f * x * (1.0f + erff(x * 0.70710678118654752f));
}

// async global->LDS, 16B per lane; LDS dest is wave-uniform base + lane*16
__device__ __forceinline__ void gl_lds16(const void* g, void* l) {
    __builtin_amdgcn_global_load_lds(
        (__attribute__((address_space(1))) void*)(void*)g,
        (__attribute__((address_space(3))) void*)l, 16, 0, 0);
}

#define MFMA16(a, b, c) __builtin_amdgcn_mfma_f32_16x16x32_bf16((a), (b), (c), 0, 0, 0)
#define SB0 __builtin_amdgcn_sched_barrier(0)

// ---------------------------------------------------------------------------
// 128x128 GEMM, BK=64, 4 waves (2x2), single-buffered (measured best).
// LOC=1: linear grid remapped into 512-block chunks (32 rows x 16 cols) for
// L3 B-residency (decoder: fetch 798->~150MB, 325->~255us). SPLITK>1: grid.z
// splits K; partial z writes f32 to Cout + z*4096*N_; bias only z==0.
// ---------------------------------------------------------------------------
template<int EPI, int OUTF32, int LOC, int SPLITK>
__global__ __launch_bounds__(256, 2) void gemm_bf16(
    const u16* __restrict__ A, const u16* __restrict__ Bt,
    const float* __restrict__ bias, void* __restrict__ Cout,
    int N_, int K_)
{
    __shared__ u16 lA[128 * 64];
    __shared__ u16 lB[128 * 64];
    const int tid  = threadIdx.x;
    const int lane = tid & 63;
    const int wave = tid >> 6;
    const int wr = wave >> 1, wc = wave & 1;
    long row0, col0;
    if (LOC) {   // linear grid: chunk = 512 blocks = 32 rows x 16 cols, row fastest
        const int bid = blockIdx.x;
        const int chunk = bid >> 9, rem = bid & 511;
        row0 = (long)(rem & 31) * 128;
        col0 = (long)(chunk * 16 + (rem >> 5)) * 128;
    } else {
        row0 = (long)blockIdx.y * 128;
        col0 = (long)blockIdx.x * 128;
    }
    const int KS = K_ / SPLITK;
    const int kz = (SPLITK > 1) ? blockIdx.z * KS : 0;

    f32x4 acc[4][4];
#pragma unroll
    for (int i = 0; i < 4; ++i)
#pragma unroll
        for (int j = 0; j < 4; ++j)
#pragma unroll
            for (int t = 0; t < 4; ++t) acc[i][j][t] = 0.f;

    int sRow[4], sKb[4];
#pragma unroll
    for (int t = 0; t < 4; ++t) {
        int byteoff = (wave * 4 + t) * 1024 + lane * 16;
        int r = byteoff >> 7;
        sRow[t] = r;
        sKb[t]  = (byteoff & 127) ^ ((r & 7) << 4);
    }
    const int laneRC = lane & 15;
    const int laneK2 = (lane >> 4) * 16;

    for (int k0 = kz; k0 < kz + KS; k0 += 64) {
#pragma unroll
        for (int t = 0; t < 4; ++t) {
            const int cb = (wave * 4 + t) * 1024;
            gl_lds16(A  + (row0 + sRow[t]) * K_ + k0 + (sKb[t] >> 1), (char*)lA + cb);
            gl_lds16(Bt + (col0 + sRow[t]) * K_ + k0 + (sKb[t] >> 1), (char*)lB + cb);
        }
        __syncthreads();
#pragma unroll
        for (int kk = 0; kk < 2; ++kk) {
            bf16x8 af[4], bfr[4];
#pragma unroll
            for (int i = 0; i < 4; ++i) {
                int r = wr * 64 + i * 16 + laneRC;
                af[i] = *(const bf16x8*)((const char*)lA + r * 128 + ((kk * 64 + laneK2) ^ ((r & 7) << 4)));
            }
#pragma unroll
            for (int j = 0; j < 4; ++j) {
                int n = wc * 64 + j * 16 + laneRC;
                bfr[j] = *(const bf16x8*)((const char*)lB + n * 128 + ((kk * 64 + laneK2) ^ ((n & 7) << 4)));
            }
#pragma unroll
            for (int i = 0; i < 4; ++i)
#pragma unroll
                for (int j = 0; j < 4; ++j)
                    acc[i][j] = MFMA16(af[i], bfr[j], acc[i][j]);
        }
        __syncthreads();
    }

    float* outF = (float*)Cout + (SPLITK > 1 ? (long)blockIdx.z * 4096 * N_ : 0);
#pragma unroll
    for (int j = 0; j < 4; ++j) {
        const long cidx = col0 + wc * 64 + j * 16 + laneRC;
        const float bvv = (SPLITK == 1 || blockIdx.z == 0) ? bias[cidx] : 0.f;
#pragma unroll
        for (int i = 0; i < 4; ++i) {
            const long rbase = row0 + wr * 64 + i * 16 + ((lane >> 4) << 2);
#pragma unroll
            for (int t = 0; t < 4; ++t) {
                float v = acc[i][j][t] + bvv;
                if (EPI) v = gelu_f(v);
                const long off = (rbase + t) * N_ + cidx;
                if (OUTF32) outF[off] = v;
                else        ((u16*)Cout)[off] = f2bf(v);
            }
        }
    }
}

// ---------------------------------------------------------------------------
// 64x64 GEMM, BK=64, 4 waves (2x2, wave-tile 32x32), 16 KiB LDS.
// For K=768/N=768 GEMMs (o-proj, head): 768 blocks.
// ---------------------------------------------------------------------------
template<int EPI, int OUTF32>
__global__ __launch_bounds__(256, 4) void gemm64(
    const u16* __restrict__ A, const u16* __restrict__ Bt,
    const float* __restrict__ bias, void* __restrict__ Cout,
    int N_, int K_)
{
    __shared__ u16 lA[64 * 64];
    __shared__ u16 lB[64 * 64];
    const int tid  = threadIdx.x;
    const int lane = tid & 63;
    const int wave = tid >> 6;
    const int wr = wave >> 1, wc = wave & 1;
    const long row0 = (long)blockIdx.y * 64;
    const long col0 = (long)blockIdx.x * 64;

    f32x4 acc[2][2];
#pragma unroll
    for (int i = 0; i < 2; ++i)
#pragma unroll
        for (int j = 0; j < 2; ++j)
#pragma unroll
            for (int t = 0; t < 4; ++t) acc[i][j][t] = 0.f;

    int sRow[2], sKb[2];
#pragma unroll
    for (int t = 0; t < 2; ++t) {
        int byteoff = (wave * 2 + t) * 1024 + lane * 16;
        int r = byteoff >> 7;
        sRow[t] = r;
        sKb[t]  = (byteoff & 127) ^ ((r & 7) << 4);
    }
    const int laneRC = lane & 15;
    const int laneK2 = (lane >> 4) * 16;

    for (int k0 = 0; k0 < K_; k0 += 64) {
#pragma unroll
        for (int t = 0; t < 2; ++t) {
            const int cb = (wave * 2 + t) * 1024;
            gl_lds16(A  + (row0 + sRow[t]) * K_ + k0 + (sKb[t] >> 1), (char*)lA + cb);
            gl_lds16(Bt + (col0 + sRow[t]) * K_ + k0 + (sKb[t] >> 1), (char*)lB + cb);
        }
        __syncthreads();
#pragma unroll
        for (int kk = 0; kk < 2; ++kk) {
            bf16x8 af[2], bfr[2];
#pragma unroll
            for (int i = 0; i < 2; ++i) {
                int r = wr * 32 + i * 16 + laneRC;
                af[i] = *(const bf16x8*)((const char*)lA + r * 128 + ((kk * 64 + laneK2) ^ ((r & 7) << 4)));
            }
#pragma unroll
            for (int j = 0; j < 2; ++j) {
                int n = wc * 32 + j * 16 + laneRC;
                bfr[j] = *(const bf16x8*)((const char*)lB + n * 128 + ((kk * 64 + laneK2) ^ ((n & 7) << 4)));
            }
#pragma unroll
            for (int i = 0; i < 2; ++i)
#pragma unroll
                for (int j = 0; j < 2; ++j)
                    acc[i][j] = MFMA16(af[i], bfr[j], acc[i][j]);
        }
        __syncthreads();
    }

#pragma unroll
    for (int j = 0; j < 2; ++j) {
        const long cidx = col0 + wc * 32 + j * 16 + laneRC;
        const float bvv = bias[cidx];
#pragma unroll
        for (int i = 0; i < 2; ++i) {
            const long rbase = row0 + wr * 32 + i * 16 + ((lane >> 4) << 2);
#pragma unroll
            for (int t = 0; t < 4; ++t) {
                float v = acc[i][j][t] + bvv;
                if (EPI) v = gelu_f(v);
                const long off = (rbase + t) * N_ + cidx;
                if (OUTF32) ((float*)Cout)[off] = v;
                else        ((u16*)Cout)[off]  = f2bf(v);
            }
        }
    }
}

// ---------------------------------------------------------------------------
// Flash attention v4: lQ/lP share one 8KB buffer (wave w touches only rows
// [16w,16w+16) in both roles; Q-read precedes first P-write per-wave, DS ops
// in-order per wave) -> LDS 40KB -> 4 blocks/CU. Ones-column MFMA row sums,
// swapped PV (O^T layout), defer-max check every 8th tile, setprio.
// ---------------------------------------------------------------------------
__global__ __launch_bounds__(256, 4) void attn_fwd(
    const u16* __restrict__ qkv, u16* __restrict__ outb, float scale)
{
    __shared__ u16 lQP[64 * 64];         // Q at init, P afterwards
    __shared__ u16 lK[2][64 * 64];
    __shared__ u16 lVt[2][64 * 64];
    const int bh = blockIdx.x;           // b*12 + h
    const int b = bh / 12, h = bh % 12;
    const int q0 = blockIdx.y * 64;
    const int tid = threadIdx.x, lane = tid & 63, wave = tid >> 6;
    const long baseQ = (long)b * 2048 * 2304 + h * 64;
    const long baseK = baseQ + 768;
    const long baseV = baseQ + 1536;
    const int laneRC = lane & 15;
    const int laneK2 = (lane >> 4) * 16;

    int stR[2], stC[2];
#pragma unroll
    for (int t = 0; t < 2; ++t) {
        const int byteoff = (wave * 2 + t) * 1024 + lane * 16;
        const int r = byteoff >> 7;
        stR[t] = r;
        stC[t] = ((byteoff & 127) ^ ((r & 7) << 4)) >> 1;
    }

#define STAGEK(BUF, KB0) do {                                                    \
    _Pragma("unroll") for (int t = 0; t < 2; ++t)                                \
        gl_lds16(qkv + baseK + (long)((KB0) + stR[t]) * 2304 + stC[t],           \
                 (char*)lK[BUF] + (wave * 2 + t) * 1024);                        \
} while (0)

#pragma unroll
    for (int t = 0; t < 2; ++t)
        gl_lds16(qkv + baseQ + (long)(q0 + stR[t]) * 2304 + stC[t],
                 (char*)lQP + (wave * 2 + t) * 1024);
    STAGEK(0, 0);
    u16x8 vA0, vA1;
    {
        const u16x8* gv = (const u16x8*)(qkv + baseV + (long)lane * 2304 + wave * 16);
        vA0 = gv[0]; vA1 = gv[1];
    }
    __syncthreads();   // Q + K[0] landed, V-regs present

    bf16x8 qf[2];
#pragma unroll
    for (int kk = 0; kk < 2; ++kk) {
        int r = wave * 16 + laneRC;
        qf[kk] = *(const bf16x8*)((const char*)lQP + r * 128 + ((kk * 64 + laneK2) ^ ((r & 7) << 4)));
    }

    bf16x8 onesf;
#pragma unroll
    for (int j = 0; j < 8; ++j) onesf[j] = (__bf16)1.0f;

    float mrun[4];
    f32x4 oacc[4], oaccS;            // oacc in O^T layout; oaccS = row sums
#pragma unroll
    for (int r = 0; r < 4; ++r) mrun[r] = -1e30f;
#pragma unroll
    for (int dc = 0; dc < 4; ++dc)
#pragma unroll
        for (int t = 0; t < 4; ++t) oacc[dc][t] = 0.f;
#pragma unroll
    for (int t = 0; t < 4; ++t) oaccS[t] = 0.f;

    u16x8 vB0 = vA0, vB1 = vA1;
    for (int kt = 0; kt < 32; ++kt) {
        const int cur = kt & 1;
        asm volatile("s_waitcnt vmcnt(0)" ::: "memory");
        SB0;
        {
            const int kv = lane, dg = wave;
            char* vt = (char*)lVt[cur];
#pragma unroll
            for (int j = 0; j < 8; ++j) {
                int d0 = dg * 16 + j;
                *(u16*)(vt + d0 * 128 + ((kv * 2) ^ ((d0 & 7) << 4))) = vA0[j];
                int d1 = dg * 16 + 8 + j;
                *(u16*)(vt + d1 * 128 + ((kv * 2) ^ ((d1 & 7) << 4))) = vA1[j];
            }
        }
        __builtin_amdgcn_s_barrier();
        SB0;
        if (kt + 1 < 32) {
            STAGEK(cur ^ 1, (kt + 1) * 64);
            const u16x8* gv = (const u16x8*)(qkv + baseV + (long)((kt + 1) * 64 + lane) * 2304 + wave * 16);
            vB0 = gv[0]; vB1 = gv[1];
        }
        const char* lKc = (const char*)lK[cur];
        const char* lVc = (const char*)lVt[cur];

        // S = Q K^T
        f32x4 s[4];
#pragma unroll
        for (int cb = 0; cb < 4; ++cb)
#pragma unroll
            for (int t = 0; t < 4; ++t) s[cb][t] = 0.f;
        __builtin_amdgcn_s_setprio(1);
#pragma unroll
        for (int kk = 0; kk < 2; ++kk) {
            bf16x8 kf[4];
#pragma unroll
            for (int cb = 0; cb < 4; ++cb) {
                int kr = cb * 16 + laneRC;
                kf[cb] = *(const bf16x8*)(lKc + kr * 128 + ((kk * 64 + laneK2) ^ ((kr & 7) << 4)));
            }
#pragma unroll
            for (int cb = 0; cb < 4; ++cb)
                s[cb] = MFMA16(qf[kk], kf[cb], s[cb]);
        }
        __builtin_amdgcn_s_setprio(0);

        // defer-max online softmax; reduce-check only every 8th tile
        if ((kt & 7) == 0) {
            float tm[4];
#pragma unroll
            for (int r = 0; r < 4; ++r) {
                float v = fmaxf(fmaxf(s[0][r], s[1][r]), fmaxf(s[2][r], s[3][r])) * scale;
#pragma unroll
                for (int msk = 1; msk < 16; msk <<= 1) v = fmaxf(v, __shfl_xor(v, msk, 64));
                tm[r] = v;
            }
            float ex = fmaxf(fmaxf(tm[0] - mrun[0], tm[1] - mrun[1]),
                             fmaxf(tm[2] - mrun[2], tm[3] - mrun[3]));
            if (__ballot(ex > 8.0f)) {       // rescale path (rare after tile 0)
                float corr[4];
#pragma unroll
                for (int r = 0; r < 4; ++r) {
                    float mnew = fmaxf(mrun[r], tm[r]);
                    corr[r] = __expf(mrun[r] - mnew);
                    mrun[r] = mnew;
                }
                // corr is in QK layout; PV layout needs corr for q = lane&15
                const int srcl = ((lane & 15) >> 2) << 4;
                float c0 = __shfl(corr[0], srcl, 64);
                float c1 = __shfl(corr[1], srcl, 64);
                float c2 = __shfl(corr[2], srcl, 64);
                float c3 = __shfl(corr[3], srcl, 64);
                const int selr = (lane & 15) & 3;
                float cp = selr == 0 ? c0 : (selr == 1 ? c1 : (selr == 2 ? c2 : c3));
#pragma unroll
                for (int dc = 0; dc < 4; ++dc)
#pragma unroll
                    for (int t = 0; t < 4; ++t) oacc[dc][t] *= cp;
#pragma unroll
                for (int t = 0; t < 4; ++t) oaccS[t] *= cp;
            }
        }
#pragma unroll
        for (int cb2 = 0; cb2 < 4; ++cb2) {
            int pcol = cb2 * 16 + laneRC;
#pragma unroll
            for (int r = 0; r < 4; ++r) {
                float pv = __expf(s[cb2][r] * scale - mrun[r]);
                int prow = wave * 16 + ((lane >> 4) << 2) + r;
                *(u16*)((char*)lQP + prow * 128 + ((pcol * 2) ^ ((prow & 7) << 4))) = f2bf(pv);
            }
        }

        // O^T += V^T P^T ; sums += ones P^T   (swapped operands)
        __builtin_amdgcn_s_setprio(1);
#pragma unroll
        for (int kk = 0; kk < 2; ++kk) {
            bf16x8 pf, vf[4];
            {
                int pr = wave * 16 + laneRC;
                pf = *(const bf16x8*)((const char*)lQP + pr * 128 + ((kk * 64 + laneK2) ^ ((pr & 7) << 4)));
            }
#pragma unroll
            for (int dc = 0; dc < 4; ++dc) {
                int d = dc * 16 + laneRC;
                vf[dc] = *(const bf16x8*)(lVc + d * 128 + ((kk * 64 + laneK2) ^ ((d & 7) << 4)));
            }
#pragma unroll
            for (int dc = 0; dc < 4; ++dc)
                oacc[dc] = MFMA16(vf[dc], pf, oacc[dc]);
            oaccS = MFMA16(onesf, pf, oaccS);
        }
        __builtin_amdgcn_s_setprio(0);
        vA0 = vB0; vA1 = vB1;
    }
#undef STAGEK

    // epilogue: lane holds q = lane&15, d-rows dc*16 + (lane>>4)*4 + t
    const float inv = 1.0f / oaccS[0];
    const long rowq = (long)b * 2048 + q0 + wave * 16 + (lane & 15);
#pragma unroll
    for (int dc = 0; dc < 4; ++dc) {
        const int colb = h * 64 + dc * 16 + ((lane >> 4) << 2);
        ushort4 st;
        st.x = f2bf(oacc[dc][0] * inv);
        st.y = f2bf(oacc[dc][1] * inv);
        st.z = f2bf(oacc[dc][2] * inv);
        st.w = f2bf(oacc[dc][3] * inv);
        *(ushort4*)(outb + rowq * 768 + colb) = st;
    }
}

// ---------------------------------------------------------------------------
// fused residual-add + NP partial-sums + LayerNorm; wave-per-row, float4 loads
// ---------------------------------------------------------------------------
template<int NP>
__global__ __launch_bounds__(256) void ln_fused(
    const float* __restrict__ a, const float* __restrict__ parts, long pstride,
    const float* __restrict__ g, const float* __restrict__ be,
    float* __restrict__ outf, u16* __restrict__ outb)
{
    const int wave = threadIdx.x >> 6, lane = threadIdx.x & 63;
    const int row = blockIdx.x * 4 + wave;
    const size_t rbase = (size_t)row * 768;
    float4 v[3];
    float s1 = 0.f, s2 = 0.f;
#pragma unroll
    for (int i = 0; i < 3; ++i) {
        const int c = lane * 4 + i * 256;
        float4 x = *(const float4*)(a + rbase + c);
#pragma unroll
        for (int p = 0; p < NP; ++p) {
            const float4 y = *(const float4*)(parts + (size_t)p * pstride + rbase + c);
            x.x += y.x; x.y += y.y; x.z += y.z; x.w += y.w;
        }
        v[i] = x;
        s1 += x.x + x.y + x.z + x.w;
        s2 += x.x * x.x + x.y * x.y + x.z * x.z + x.w * x.w;
    }
#pragma unroll
    for (int m = 1; m < 64; m <<= 1) { s1 += __shfl_xor(s1, m, 64); s2 += __shfl_xor(s2, m, 64); }
    const float mean = s1 * (1.f / 768.f);
    const float var  = s2 * (1.f / 768.f) - mean * mean;
    const float rstd = rsqrtf(var + 1e-5f);
#pragma unroll
    for (int i = 0; i < 3; ++i) {
        const int c = lane * 4 + i * 256;
        const float4 gg = *(const float4*)(g + c);
        const float4 bb = *(const float4*)(be + c);
        float4 y;
        y.x = (v[i].x - mean) * rstd * gg.x + bb.x;
        y.y = (v[i].y - mean) * rstd * gg.y + bb.y;
        y.z = (v[i].z - mean) * rstd * gg.z + bb.z;
        y.w = (v[i].w - mean) * rstd * gg.w + bb.w;
        if (outf) *(float4*)(outf + rbase + c) = y;
        ushort4 u; u.x = f2bf(y.x); u.y = f2bf(y.y); u.z = f2bf(y.z); u.w = f2bf(y.w);
        *(ushort4*)(outb + rbase + c) = u;
    }
}

// ---------------------------------------------------------------------------
// ONE prep launch: 13 weight transposes (blocks [0,14400)) + embB cvt +
// embed+PE + bias concat (blocks [14400, 14400+36306)).
// ---------------------------------------------------------------------------
struct PrepArgs {
    const float* tsrc[13]; u16* tdst[13];
    const float* emb; u16* embB;
    const int* ids; float* xf; u16* xb;
    const float* bq; const float* bk; const float* bv; float* bqkv;
};
__global__ __launch_bounds__(256) void prep_all(PrepArgs pa)
{
    const int bid = blockIdx.x;
    if (bid < 14400) {
        // ---- transpose section: z 0..8 square 768x768; 9..10 W1 768x3072; 11..12 W2 3072x768
        int z, bx, by, R, C;
        if (bid < 5184)       { z = bid / 576;              int r = bid - z * 576;    bx = r % 24; by = r / 24; R = 768;  C = 768;  }
        else if (bid < 9792)  { z = 9 + (bid - 5184) / 2304;  int r = (bid - 5184) % 2304; bx = r % 96; by = r / 96; R = 768;  C = 3072; }
        else                  { z = 11 + (bid - 9792) / 2304; int r = (bid - 9792) % 2304; bx = r % 24; by = r / 24; R = 3072; C = 768;  }
        __shared__ float t[32][33];
        const float* in = pa.tsrc[z];
        u16* out = pa.tdst[z];
        const int c0 = bx * 32, r0 = by * 32;
        const int tx = threadIdx.x & 31, ty = threadIdx.x >> 5;
#pragma unroll
        for (int i = 0; i < 4; ++i)
            t[ty + 8 * i][tx] = in[(size_t)(r0 + ty + 8 * i) * C + c0 + tx];
        __syncthreads();
#pragma unroll
        for (int i = 0; i < 4; ++i)
            out[(size_t)(c0 + ty + 8 * i) * R + r0 + tx] = f2bf(t[tx][ty + 8 * i]);
        return;
    }
    // ---- elementwise section
    const long A = 6144000;      // V*D/4 vec4 conversions
    const long B = 3145728;      // 4096*768 embed elements
    long t = (long)(bid - 14400) * 256 + threadIdx.x;
    if (t < A) {
        const long i = t * 4;
        const float4 f = *(const float4*)(pa.emb + i);
        ushort4 u; u.x = f2bf(f.x); u.y = f2bf(f.y); u.z = f2bf(f.z); u.w = f2bf(f.w);
        *(ushort4*)(pa.embB + i) = u;
    } else if (t < A + B) {
        const int idx = (int)(t - A);
        const int row = idx / 768, d = idx - row * 768;
        const int s = row & 2047;
        const float e = pa.emb[(long)pa.ids[row] * 768 + d];
        const int j = d >> 1;
        const float ang = (float)s * __expf(-0.011992630692677324f * (float)(4 * j));
        const float pe = (d & 1) ? __cosf(ang) : __sinf(ang);
        const float v = e + pe;
        pa.xf[idx] = v;
        pa.xb[idx] = f2bf(v);
    } else {
        const int i = (int)(t - A - B);
        if (i < 4608) {
            int l = i / 2304, j = i - l * 2304;
            float v = (j < 768) ? pa.bq[l * 768 + j]
                    : (j < 1536) ? pa.bk[l * 768 + j - 768]
                    : pa.bv[l * 768 + j - 1536];
            pa.bqkv[i] = v;
        }
    }
}

// ---------------------------------------------------------------------------
extern "C" void kernel_launch(void* const* d_in, const int* in_sizes, int n_in,
                              void* d_out, int out_size, void* d_ws, size_t ws_size,
                              hipStream_t stream)
{
    const int S = 2048, D = 768, H = 12, L = 2, V = 32000, DF = 3072, M = 4096, NQKV = 2304;
    (void)in_sizes; (void)n_in; (void)out_size; (void)ws_size; (void)H; (void)S;

    const int*   ids  = (const int*)  d_in[0];
    const float* emb  = (const float*)d_in[1];
    const float* Wq   = (const float*)d_in[2];
    const float* bq   = (const float*)d_in[3];
    const float* Wk   = (const float*)d_in[4];
    const float* bk   = (const float*)d_in[5];
    const float* Wv   = (const float*)d_in[6];
    const float* bv   = (const float*)d_in[7];
    const float* Wo   = (const float*)d_in[8];
    const float* bo   = (const float*)d_in[9];
    const float* ln1g = (const float*)d_in[10];
    const float* ln1b = (const float*)d_in[11];
    const float* W1   = (const float*)d_in[12];
    const float* b1   = (const float*)d_in[13];
    const float* W2   = (const float*)d_in[14];
    const float* b2   = (const float*)d_in[15];
    const float* ln2g = (const float*)d_in[16];
    const float* ln2b = (const float*)d_in[17];
    const float* Wd   = (const float*)d_in[18];
    const float* bd   = (const float*)d_in[19];
    const float* lnmg = (const float*)d_in[20];
    const float* lnmb = (const float*)d_in[21];
    const float* decb = (const float*)d_in[22];

    char* p = (char*)d_ws;
    auto carve = [&](size_t bytes) { char* r = p; p += (bytes + 255) & ~(size_t)255; return r; };
    u16*   embB  = (u16*)  carve((size_t)V * D * 2);
    u16*   wqkvT = (u16*)  carve((size_t)L * NQKV * D * 2);
    float* bqkv  = (float*)carve((size_t)L * NQKV * 4);
    u16*   woT   = (u16*)  carve((size_t)L * D * D * 2);
    u16*   w1T   = (u16*)  carve((size_t)L * DF * D * 2);
    u16*   w2T   = (u16*)  carve((size_t)L * D * DF * 2);
    u16*   wdT   = (u16*)  carve((size_t)D * D * 2);
    float* xf    = (float*)carve((size_t)M * D * 4);
    u16*   xb    = (u16*)  carve((size_t)M * D * 2);
    u16*   qkvB  = (u16*)  carve((size_t)M * NQKV * 2);
    u16*   aoB   = (u16*)  carve((size_t)M * D * 2);
    float* tmpf  = (float*)carve((size_t)M * D * 4 * 4);   // split-K partials
    u16*   hB    = (u16*)  carve((size_t)M * DF * 2);

    {   // single prep launch: 13 transposes + cvt + embed/PE + bias concat
        PrepArgs pa;
        for (int l = 0; l < L; ++l) {
            pa.tsrc[l * 4 + 0] = Wq + (size_t)l * D * D; pa.tdst[l * 4 + 0] = wqkvT + (size_t)l * NQKV * D;
            pa.tsrc[l * 4 + 1] = Wk + (size_t)l * D * D; pa.tdst[l * 4 + 1] = wqkvT + (size_t)l * NQKV * D + (size_t)D * D;
            pa.tsrc[l * 4 + 2] = Wv + (size_t)l * D * D; pa.tdst[l * 4 + 2] = wqkvT + (size_t)l * NQKV * D + (size_t)2 * D * D;
            pa.tsrc[l * 4 + 3] = Wo + (size_t)l * D * D; pa.tdst[l * 4 + 3] = woT + (size_t)l * D * D;
        }
        pa.tsrc[8]  = Wd;                    pa.tdst[8]  = wdT;
        pa.tsrc[9]  = W1;                    pa.tdst[9]  = w1T;
        pa.tsrc[10] = W1 + (size_t)D * DF;   pa.tdst[10] = w1T + (size_t)DF * D;
        pa.tsrc[11] = W2;                    pa.tdst[11] = w2T;
        pa.tsrc[12] = W2 + (size_t)DF * D;   pa.tdst[12] = w2T + (size_t)D * DF;
        pa.emb = emb; pa.embB = embB;
        pa.ids = ids; pa.xf = xf; pa.xb = xb;
        pa.bq = bq; pa.bk = bk; pa.bv = bv; pa.bqkv = bqkv;
        prep_all<<<14400 + 36306, 256, 0, stream>>>(pa);
    }

    const float scale = 0.036084391824351615f;  // 1/sqrt(768)
    const long PSTR = (long)M * D;
    for (int l = 0; l < L; ++l) {
        gemm_bf16<0, 0, 0, 1><<<dim3(NQKV / 128, M / 128), 256, 0, stream>>>(xb, wqkvT + (size_t)l * NQKV * D, bqkv + l * NQKV, qkvB, NQKV, D);
        attn_fwd<<<dim3(24, 32), 256, 0, stream>>>(qkvB, aoB, scale);
        gemm64<0, 1><<<dim3(D / 64, M / 64), 256, 0, stream>>>(aoB, woT + (size_t)l * D * D, bo + l * D, tmpf, D, D);
        ln_fused<1><<<M / 4, 256, 0, stream>>>(xf, tmpf, PSTR, ln1g + l * D, ln1b + l * D, xf, xb);
        gemm_bf16<1, 0, 0, 1><<<dim3(DF / 128, M / 128), 256, 0, stream>>>(xb, w1T + (size_t)l * DF * D, b1 + l * DF, hB, DF, D);
        gemm_bf16<0, 1, 0, 2><<<dim3(D / 128, M / 128, 2), 256, 0, stream>>>(hB, w2T + (size_t)l * D * DF, b2 + l * D, tmpf, D, DF);
        ln_fused<2><<<M / 4, 256, 0, stream>>>(xf, tmpf, PSTR, ln2g + l * D, ln2b + l * D, xf, xb);
    }
    gemm64<1, 1><<<dim3(D / 64, M / 64), 256, 0, stream>>>(xb, wdT, bd, tmpf, D, D);
    ln_fused<0><<<M / 4, 256, 0, stream>>>(tmpf, nullptr, 0, lnmg, lnmb, nullptr, aoB);
    gemm_bf16<0, 1, 1, 1><<<V / 128 * 32, 256, 0, stream>>>(aoB, embB, decb, (float*)d_out, V, D);
}